// Round 2
// baseline (2479.539 us; speedup 1.0000x reference)
//
#include <hip/hip_runtime.h>

typedef unsigned int u32;

__device__ __forceinline__ float sigmoidf_(float x){
  return 1.f / (1.f + __expf(-x));
}

// ---------------- conv3x3 64->64, pad 1, 128x128, fp32 ----------------
// block 256: tx(16 cols) x ocg(4 groups of 16 oc) x ry(4 strips of 4 rows)
__global__ __launch_bounds__(256) void k_conv(
    const float* __restrict__ in, const float* __restrict__ w,
    const float* __restrict__ resid, float* __restrict__ out, int relu)
{
  __shared__ float tile[18 * 20];
  __shared__ float wt[64 * 12];
  int tid = threadIdx.x;
  int bx = blockIdx.x, by = blockIdx.y, bz = blockIdx.z;
  int tx = tid & 15;
  int ocg = (tid >> 4) & 3;
  int ry = tid >> 6;
  float acc[64];
#pragma unroll
  for (int i = 0; i < 64; i++) acc[i] = 0.f;
  int row0 = by * 16 - 1, col0 = bx * 16 - 1;
  const float* inB = in + (size_t)bz * 64 * 128 * 128;
  for (int ic = 0; ic < 64; ic++){
    __syncthreads();
    for (int i = tid; i < 324; i += 256){
      int r = i / 18, c = i - r * 18;
      int gr = row0 + r, gc = col0 + c;
      float v = 0.f;
      if ((u32)gr < 128u && (u32)gc < 128u)
        v = inB[(ic * 128 + gr) * 128 + gc];
      tile[r * 20 + c] = v;
    }
    for (int i = tid; i < 576; i += 256){
      int oc = i / 9, t = i - oc * 9;
      wt[oc * 12 + t] = w[(oc * 64 + ic) * 9 + t];
    }
    __syncthreads();
    float tv[6][3];
#pragma unroll
    for (int rr = 0; rr < 6; rr++)
#pragma unroll
      for (int cc = 0; cc < 3; cc++)
        tv[rr][cc] = tile[(ry * 4 + rr) * 20 + tx + cc];
#pragma unroll
    for (int i = 0; i < 16; i++){
      int oc = ocg * 16 + i;
      const float* wp = &wt[oc * 12];
      float w0 = wp[0], w1 = wp[1], w2 = wp[2], w3 = wp[3], w4 = wp[4];
      float w5 = wp[5], w6 = wp[6], w7 = wp[7], w8 = wp[8];
#pragma unroll
      for (int j = 0; j < 4; j++){
        float a = acc[j * 16 + i];
        a = fmaf(w0, tv[j][0], a);   a = fmaf(w1, tv[j][1], a);   a = fmaf(w2, tv[j][2], a);
        a = fmaf(w3, tv[j+1][0], a); a = fmaf(w4, tv[j+1][1], a); a = fmaf(w5, tv[j+1][2], a);
        a = fmaf(w6, tv[j+2][0], a); a = fmaf(w7, tv[j+2][1], a); a = fmaf(w8, tv[j+2][2], a);
        acc[j * 16 + i] = a;
      }
    }
  }
#pragma unroll
  for (int i = 0; i < 16; i++){
    int oc = ocg * 16 + i;
#pragma unroll
    for (int j = 0; j < 4; j++){
      int gr = by * 16 + ry * 4 + j;
      int gc = bx * 16 + tx;
      size_t idx = ((size_t)(bz * 64 + oc) * 128 + gr) * 128 + gc;
      float v = acc[j * 16 + i];
      if (relu) v = fmaxf(v, 0.f);
      if (resid) v += resid[idx];
      out[idx] = v;
    }
  }
}

// ---------------- 2x2 avg downsample + NCHW->(b,l,c) tokenize ----------------
__global__ void k_tok(const float* __restrict__ xr, float* __restrict__ T){
  int idx = blockIdx.x * 256 + threadIdx.x; // 4*4096*64
  int c = idx & 63;
  int l = (idx >> 6) & 4095;
  int b = idx >> 18;
  int r = l >> 6, cl = l & 63;
  const float* p = xr + (((size_t)(b * 64 + c) * 128 + 2 * r) * 128 + 2 * cl);
  T[idx] = 0.25f * (p[0] + p[1] + p[128] + p[129]);
}

// ---------------- layernorm over c=64 ----------------
__global__ void k_ln(const float* __restrict__ T, const float* __restrict__ w,
                     const float* __restrict__ b, float* __restrict__ out){
  int row = blockIdx.x * 4 + (threadIdx.x >> 6);
  int c = threadIdx.x & 63;
  float v = T[row * 64 + c];
  float s = v;
  for (int m = 32; m; m >>= 1) s += __shfl_xor(s, m);
  float mu = s * (1.f / 64.f);
  float d = v - mu;
  float q = d * d;
  for (int m = 32; m; m >>= 1) q += __shfl_xor(q, m);
  float var = q * (1.f / 64.f);
  out[row * 64 + c] = d * rsqrtf(var + 1e-5f) * w[c] + b[c];
}

// ---------------- in_proj: (16k,64) @ (64,256)^T -> XC(128) | Z(128) ----------------
__global__ __launch_bounds__(256) void k_inproj(const float* __restrict__ LN,
                                                const float* __restrict__ W,
                                                float* __restrict__ XC, float* __restrict__ Z){
  __shared__ float ln[16 * 64];
  int tid = threadIdx.x;
  int t0 = blockIdx.x * 16;
  for (int i = tid; i < 1024; i += 256) ln[i] = LN[(size_t)t0 * 64 + i];
  __syncthreads();
  int j = tid;
  float wr[64];
  const float4* wp = (const float4*)(W + j * 64);
#pragma unroll
  for (int q = 0; q < 16; q++){
    float4 u = wp[q];
    wr[q*4+0] = u.x; wr[q*4+1] = u.y; wr[q*4+2] = u.z; wr[q*4+3] = u.w;
  }
  float acc[16];
#pragma unroll
  for (int t = 0; t < 16; t++) acc[t] = 0.f;
#pragma unroll
  for (int k = 0; k < 64; k += 4){
#pragma unroll
    for (int t = 0; t < 16; t++){
      float4 lv = *(const float4*)&ln[t * 64 + k];
      acc[t] = fmaf(wr[k], lv.x, fmaf(wr[k+1], lv.y, fmaf(wr[k+2], lv.z, fmaf(wr[k+3], lv.w, acc[t]))));
    }
  }
#pragma unroll
  for (int t = 0; t < 16; t++){
    size_t tg = t0 + t;
    if (j < 128) XC[tg * 128 + j] = acc[t];
    else         Z[tg * 128 + j - 128] = acc[t];
  }
}

// ---------------- causal depthwise conv(4) + bias + silu ----------------
__global__ void k_dwconv(const float* __restrict__ XC, const float* __restrict__ cw,
                         const float* __restrict__ cb, float* __restrict__ U){
  int idx = blockIdx.x * 256 + threadIdx.x; // 4*4096*128
  int n = idx & 127;
  int l = (idx >> 7) & 4095;
  float4 wv = *(const float4*)(cw + n * 4);
  float a = cb[n];
  a = fmaf(wv.w, XC[idx], a);
  if (l >= 1) a = fmaf(wv.z, XC[idx - 128], a);
  if (l >= 2) a = fmaf(wv.y, XC[idx - 256], a);
  if (l >= 3) a = fmaf(wv.x, XC[idx - 384], a);
  U[idx] = a * sigmoidf_(a);
}

// ---------------- x_proj: (16k,128) @ (128,36)^T ----------------
__global__ __launch_bounds__(256) void k_xproj(const float* __restrict__ U,
                                               const float* __restrict__ XW,
                                               float* __restrict__ DBL){
  __shared__ float xp[128 * 36]; // [k][j]
  int tid = threadIdx.x;
  for (int i = tid; i < 4608; i += 256){
    int k = i / 36, j = i - k * 36;
    xp[i] = XW[j * 128 + k];
  }
  __syncthreads();
  int wv = tid >> 6, j = tid & 63;
  size_t tg = (size_t)blockIdx.x * 4 + wv;
  if (j < 36){
    float acc = 0.f;
    const float4* up = (const float4*)(U + tg * 128);
#pragma unroll
    for (int k4 = 0; k4 < 32; k4++){
      float4 u = up[k4];
      const float* x0 = &xp[(k4 * 4) * 36 + j];
      acc = fmaf(u.x, x0[0],   acc);
      acc = fmaf(u.y, x0[36],  acc);
      acc = fmaf(u.z, x0[72],  acc);
      acc = fmaf(u.w, x0[108], acc);
    }
    DBL[tg * 36 + j] = acc;
  }
}

// ---------------- dt = softplus(dtr @ dt_w^T + dt_b) ----------------
__global__ void k_dt(const float* __restrict__ DBL, const float* __restrict__ DW,
                     const float* __restrict__ DB, float* __restrict__ DT){
  int idx = blockIdx.x * 256 + threadIdx.x; // 4*4096*128
  int n = idx & 127;
  size_t tg = (size_t)(idx >> 7);
  float4 d = *(const float4*)(DBL + tg * 36);
  float4 wv = *(const float4*)(DW + n * 4);
  float x = DB[n];
  x = fmaf(wv.x, d.x, x); x = fmaf(wv.y, d.y, x); x = fmaf(wv.z, d.z, x); x = fmaf(wv.w, d.w, x);
  DT[idx] = fmaxf(x, 0.f) + log1pf(__expf(-fabsf(x)));
}

// ---------------- selective scan (both mambas) ----------------
// grid 64: m(2) x b(4) x cg(8).  block 256 = 16 ch x 16 s.
__global__ __launch_bounds__(256) void k_scan(
    const float* __restrict__ DT0, const float* __restrict__ DBL0, const float* __restrict__ U0,
    const float* __restrict__ Z0, const float* __restrict__ AL0, const float* __restrict__ D0,
    float* __restrict__ Y0,
    const float* __restrict__ DT1, const float* __restrict__ DBL1, const float* __restrict__ U1,
    const float* __restrict__ Z1, const float* __restrict__ AL1, const float* __restrict__ D1,
    float* __restrict__ Y1)
{
  __shared__ float sdt[16*68], su[16*68], sz[16*68], sB[16*68], sC[16*68], sy[16*68];
  int bid = blockIdx.x;
  int m = bid >> 5;
  int rem = bid & 31;
  int b = rem >> 3;
  int cg = rem & 7;
  const float* DTp  = m ? DT1  : DT0;
  const float* DBLp = m ? DBL1 : DBL0;
  const float* Up   = m ? U1   : U0;
  const float* Zp   = m ? Z1   : Z0;
  const float* ALp  = m ? AL1  : AL0;
  const float* Dp   = m ? D1   : D0;
  float*       Yp   = m ? Y1   : Y0;
  int tid = threadIdx.x;
  int s = tid & 15;
  int chl = tid >> 4;
  int n = cg * 16 + chl;
  float A1 = -__expf(ALp[n * 16 + s]);
  float Dn = Dp[n];
  float h = 0.f;
  size_t base = (size_t)b * 4096;
  for (int c = 0; c < 64; c++){
    int l0 = c * 64;
    __syncthreads();
    for (int i = tid; i < 1024; i += 256){
      int ch = i & 15, l = i >> 4;
      size_t off = (base + l0 + l) * 128 + cg * 16 + ch;
      sdt[ch * 68 + l] = DTp[off];
      su[ch * 68 + l]  = Up[off];
      sz[ch * 68 + l]  = Zp[off];
      size_t ob = (base + l0 + l) * 36;
      sB[ch * 68 + l] = DBLp[ob + 4 + ch];
      sC[ch * 68 + l] = DBLp[ob + 20 + ch];
    }
    __syncthreads();
#pragma unroll
    for (int l4 = 0; l4 < 16; l4++){
      float4 dtv = *(const float4*)&sdt[chl * 68 + l4 * 4];
      float4 uv  = *(const float4*)&su[chl * 68 + l4 * 4];
      float4 Bv  = *(const float4*)&sB[s * 68 + l4 * 4];
      float4 Cv  = *(const float4*)&sC[s * 68 + l4 * 4];
#pragma unroll
      for (int j = 0; j < 4; j++){
        float dt = (&dtv.x)[j];
        float dA = __expf(dt * A1);
        h = fmaf(dA, h, dt * (&Bv.x)[j] * (&uv.x)[j]);
        float p = h * (&Cv.x)[j];
        p += __shfl_xor(p, 1);
        p += __shfl_xor(p, 2);
        p += __shfl_xor(p, 4);
        p += __shfl_xor(p, 8);
        if (s == 0){
          float y = p + (&uv.x)[j] * Dn;
          float zv = sz[chl * 68 + l4 * 4 + j];
          y = y * (zv * sigmoidf_(zv));
          sy[chl * 68 + l4 * 4 + j] = y;
        }
      }
    }
    __syncthreads();
    for (int i = tid; i < 1024; i += 256){
      int ch = i & 15, l = i >> 4;
      Yp[(base + l0 + l) * 128 + cg * 16 + ch] = sy[ch * 68 + l];
    }
  }
}

// ---------------- out_proj: (16k,128) @ (128,64)^T ----------------
__global__ __launch_bounds__(256) void k_outproj(const float* __restrict__ Y,
                                                 const float* __restrict__ W,
                                                 float* __restrict__ OUT){
  __shared__ float yl[16 * 128];
  __shared__ float wT[128 * 65];
  int tid = threadIdx.x;
  size_t t0 = (size_t)blockIdx.x * 16;
  for (int i = tid; i < 2048; i += 256) yl[i] = Y[t0 * 128 + i];
  for (int i = tid; i < 8192; i += 256){
    int k = i & 127, j = i >> 7;
    wT[k * 65 + j] = W[j * 128 + k];
  }
  __syncthreads();
  int j = tid & 63;
  int tg = tid >> 6;
  float acc[4] = {0.f, 0.f, 0.f, 0.f};
  for (int k = 0; k < 128; k += 4){
    float w0 = wT[k * 65 + j], w1 = wT[(k+1) * 65 + j];
    float w2 = wT[(k+2) * 65 + j], w3 = wT[(k+3) * 65 + j];
#pragma unroll
    for (int t = 0; t < 4; t++){
      float4 yv = *(const float4*)&yl[(tg * 4 + t) * 128 + k];
      acc[t] = fmaf(w0, yv.x, fmaf(w1, yv.y, fmaf(w2, yv.z, fmaf(w3, yv.w, acc[t]))));
    }
  }
#pragma unroll
  for (int t = 0; t < 4; t++)
    OUT[(t0 + tg * 4 + t) * 64 + j] = acc[t];
}

// ---------------- softmax over L: partial pass ----------------
__global__ void k_smA(const float* __restrict__ G, float* __restrict__ P){
  int bid = blockIdx.x; // 64 = b(4) x lc(16)
  int b = bid >> 4, lc = bid & 15;
  int tid = threadIdx.x;
  int j = tid & 63, part = tid >> 6;
  size_t base = (size_t)b * 4096 + lc * 256;
  float mx = -3.4e38f;
  for (int i = 0; i < 64; i++){
    int l = part + i * 4;
    mx = fmaxf(mx, G[(base + l) * 64 + j]);
  }
  float sm = 0.f;
  for (int i = 0; i < 64; i++){
    int l = part + i * 4;
    sm += __expf(G[(base + l) * 64 + j] - mx);
  }
  __shared__ float sM[256], sS[256];
  sM[tid] = mx; sS[tid] = sm;
  __syncthreads();
  if (tid < 64){
    float M = sM[tid], S = sS[tid];
    for (int p = 1; p < 4; p++){
      float m2 = sM[p * 64 + tid], s2 = sS[p * 64 + tid];
      float Mn = fmaxf(M, m2);
      S = S * __expf(M - Mn) + s2 * __expf(m2 - Mn);
      M = Mn;
    }
    P[(bid * 64 + tid) * 2] = M;
    P[(bid * 64 + tid) * 2 + 1] = S;
  }
}

__global__ void k_smB(const float* __restrict__ P, float* __restrict__ F){
  int tid = threadIdx.x; // 256 = b(4) x j(64)
  int b = tid >> 6, j = tid & 63;
  float M = -3.4e38f, S = 0.f;
  for (int lc = 0; lc < 16; lc++){
    int idx = ((b * 16 + lc) * 64 + j) * 2;
    float m2 = P[idx], s2 = P[idx + 1];
    float Mn = fmaxf(M, m2);
    S = S * __expf(M - Mn) + s2 * __expf(m2 - Mn);
    M = Mn;
  }
  F[(b * 64 + j) * 2] = M;
  F[(b * 64 + j) * 2 + 1] = S;
}

// ---------------- combine + transpose to (b,c,64,64) ----------------
__global__ void k_combine(const float* __restrict__ T, const float* __restrict__ MAIN,
                          const float* __restrict__ G, const float* __restrict__ F,
                          float* __restrict__ FEAT){
  int bid = blockIdx.x; // 256 = b(4) x row(64)
  int b = bid >> 6, row = bid & 63;
  int tid = threadIdx.x;
  int j = tid & 63, ls = tid >> 6;
  __shared__ float tile[64 * 65];
  float M = F[(b * 64 + j) * 2], invS = 1.f / F[(b * 64 + j) * 2 + 1];
  size_t lbase = (size_t)b * 4096 + row * 64;
  for (int i = 0; i < 16; i++){
    int col = ls + i * 4;
    size_t off = (lbase + col) * 64 + j;
    float g = __expf(G[off] - M) * invS;
    tile[col * 65 + j] = T[off] + g * MAIN[off];
  }
  __syncthreads();
  int colw = tid & 63, jr = tid >> 6;
  for (int jj = jr; jj < 64; jj += 4)
    FEAT[(((size_t)b * 64 + jj) * 64 + row) * 64 + colw] = tile[colw * 65 + jj];
}

// ---------------- bilinear upsample 64->128 ----------------
__global__ void k_up(const float* __restrict__ FEAT, float* __restrict__ UP){
  size_t idx = (size_t)blockIdx.x * 256 + threadIdx.x; // 4*64*128*128
  int x = idx & 127;
  int y = (idx >> 7) & 127;
  size_t bc = idx >> 14;
  float ay = 0.5f * y - 0.25f;
  float ax = 0.5f * x - 0.25f;
  int fy = (int)floorf(ay); float wy = ay - fy;
  int fx = (int)floorf(ax); float wx = ax - fx;
  int y0 = fy < 0 ? 0 : fy, y1 = fy + 1 > 63 ? 63 : fy + 1;
  int x0 = fx < 0 ? 0 : fx, x1 = fx + 1 > 63 ? 63 : fx + 1;
  const float* p = FEAT + bc * 4096;
  float v = (1.f - wy) * ((1.f - wx) * p[y0 * 64 + x0] + wx * p[y0 * 64 + x1])
          +        wy  * ((1.f - wx) * p[y1 * 64 + x0] + wx * p[y1 * 64 + x1]);
  UP[idx] = v;
}

// ---------------- host launcher ----------------
extern "C" void kernel_launch(void* const* d_in, const int* in_sizes, int n_in,
                              void* d_out, int out_size, void* d_ws, size_t ws_size,
                              hipStream_t stream) {
  // workspace layout (float offsets)
  // phase 1: C1 @0 (4M), XR @4M (4M)  [both dead after k_tok]
  const size_t C1 = 0, XR = 4194304;
  // phase 2: per-mamba blocks overwrite phase-1 scratch
  const size_t MB0 = 0, MB1 = 10027008;
  const size_t O_LN = 0, O_XC = 1048576, O_Z = 3145728, O_U = 5242880,
               O_DT = 7340032, O_DBL = 9437184; // block size 10027008
  const size_t TOK = 20054016, OUT0 = 21102592, OUT1 = 22151168;
  const size_t SMP = 23199744, SMF = 23207936, FEAT = 23208448;
  // phase 3 reuses dead phase-2 scratch
  const size_t UP = 0, CT = 4194304;
  const size_t TOTAL = 24257024;
  if (ws_size < TOTAL * 4) return; // visible failure if ws too small

  float* ws = (float*)d_ws;
  const float* X   = (const float*)d_in[0];
  const float* CB1 = (const float*)d_in[1];
  const float* CB2 = (const float*)d_in[2];
  const float* SW1 = (const float*)d_in[3];
  const float* SW2 = (const float*)d_in[4];
  const float* LNW[2] = { (const float*)d_in[5], (const float*)d_in[7] };
  const float* LNB[2] = { (const float*)d_in[6], (const float*)d_in[8] };
  const float *INW[2], *CW[2], *CBb[2], *XPW[2], *DTW[2], *DTB[2], *AL[2], *DD[2], *OW[2];
  for (int m = 0; m < 2; m++){
    int p = 9 + m * 9;
    INW[m] = (const float*)d_in[p + 0];
    CW[m]  = (const float*)d_in[p + 1];
    CBb[m] = (const float*)d_in[p + 2];
    XPW[m] = (const float*)d_in[p + 3];
    DTW[m] = (const float*)d_in[p + 4];
    DTB[m] = (const float*)d_in[p + 5];
    AL[m]  = (const float*)d_in[p + 6];
    DD[m]  = (const float*)d_in[p + 7];
    OW[m]  = (const float*)d_in[p + 8];
  }
  size_t mb[2] = { MB0, MB1 };

  // phase 1: conv block + tokenize
  k_conv<<<dim3(8, 8, 4), 256, 0, stream>>>(X, CB1, nullptr, ws + C1, 1);
  k_conv<<<dim3(8, 8, 4), 256, 0, stream>>>(ws + C1, CB2, X, ws + XR, 0);
  k_tok<<<4096, 256, 0, stream>>>(ws + XR, ws + TOK);

  // phase 2: per-mamba pre-scan
  for (int m = 0; m < 2; m++){
    size_t B = mb[m];
    k_ln<<<4096, 256, 0, stream>>>(ws + TOK, LNW[m], LNB[m], ws + B + O_LN);
    k_inproj<<<1024, 256, 0, stream>>>(ws + B + O_LN, INW[m], ws + B + O_XC, ws + B + O_Z);
    k_dwconv<<<8192, 256, 0, stream>>>(ws + B + O_XC, CW[m], CBb[m], ws + B + O_U);
    k_xproj<<<4096, 256, 0, stream>>>(ws + B + O_U, XPW[m], ws + B + O_DBL);
    k_dt<<<8192, 256, 0, stream>>>(ws + B + O_DBL, DTW[m], DTB[m], ws + B + O_DT);
  }

  // scan (both mambas); Y reuses the XC slot
  k_scan<<<64, 256, 0, stream>>>(
      ws + MB0 + O_DT, ws + MB0 + O_DBL, ws + MB0 + O_U, ws + MB0 + O_Z, AL[0], DD[0], ws + MB0 + O_XC,
      ws + MB1 + O_DT, ws + MB1 + O_DBL, ws + MB1 + O_U, ws + MB1 + O_Z, AL[1], DD[1], ws + MB1 + O_XC);

  k_outproj<<<1024, 256, 0, stream>>>(ws + MB0 + O_XC, OW[0], ws + OUT0);
  k_outproj<<<1024, 256, 0, stream>>>(ws + MB1 + O_XC, OW[1], ws + OUT1);

  // gate softmax + combine + transpose
  k_smA<<<64, 256, 0, stream>>>(ws + OUT1, ws + SMP);
  k_smB<<<1, 256, 0, stream>>>(ws + SMP, ws + SMF);
  k_combine<<<256, 256, 0, stream>>>(ws + TOK, ws + OUT0, ws + OUT1, ws + SMF, ws + FEAT);

  // phase 3: upsample + final conv block
  k_up<<<16384, 256, 0, stream>>>(ws + FEAT, ws + UP);
  k_conv<<<dim3(8, 8, 4), 256, 0, stream>>>(ws + UP, SW1, nullptr, ws + CT, 1);
  k_conv<<<dim3(8, 8, 4), 256, 0, stream>>>(ws + CT, SW2, nullptr, (float*)d_out, 0);
}

// Round 3
// 1587.900 us; speedup vs baseline: 1.5615x; 1.5615x over previous
//
#include <hip/hip_runtime.h>

typedef unsigned int u32;

__device__ __forceinline__ float sigmoidf_(float x){
  return 1.f / (1.f + __expf(-x));
}

// ---------------- conv3x3 64->64, pad 1, 128x128, fp32 ----------------
// grid (8,8,16): z = b*4 + ocq (16 oc per block). block 256 = tx(16) x ry(16).
// Each thread: 1 output pixel x 16 oc.
__global__ __launch_bounds__(256) void k_conv(
    const float* __restrict__ in, const float* __restrict__ w,
    const float* __restrict__ resid, float* __restrict__ out, int relu)
{
  __shared__ float tile[18 * 20];
  __shared__ float wt[16 * 12];
  int tid = threadIdx.x;
  int bx = blockIdx.x, by = blockIdx.y, bz = blockIdx.z;
  int b = bz >> 2, ocq = bz & 3;
  int tx = tid & 15, ry = tid >> 4;
  float acc[16];
#pragma unroll
  for (int i = 0; i < 16; i++) acc[i] = 0.f;
  int row0 = by * 16 - 1, col0 = bx * 16 - 1;
  const float* inB = in + (size_t)b * 64 * 128 * 128;
  for (int ic = 0; ic < 64; ic++){
    __syncthreads();
    for (int i = tid; i < 324; i += 256){
      int r = i / 18, c = i - r * 18;
      int gr = row0 + r, gc = col0 + c;
      float v = 0.f;
      if ((u32)gr < 128u && (u32)gc < 128u)
        v = inB[(ic * 128 + gr) * 128 + gc];
      tile[r * 20 + c] = v;
    }
    if (tid < 144){
      int oc = tid / 9, t = tid - oc * 9;
      wt[oc * 12 + t] = w[((ocq * 16 + oc) * 64 + ic) * 9 + t];
    }
    __syncthreads();
    float tv[3][3];
#pragma unroll
    for (int rr = 0; rr < 3; rr++)
#pragma unroll
      for (int cc = 0; cc < 3; cc++)
        tv[rr][cc] = tile[(ry + rr) * 20 + tx + cc];
#pragma unroll
    for (int i = 0; i < 16; i++){
      const float* wp = &wt[i * 12];
      float a = acc[i];
      a = fmaf(wp[0], tv[0][0], a); a = fmaf(wp[1], tv[0][1], a); a = fmaf(wp[2], tv[0][2], a);
      a = fmaf(wp[3], tv[1][0], a); a = fmaf(wp[4], tv[1][1], a); a = fmaf(wp[5], tv[1][2], a);
      a = fmaf(wp[6], tv[2][0], a); a = fmaf(wp[7], tv[2][1], a); a = fmaf(wp[8], tv[2][2], a);
      acc[i] = a;
    }
  }
  int gr = by * 16 + ry, gc = bx * 16 + tx;
#pragma unroll
  for (int i = 0; i < 16; i++){
    size_t idx = ((size_t)(b * 64 + ocq * 16 + i) * 128 + gr) * 128 + gc;
    float v = acc[i];
    if (relu) v = fmaxf(v, 0.f);
    if (resid) v += resid[idx];
    out[idx] = v;
  }
}

// ---------------- 2x2 avg downsample + NCHW->(b,l,c) tokenize ----------------
__global__ void k_tok(const float* __restrict__ xr, float* __restrict__ T){
  int idx = blockIdx.x * 256 + threadIdx.x; // 4*4096*64
  int c = idx & 63;
  int l = (idx >> 6) & 4095;
  int b = idx >> 18;
  int r = l >> 6, cl = l & 63;
  const float* p = xr + (((size_t)(b * 64 + c) * 128 + 2 * r) * 128 + 2 * cl);
  T[idx] = 0.25f * (p[0] + p[1] + p[128] + p[129]);
}

// ---------------- layernorm over c=64 ----------------
__global__ void k_ln(const float* __restrict__ T, const float* __restrict__ w,
                     const float* __restrict__ b, float* __restrict__ out){
  int row = blockIdx.x * 4 + (threadIdx.x >> 6);
  int c = threadIdx.x & 63;
  float v = T[row * 64 + c];
  float s = v;
  for (int m = 32; m; m >>= 1) s += __shfl_xor(s, m);
  float mu = s * (1.f / 64.f);
  float d = v - mu;
  float q = d * d;
  for (int m = 32; m; m >>= 1) q += __shfl_xor(q, m);
  float var = q * (1.f / 64.f);
  out[row * 64 + c] = d * rsqrtf(var + 1e-5f) * w[c] + b[c];
}

// ---------------- in_proj: (16k,64) @ (64,256)^T -> XC(128) | Z(128) ----------------
__global__ __launch_bounds__(256) void k_inproj(const float* __restrict__ LN,
                                                const float* __restrict__ W,
                                                float* __restrict__ XC, float* __restrict__ Z){
  __shared__ float ln[16 * 64];
  int tid = threadIdx.x;
  int t0 = blockIdx.x * 16;
  for (int i = tid; i < 1024; i += 256) ln[i] = LN[(size_t)t0 * 64 + i];
  __syncthreads();
  int j = tid;
  float wr[64];
  const float4* wp = (const float4*)(W + j * 64);
#pragma unroll
  for (int q = 0; q < 16; q++){
    float4 u = wp[q];
    wr[q*4+0] = u.x; wr[q*4+1] = u.y; wr[q*4+2] = u.z; wr[q*4+3] = u.w;
  }
  float acc[16];
#pragma unroll
  for (int t = 0; t < 16; t++) acc[t] = 0.f;
#pragma unroll
  for (int k = 0; k < 64; k += 4){
#pragma unroll
    for (int t = 0; t < 16; t++){
      float4 lv = *(const float4*)&ln[t * 64 + k];
      acc[t] = fmaf(wr[k], lv.x, fmaf(wr[k+1], lv.y, fmaf(wr[k+2], lv.z, fmaf(wr[k+3], lv.w, acc[t]))));
    }
  }
#pragma unroll
  for (int t = 0; t < 16; t++){
    size_t tg = t0 + t;
    if (j < 128) XC[tg * 128 + j] = acc[t];
    else         Z[tg * 128 + j - 128] = acc[t];
  }
}

// ---------------- causal depthwise conv(4) + bias + silu ----------------
__global__ void k_dwconv(const float* __restrict__ XC, const float* __restrict__ cw,
                         const float* __restrict__ cb, float* __restrict__ U){
  int idx = blockIdx.x * 256 + threadIdx.x; // 4*4096*128
  int n = idx & 127;
  int l = (idx >> 7) & 4095;
  float4 wv = *(const float4*)(cw + n * 4);
  float a = cb[n];
  a = fmaf(wv.w, XC[idx], a);
  if (l >= 1) a = fmaf(wv.z, XC[idx - 128], a);
  if (l >= 2) a = fmaf(wv.y, XC[idx - 256], a);
  if (l >= 3) a = fmaf(wv.x, XC[idx - 384], a);
  U[idx] = a * sigmoidf_(a);
}

// ---------------- x_proj: (16k,128) @ (128,36)^T ----------------
__global__ __launch_bounds__(256) void k_xproj(const float* __restrict__ U,
                                               const float* __restrict__ XW,
                                               float* __restrict__ DBL){
  __shared__ float xp[128 * 36]; // [k][j]
  int tid = threadIdx.x;
  for (int i = tid; i < 4608; i += 256){
    int k = i / 36, j = i - k * 36;
    xp[i] = XW[j * 128 + k];
  }
  __syncthreads();
  int wv = tid >> 6, j = tid & 63;
  size_t tg = (size_t)blockIdx.x * 4 + wv;
  if (j < 36){
    float acc = 0.f;
    const float4* up = (const float4*)(U + tg * 128);
#pragma unroll
    for (int k4 = 0; k4 < 32; k4++){
      float4 u = up[k4];
      const float* x0 = &xp[(k4 * 4) * 36 + j];
      acc = fmaf(u.x, x0[0],   acc);
      acc = fmaf(u.y, x0[36],  acc);
      acc = fmaf(u.z, x0[72],  acc);
      acc = fmaf(u.w, x0[108], acc);
    }
    DBL[tg * 36 + j] = acc;
  }
}

// ---------------- dt = softplus(dtr @ dt_w^T + dt_b) ----------------
__global__ void k_dt(const float* __restrict__ DBL, const float* __restrict__ DW,
                     const float* __restrict__ DB, float* __restrict__ DT){
  int idx = blockIdx.x * 256 + threadIdx.x; // 4*4096*128
  int n = idx & 127;
  size_t tg = (size_t)(idx >> 7);
  float4 d = *(const float4*)(DBL + tg * 36);
  float4 wv = *(const float4*)(DW + n * 4);
  float x = DB[n];
  x = fmaf(wv.x, d.x, x); x = fmaf(wv.y, d.y, x); x = fmaf(wv.z, d.z, x); x = fmaf(wv.w, d.w, x);
  DT[idx] = fmaxf(x, 0.f) + log1pf(__expf(-fabsf(x)));
}

// ================= chunked parallel scan =================
// L=4096 split into 64 chunks of 64. Recurrence per (m,b,n,s):
//   h_t = a_t h_{t-1} + b_t,  a_t = exp(dt*A1), b_t = dt*B*u.
// Phase A: per-chunk local scan from 0 -> (prod a, h_final).
// Phase B: prefix across chunks -> h_in per chunk.
// Phase C: re-scan chunk seeded with h_in, reduce over s, gate, write y.

// Phase A. grid 4096: bid = ((m*4+b)*64+c)*8 + cg. block 256 = 16 ch x 16 s.
__global__ __launch_bounds__(256) void k_scanA(
    const float* __restrict__ DT0, const float* __restrict__ DBL0, const float* __restrict__ U0,
    const float* __restrict__ AL0,
    const float* __restrict__ DT1, const float* __restrict__ DBL1, const float* __restrict__ U1,
    const float* __restrict__ AL1,
    float* __restrict__ HF, float* __restrict__ AP)
{
  __shared__ float sdt[16*68], su[16*68], sB[16*68];
  int bid = blockIdx.x;
  int cg = bid & 7;
  int c  = (bid >> 3) & 63;
  int b  = (bid >> 9) & 3;
  int m  = bid >> 11;
  const float* DTp  = m ? DT1  : DT0;
  const float* DBLp = m ? DBL1 : DBL0;
  const float* Up   = m ? U1   : U0;
  const float* ALp  = m ? AL1  : AL0;
  int tid = threadIdx.x;
  int s = tid & 15;
  int chl = tid >> 4;
  int n = cg * 16 + chl;
  size_t base = (size_t)b * 4096 + c * 64;
  for (int i = tid; i < 1024; i += 256){
    int ch = i & 15, l = i >> 4;
    size_t off = (base + l) * 128 + cg * 16 + ch;
    sdt[ch * 68 + l] = DTp[off];
    su[ch * 68 + l]  = Up[off];
    sB[ch * 68 + l]  = DBLp[(base + l) * 36 + 4 + ch];
  }
  float A1 = -__expf(ALp[n * 16 + s]);
  __syncthreads();
  float h = 0.f, ap = 1.f;
#pragma unroll
  for (int l4 = 0; l4 < 16; l4++){
    float4 dtv = *(const float4*)&sdt[chl * 68 + l4 * 4];
    float4 uv  = *(const float4*)&su[chl * 68 + l4 * 4];
    float4 Bv  = *(const float4*)&sB[s * 68 + l4 * 4];
#pragma unroll
    for (int j = 0; j < 4; j++){
      float dt = (&dtv.x)[j];
      float a = __expf(dt * A1);
      h = fmaf(a, h, dt * (&Bv.x)[j] * (&uv.x)[j]);
      ap *= a;
    }
  }
  size_t o = (size_t)(bid >> 3) * 2048 + n * 16 + s;
  HF[o] = h;
  AP[o] = ap;
}

// Phase B. grid 64 x 256 = 16384 recurrences; 64 chunks each.
__global__ __launch_bounds__(256) void k_scanB(
    const float* __restrict__ HF, const float* __restrict__ AP, float* __restrict__ HIN)
{
  int r = blockIdx.x * 256 + threadIdx.x;
  int q = r >> 11;        // (m*4+b)
  int p = r & 2047;       // n*16+s
  float h = 0.f;
  for (int c = 0; c < 64; c++){
    size_t o = (size_t)(q * 64 + c) * 2048 + p;
    HIN[o] = h;
    h = fmaf(AP[o], h, HF[o]);
  }
}

// Phase C. same decode as A; seeded scan + y output.
__global__ __launch_bounds__(256) void k_scanC(
    const float* __restrict__ DT0, const float* __restrict__ DBL0, const float* __restrict__ U0,
    const float* __restrict__ Z0, const float* __restrict__ AL0, const float* __restrict__ D0,
    float* __restrict__ Y0,
    const float* __restrict__ DT1, const float* __restrict__ DBL1, const float* __restrict__ U1,
    const float* __restrict__ Z1, const float* __restrict__ AL1, const float* __restrict__ D1,
    float* __restrict__ Y1,
    const float* __restrict__ HIN)
{
  __shared__ float sdt[16*68], su[16*68], sz[16*68], sB[16*68], sC[16*68], sy[16*68];
  int bid = blockIdx.x;
  int cg = bid & 7;
  int c  = (bid >> 3) & 63;
  int b  = (bid >> 9) & 3;
  int m  = bid >> 11;
  const float* DTp  = m ? DT1  : DT0;
  const float* DBLp = m ? DBL1 : DBL0;
  const float* Up   = m ? U1   : U0;
  const float* Zp   = m ? Z1   : Z0;
  const float* ALp  = m ? AL1  : AL0;
  const float* Dp   = m ? D1   : D0;
  float*       Yp   = m ? Y1   : Y0;
  int tid = threadIdx.x;
  int s = tid & 15;
  int chl = tid >> 4;
  int n = cg * 16 + chl;
  size_t base = (size_t)b * 4096 + c * 64;
  for (int i = tid; i < 1024; i += 256){
    int ch = i & 15, l = i >> 4;
    size_t off = (base + l) * 128 + cg * 16 + ch;
    sdt[ch * 68 + l] = DTp[off];
    su[ch * 68 + l]  = Up[off];
    sz[ch * 68 + l]  = Zp[off];
    size_t ob = (base + l) * 36;
    sB[ch * 68 + l] = DBLp[ob + 4 + ch];
    sC[ch * 68 + l] = DBLp[ob + 20 + ch];
  }
  float A1 = -__expf(ALp[n * 16 + s]);
  float Dn = Dp[n];
  float h = HIN[(size_t)(bid >> 3) * 2048 + n * 16 + s];
  __syncthreads();
#pragma unroll
  for (int l4 = 0; l4 < 16; l4++){
    float4 dtv = *(const float4*)&sdt[chl * 68 + l4 * 4];
    float4 uv  = *(const float4*)&su[chl * 68 + l4 * 4];
    float4 Bv  = *(const float4*)&sB[s * 68 + l4 * 4];
    float4 Cv  = *(const float4*)&sC[s * 68 + l4 * 4];
#pragma unroll
    for (int j = 0; j < 4; j++){
      float dt = (&dtv.x)[j];
      float a = __expf(dt * A1);
      h = fmaf(a, h, dt * (&Bv.x)[j] * (&uv.x)[j]);
      float p = h * (&Cv.x)[j];
      p += __shfl_xor(p, 1);
      p += __shfl_xor(p, 2);
      p += __shfl_xor(p, 4);
      p += __shfl_xor(p, 8);
      if (s == 0){
        float y = p + (&uv.x)[j] * Dn;
        float zv = sz[chl * 68 + l4 * 4 + j];
        y = y * (zv * sigmoidf_(zv));
        sy[chl * 68 + l4 * 4 + j] = y;
      }
    }
  }
  __syncthreads();
  for (int i = tid; i < 1024; i += 256){
    int ch = i & 15, l = i >> 4;
    Yp[(base + l) * 128 + cg * 16 + ch] = sy[ch * 68 + l];
  }
}

// ---------------- out_proj: (16k,128) @ (128,64)^T ----------------
__global__ __launch_bounds__(256) void k_outproj(const float* __restrict__ Y,
                                                 const float* __restrict__ W,
                                                 float* __restrict__ OUT){
  __shared__ float yl[16 * 128];
  __shared__ float wT[128 * 65];
  int tid = threadIdx.x;
  size_t t0 = (size_t)blockIdx.x * 16;
  for (int i = tid; i < 2048; i += 256) yl[i] = Y[t0 * 128 + i];
  for (int i = tid; i < 8192; i += 256){
    int k = i & 127, j = i >> 7;
    wT[k * 65 + j] = W[j * 128 + k];
  }
  __syncthreads();
  int j = tid & 63;
  int tg = tid >> 6;
  float acc[4] = {0.f, 0.f, 0.f, 0.f};
  for (int k = 0; k < 128; k += 4){
    float w0 = wT[k * 65 + j], w1 = wT[(k+1) * 65 + j];
    float w2 = wT[(k+2) * 65 + j], w3 = wT[(k+3) * 65 + j];
#pragma unroll
    for (int t = 0; t < 4; t++){
      float4 yv = *(const float4*)&yl[(tg * 4 + t) * 128 + k];
      acc[t] = fmaf(w0, yv.x, fmaf(w1, yv.y, fmaf(w2, yv.z, fmaf(w3, yv.w, acc[t]))));
    }
  }
#pragma unroll
  for (int t = 0; t < 4; t++)
    OUT[(t0 + tg * 4 + t) * 64 + j] = acc[t];
}

// ---------------- softmax over L: partial pass ----------------
__global__ void k_smA(const float* __restrict__ G, float* __restrict__ P){
  int bid = blockIdx.x; // 64 = b(4) x lc(16)
  int b = bid >> 4, lc = bid & 15;
  int tid = threadIdx.x;
  int j = tid & 63, part = tid >> 6;
  size_t base = (size_t)b * 4096 + lc * 256;
  float mx = -3.4e38f;
  for (int i = 0; i < 64; i++){
    int l = part + i * 4;
    mx = fmaxf(mx, G[(base + l) * 64 + j]);
  }
  float sm = 0.f;
  for (int i = 0; i < 64; i++){
    int l = part + i * 4;
    sm += __expf(G[(base + l) * 64 + j] - mx);
  }
  __shared__ float sM[256], sS[256];
  sM[tid] = mx; sS[tid] = sm;
  __syncthreads();
  if (tid < 64){
    float M = sM[tid], S = sS[tid];
    for (int p = 1; p < 4; p++){
      float m2 = sM[p * 64 + tid], s2 = sS[p * 64 + tid];
      float Mn = fmaxf(M, m2);
      S = S * __expf(M - Mn) + s2 * __expf(m2 - Mn);
      M = Mn;
    }
    P[(bid * 64 + tid) * 2] = M;
    P[(bid * 64 + tid) * 2 + 1] = S;
  }
}

__global__ void k_smB(const float* __restrict__ P, float* __restrict__ F){
  int tid = threadIdx.x; // 256 = b(4) x j(64)
  int b = tid >> 6, j = tid & 63;
  float M = -3.4e38f, S = 0.f;
  for (int lc = 0; lc < 16; lc++){
    int idx = ((b * 16 + lc) * 64 + j) * 2;
    float m2 = P[idx], s2 = P[idx + 1];
    float Mn = fmaxf(M, m2);
    S = S * __expf(M - Mn) + s2 * __expf(m2 - Mn);
    M = Mn;
  }
  F[(b * 64 + j) * 2] = M;
  F[(b * 64 + j) * 2 + 1] = S;
}

// ---------------- combine + transpose to (b,c,64,64) ----------------
__global__ void k_combine(const float* __restrict__ T, const float* __restrict__ MAIN,
                          const float* __restrict__ G, const float* __restrict__ F,
                          float* __restrict__ FEAT){
  int bid = blockIdx.x; // 256 = b(4) x row(64)
  int b = bid >> 6, row = bid & 63;
  int tid = threadIdx.x;
  int j = tid & 63, ls = tid >> 6;
  __shared__ float tile[64 * 65];
  float M = F[(b * 64 + j) * 2], invS = 1.f / F[(b * 64 + j) * 2 + 1];
  size_t lbase = (size_t)b * 4096 + row * 64;
  for (int i = 0; i < 16; i++){
    int col = ls + i * 4;
    size_t off = (lbase + col) * 64 + j;
    float g = __expf(G[off] - M) * invS;
    tile[col * 65 + j] = T[off] + g * MAIN[off];
  }
  __syncthreads();
  int colw = tid & 63, jr = tid >> 6;
  for (int jj = jr; jj < 64; jj += 4)
    FEAT[(((size_t)b * 64 + jj) * 64 + row) * 64 + colw] = tile[colw * 65 + jj];
}

// ---------------- bilinear upsample 64->128 ----------------
__global__ void k_up(const float* __restrict__ FEAT, float* __restrict__ UP){
  size_t idx = (size_t)blockIdx.x * 256 + threadIdx.x; // 4*64*128*128
  int x = idx & 127;
  int y = (idx >> 7) & 127;
  size_t bc = idx >> 14;
  float ay = 0.5f * y - 0.25f;
  float ax = 0.5f * x - 0.25f;
  int fy = (int)floorf(ay); float wy = ay - fy;
  int fx = (int)floorf(ax); float wx = ax - fx;
  int y0 = fy < 0 ? 0 : fy, y1 = fy + 1 > 63 ? 63 : fy + 1;
  int x0 = fx < 0 ? 0 : fx, x1 = fx + 1 > 63 ? 63 : fx + 1;
  const float* p = FEAT + bc * 4096;
  float v = (1.f - wy) * ((1.f - wx) * p[y0 * 64 + x0] + wx * p[y0 * 64 + x1])
          +        wy  * ((1.f - wx) * p[y1 * 64 + x0] + wx * p[y1 * 64 + x1]);
  UP[idx] = v;
}

// ---------------- host launcher ----------------
extern "C" void kernel_launch(void* const* d_in, const int* in_sizes, int n_in,
                              void* d_out, int out_size, void* d_ws, size_t ws_size,
                              hipStream_t stream) {
  // workspace layout (float offsets)
  const size_t C1 = 0, XR = 4194304;
  const size_t MB0 = 0, MB1 = 10027008;
  const size_t O_LN = 0, O_XC = 1048576, O_Z = 3145728, O_U = 5242880,
               O_DT = 7340032, O_DBL = 9437184; // block size 10027008
  const size_t TOK = 20054016, OUT0 = 21102592, OUT1 = 22151168;
  const size_t SMP = 23199744, SMF = 23207936, FEAT = 23208448;
  const size_t UP = 0, CT = 4194304;
  const size_t TOTAL = 24257024;
  // scan scratch in dead slots:
  //   HF  -> MB0+O_XC          (XC0 dead after dwconv; 1M)
  //   AP  -> MB0+O_XC+1048576  (second half of XC0 slot; 1M)
  //   HIN -> MB0+O_LN          (LN0 dead after inproj; 1M)
  // phase C writes Y0 over HF/AP (dead after phase B), Y1 into XC1 slot.
  if (ws_size < TOTAL * 4) return;

  float* ws = (float*)d_ws;
  const float* X   = (const float*)d_in[0];
  const float* CB1 = (const float*)d_in[1];
  const float* CB2 = (const float*)d_in[2];
  const float* SW1 = (const float*)d_in[3];
  const float* SW2 = (const float*)d_in[4];
  const float* LNW[2] = { (const float*)d_in[5], (const float*)d_in[7] };
  const float* LNB[2] = { (const float*)d_in[6], (const float*)d_in[8] };
  const float *INW[2], *CW[2], *CBb[2], *XPW[2], *DTW[2], *DTB[2], *AL[2], *DD[2], *OW[2];
  for (int m = 0; m < 2; m++){
    int p = 9 + m * 9;
    INW[m] = (const float*)d_in[p + 0];
    CW[m]  = (const float*)d_in[p + 1];
    CBb[m] = (const float*)d_in[p + 2];
    XPW[m] = (const float*)d_in[p + 3];
    DTW[m] = (const float*)d_in[p + 4];
    DTB[m] = (const float*)d_in[p + 5];
    AL[m]  = (const float*)d_in[p + 6];
    DD[m]  = (const float*)d_in[p + 7];
    OW[m]  = (const float*)d_in[p + 8];
  }
  size_t mb[2] = { MB0, MB1 };

  // phase 1: conv block + tokenize
  k_conv<<<dim3(8, 8, 16), 256, 0, stream>>>(X, CB1, nullptr, ws + C1, 1);
  k_conv<<<dim3(8, 8, 16), 256, 0, stream>>>(ws + C1, CB2, X, ws + XR, 0);
  k_tok<<<4096, 256, 0, stream>>>(ws + XR, ws + TOK);

  // phase 2: per-mamba pre-scan
  for (int m = 0; m < 2; m++){
    size_t B = mb[m];
    k_ln<<<4096, 256, 0, stream>>>(ws + TOK, LNW[m], LNB[m], ws + B + O_LN);
    k_inproj<<<1024, 256, 0, stream>>>(ws + B + O_LN, INW[m], ws + B + O_XC, ws + B + O_Z);
    k_dwconv<<<8192, 256, 0, stream>>>(ws + B + O_XC, CW[m], CBb[m], ws + B + O_U);
    k_xproj<<<4096, 256, 0, stream>>>(ws + B + O_U, XPW[m], ws + B + O_DBL);
    k_dt<<<8192, 256, 0, stream>>>(ws + B + O_DBL, DTW[m], DTB[m], ws + B + O_DT);
  }

  float* HF  = ws + MB0 + O_XC;
  float* AP  = ws + MB0 + O_XC + 1048576;
  float* HIN = ws + MB0 + O_LN;

  k_scanA<<<4096, 256, 0, stream>>>(
      ws + MB0 + O_DT, ws + MB0 + O_DBL, ws + MB0 + O_U, AL[0],
      ws + MB1 + O_DT, ws + MB1 + O_DBL, ws + MB1 + O_U, AL[1],
      HF, AP);
  k_scanB<<<64, 256, 0, stream>>>(HF, AP, HIN);
  k_scanC<<<4096, 256, 0, stream>>>(
      ws + MB0 + O_DT, ws + MB0 + O_DBL, ws + MB0 + O_U, ws + MB0 + O_Z, AL[0], DD[0], ws + MB0 + O_XC,
      ws + MB1 + O_DT, ws + MB1 + O_DBL, ws + MB1 + O_U, ws + MB1 + O_Z, AL[1], DD[1], ws + MB1 + O_XC,
      HIN);

  k_outproj<<<1024, 256, 0, stream>>>(ws + MB0 + O_XC, OW[0], ws + OUT0);
  k_outproj<<<1024, 256, 0, stream>>>(ws + MB1 + O_XC, OW[1], ws + OUT1);

  // gate softmax + combine + transpose
  k_smA<<<64, 256, 0, stream>>>(ws + OUT1, ws + SMP);
  k_smB<<<1, 256, 0, stream>>>(ws + SMP, ws + SMF);
  k_combine<<<256, 256, 0, stream>>>(ws + TOK, ws + OUT0, ws + OUT1, ws + SMF, ws + FEAT);

  // phase 3: upsample + final conv block
  k_up<<<16384, 256, 0, stream>>>(ws + FEAT, ws + UP);
  k_conv<<<dim3(8, 8, 16), 256, 0, stream>>>(ws + UP, SW1, nullptr, ws + CT, 1);
  k_conv<<<dim3(8, 8, 16), 256, 0, stream>>>(ws + CT, SW2, nullptr, (float*)d_out, 0);
}

// Round 4
// 1189.047 us; speedup vs baseline: 2.0853x; 1.3354x over previous
//
#include <hip/hip_runtime.h>

typedef unsigned int u32;

__device__ __forceinline__ float sigmoidf_(float x){
  return 1.f / (1.f + __expf(-x));
}

// ---------------- conv3x3 64->64, pad 1, 128x128, fp32 ----------------
// grid (8,8,16): z = b*4 + ocq (16 oc per block). block 256 = tx(16) x ry(16).
__global__ __launch_bounds__(256) void k_conv(
    const float* __restrict__ in, const float* __restrict__ w,
    const float* __restrict__ resid, float* __restrict__ out, int relu)
{
  __shared__ float tile[18 * 20];
  __shared__ float wt[16 * 12];
  int tid = threadIdx.x;
  int bx = blockIdx.x, by = blockIdx.y, bz = blockIdx.z;
  int b = bz >> 2, ocq = bz & 3;
  int tx = tid & 15, ry = tid >> 4;
  float acc[16];
#pragma unroll
  for (int i = 0; i < 16; i++) acc[i] = 0.f;
  int row0 = by * 16 - 1, col0 = bx * 16 - 1;
  const float* inB = in + (size_t)b * 64 * 128 * 128;
  for (int ic = 0; ic < 64; ic++){
    __syncthreads();
    for (int i = tid; i < 324; i += 256){
      int r = i / 18, c = i - r * 18;
      int gr = row0 + r, gc = col0 + c;
      float v = 0.f;
      if ((u32)gr < 128u && (u32)gc < 128u)
        v = inB[(ic * 128 + gr) * 128 + gc];
      tile[r * 20 + c] = v;
    }
    if (tid < 144){
      int oc = tid / 9, t = tid - oc * 9;
      wt[oc * 12 + t] = w[((ocq * 16 + oc) * 64 + ic) * 9 + t];
    }
    __syncthreads();
    float tv[3][3];
#pragma unroll
    for (int rr = 0; rr < 3; rr++)
#pragma unroll
      for (int cc = 0; cc < 3; cc++)
        tv[rr][cc] = tile[(ry + rr) * 20 + tx + cc];
#pragma unroll
    for (int i = 0; i < 16; i++){
      const float* wp = &wt[i * 12];
      float a = acc[i];
      a = fmaf(wp[0], tv[0][0], a); a = fmaf(wp[1], tv[0][1], a); a = fmaf(wp[2], tv[0][2], a);
      a = fmaf(wp[3], tv[1][0], a); a = fmaf(wp[4], tv[1][1], a); a = fmaf(wp[5], tv[1][2], a);
      a = fmaf(wp[6], tv[2][0], a); a = fmaf(wp[7], tv[2][1], a); a = fmaf(wp[8], tv[2][2], a);
      acc[i] = a;
    }
  }
  int gr = by * 16 + ry, gc = bx * 16 + tx;
#pragma unroll
  for (int i = 0; i < 16; i++){
    size_t idx = ((size_t)(b * 64 + ocq * 16 + i) * 128 + gr) * 128 + gc;
    float v = acc[i];
    if (relu) v = fmaxf(v, 0.f);
    if (resid) v += resid[idx];
    out[idx] = v;
  }
}

// ---------------- 2x2 avg downsample + NCHW->(b,l,c) tokenize ----------------
__global__ void k_tok(const float* __restrict__ xr, float* __restrict__ T){
  int idx = blockIdx.x * 256 + threadIdx.x; // 4*4096*64
  int c = idx & 63;
  int l = (idx >> 6) & 4095;
  int b = idx >> 18;
  int r = l >> 6, cl = l & 63;
  const float* p = xr + (((size_t)(b * 64 + c) * 128 + 2 * r) * 128 + 2 * cl);
  T[idx] = 0.25f * (p[0] + p[1] + p[128] + p[129]);
}

// ---------------- layernorm over c=64 ----------------
__global__ void k_ln(const float* __restrict__ T, const float* __restrict__ w,
                     const float* __restrict__ b, float* __restrict__ out){
  int row = blockIdx.x * 4 + (threadIdx.x >> 6);
  int c = threadIdx.x & 63;
  float v = T[row * 64 + c];
  float s = v;
  for (int m = 32; m; m >>= 1) s += __shfl_xor(s, m);
  float mu = s * (1.f / 64.f);
  float d = v - mu;
  float q = d * d;
  for (int m = 32; m; m >>= 1) q += __shfl_xor(q, m);
  float var = q * (1.f / 64.f);
  out[row * 64 + c] = d * rsqrtf(var + 1e-5f) * w[c] + b[c];
}

// ---------------- in_proj: (16k,64) @ (64,256)^T -> XC(128) | Z(128) ----------------
// grid (1024, 2): x = token tile (16 tokens), y = col half (128 cols).
// block 256 = j(128 cols) x th(2 token halves of 8). W staged in LDS as [k][j]
// (stride 132: reads conflict-free, no per-thread weight arrays -> no spill).
__global__ __launch_bounds__(256) void k_inproj(const float* __restrict__ LN,
                                                const float* __restrict__ W,
                                                float* __restrict__ XC, float* __restrict__ Z){
  __shared__ float wL[64 * 132];
  __shared__ float ln[16 * 64];
  int tid = threadIdx.x;
  int t0 = blockIdx.x * 16;
  int j0 = blockIdx.y * 128;
  for (int i = tid; i < 1024; i += 256) ln[i] = LN[(size_t)t0 * 64 + i];
  for (int i = tid; i < 8192; i += 256){
    int jl = i >> 6, k = i & 63;
    wL[k * 132 + jl] = W[(size_t)(j0 + jl) * 64 + k];
  }
  __syncthreads();
  int j = tid & 127, th = tid >> 7;
  float acc[8];
#pragma unroll
  for (int t = 0; t < 8; t++) acc[t] = 0.f;
#pragma unroll
  for (int k4 = 0; k4 < 16; k4++){
    int k = k4 * 4;
    float w0 = wL[k * 132 + j];
    float w1 = wL[(k + 1) * 132 + j];
    float w2 = wL[(k + 2) * 132 + j];
    float w3 = wL[(k + 3) * 132 + j];
#pragma unroll
    for (int t = 0; t < 8; t++){
      float4 lv = *(const float4*)&ln[(th * 8 + t) * 64 + k];
      acc[t] = fmaf(w0, lv.x, fmaf(w1, lv.y, fmaf(w2, lv.z, fmaf(w3, lv.w, acc[t]))));
    }
  }
  int J = j0 + j;
#pragma unroll
  for (int t = 0; t < 8; t++){
    size_t tg = t0 + th * 8 + t;
    if (J < 128) XC[tg * 128 + J] = acc[t];
    else         Z[tg * 128 + J - 128] = acc[t];
  }
}

// ---------------- causal depthwise conv(4) + bias + silu ----------------
__global__ void k_dwconv(const float* __restrict__ XC, const float* __restrict__ cw,
                         const float* __restrict__ cb, float* __restrict__ U){
  int idx = blockIdx.x * 256 + threadIdx.x; // 4*4096*128
  int n = idx & 127;
  int l = (idx >> 7) & 4095;
  float4 wv = *(const float4*)(cw + n * 4);
  float a = cb[n];
  a = fmaf(wv.w, XC[idx], a);
  if (l >= 1) a = fmaf(wv.z, XC[idx - 128], a);
  if (l >= 2) a = fmaf(wv.y, XC[idx - 256], a);
  if (l >= 3) a = fmaf(wv.x, XC[idx - 384], a);
  U[idx] = a * sigmoidf_(a);
}

// ---------------- x_proj: (16k,128) @ (128,36)^T ----------------
__global__ __launch_bounds__(256) void k_xproj(const float* __restrict__ U,
                                               const float* __restrict__ XW,
                                               float* __restrict__ DBL){
  __shared__ float xp[128 * 36]; // [k][j]
  int tid = threadIdx.x;
  for (int i = tid; i < 4608; i += 256){
    int k = i / 36, j = i - k * 36;
    xp[i] = XW[j * 128 + k];
  }
  __syncthreads();
  int wv = tid >> 6, j = tid & 63;
  size_t tg = (size_t)blockIdx.x * 4 + wv;
  if (j < 36){
    float acc = 0.f;
    const float4* up = (const float4*)(U + tg * 128);
#pragma unroll
    for (int k4 = 0; k4 < 32; k4++){
      float4 u = up[k4];
      const float* x0 = &xp[(k4 * 4) * 36 + j];
      acc = fmaf(u.x, x0[0],   acc);
      acc = fmaf(u.y, x0[36],  acc);
      acc = fmaf(u.z, x0[72],  acc);
      acc = fmaf(u.w, x0[108], acc);
    }
    DBL[tg * 36 + j] = acc;
  }
}

// ---------------- dt = softplus(dtr @ dt_w^T + dt_b) ----------------
__global__ void k_dt(const float* __restrict__ DBL, const float* __restrict__ DW,
                     const float* __restrict__ DB, float* __restrict__ DT){
  int idx = blockIdx.x * 256 + threadIdx.x; // 4*4096*128
  int n = idx & 127;
  size_t tg = (size_t)(idx >> 7);
  float4 d = *(const float4*)(DBL + tg * 36);
  float4 wv = *(const float4*)(DW + n * 4);
  float x = DB[n];
  x = fmaf(wv.x, d.x, x); x = fmaf(wv.y, d.y, x); x = fmaf(wv.z, d.z, x); x = fmaf(wv.w, d.w, x);
  DT[idx] = fmaxf(x, 0.f) + log1pf(__expf(-fabsf(x)));
}

// ================= chunked parallel scan =================
// Phase A. grid 4096: bid = ((m*4+b)*64+c)*8 + cg. block 256 = 16 ch x 16 s.
__global__ __launch_bounds__(256) void k_scanA(
    const float* __restrict__ DT0, const float* __restrict__ DBL0, const float* __restrict__ U0,
    const float* __restrict__ AL0,
    const float* __restrict__ DT1, const float* __restrict__ DBL1, const float* __restrict__ U1,
    const float* __restrict__ AL1,
    float* __restrict__ HF, float* __restrict__ AP)
{
  __shared__ float sdt[16*68], su[16*68], sB[16*68];
  int bid = blockIdx.x;
  int cg = bid & 7;
  int c  = (bid >> 3) & 63;
  int b  = (bid >> 9) & 3;
  int m  = bid >> 11;
  const float* DTp  = m ? DT1  : DT0;
  const float* DBLp = m ? DBL1 : DBL0;
  const float* Up   = m ? U1   : U0;
  const float* ALp  = m ? AL1  : AL0;
  int tid = threadIdx.x;
  int s = tid & 15;
  int chl = tid >> 4;
  int n = cg * 16 + chl;
  size_t base = (size_t)b * 4096 + c * 64;
  for (int i = tid; i < 1024; i += 256){
    int ch = i & 15, l = i >> 4;
    size_t off = (base + l) * 128 + cg * 16 + ch;
    sdt[ch * 68 + l] = DTp[off];
    su[ch * 68 + l]  = Up[off];
    sB[ch * 68 + l]  = DBLp[(base + l) * 36 + 4 + ch];
  }
  float A1 = -__expf(ALp[n * 16 + s]);
  __syncthreads();
  float h = 0.f, ap = 1.f;
#pragma unroll
  for (int l4 = 0; l4 < 16; l4++){
    float4 dtv = *(const float4*)&sdt[chl * 68 + l4 * 4];
    float4 uv  = *(const float4*)&su[chl * 68 + l4 * 4];
    float4 Bv  = *(const float4*)&sB[s * 68 + l4 * 4];
#pragma unroll
    for (int j = 0; j < 4; j++){
      float dt = (&dtv.x)[j];
      float a = __expf(dt * A1);
      h = fmaf(a, h, dt * (&Bv.x)[j] * (&uv.x)[j]);
      ap *= a;
    }
  }
  size_t o = (size_t)(bid >> 3) * 2048 + n * 16 + s;
  HF[o] = h;
  AP[o] = ap;
}

// Phase B. grid 64 x 256 = 16384 recurrences; 64 chunks each.
__global__ __launch_bounds__(256) void k_scanB(
    const float* __restrict__ HF, const float* __restrict__ AP, float* __restrict__ HIN)
{
  int r = blockIdx.x * 256 + threadIdx.x;
  int q = r >> 11;        // (m*4+b)
  int p = r & 2047;       // n*16+s
  float h = 0.f;
  for (int c = 0; c < 64; c++){
    size_t o = (size_t)(q * 64 + c) * 2048 + p;
    HIN[o] = h;
    h = fmaf(AP[o], h, HF[o]);
  }
}

// Phase C. same decode as A; seeded scan + y output.
__global__ __launch_bounds__(256) void k_scanC(
    const float* __restrict__ DT0, const float* __restrict__ DBL0, const float* __restrict__ U0,
    const float* __restrict__ Z0, const float* __restrict__ AL0, const float* __restrict__ D0,
    float* __restrict__ Y0,
    const float* __restrict__ DT1, const float* __restrict__ DBL1, const float* __restrict__ U1,
    const float* __restrict__ Z1, const float* __restrict__ AL1, const float* __restrict__ D1,
    float* __restrict__ Y1,
    const float* __restrict__ HIN)
{
  __shared__ float sdt[16*68], su[16*68], sz[16*68], sB[16*68], sC[16*68], sy[16*68];
  int bid = blockIdx.x;
  int cg = bid & 7;
  int c  = (bid >> 3) & 63;
  int b  = (bid >> 9) & 3;
  int m  = bid >> 11;
  const float* DTp  = m ? DT1  : DT0;
  const float* DBLp = m ? DBL1 : DBL0;
  const float* Up   = m ? U1   : U0;
  const float* Zp   = m ? Z1   : Z0;
  const float* ALp  = m ? AL1  : AL0;
  const float* Dp   = m ? D1   : D0;
  float*       Yp   = m ? Y1   : Y0;
  int tid = threadIdx.x;
  int s = tid & 15;
  int chl = tid >> 4;
  int n = cg * 16 + chl;
  size_t base = (size_t)b * 4096 + c * 64;
  for (int i = tid; i < 1024; i += 256){
    int ch = i & 15, l = i >> 4;
    size_t off = (base + l) * 128 + cg * 16 + ch;
    sdt[ch * 68 + l] = DTp[off];
    su[ch * 68 + l]  = Up[off];
    sz[ch * 68 + l]  = Zp[off];
    size_t ob = (base + l) * 36;
    sB[ch * 68 + l] = DBLp[ob + 4 + ch];
    sC[ch * 68 + l] = DBLp[ob + 20 + ch];
  }
  float A1 = -__expf(ALp[n * 16 + s]);
  float Dn = Dp[n];
  float h = HIN[(size_t)(bid >> 3) * 2048 + n * 16 + s];
  __syncthreads();
#pragma unroll
  for (int l4 = 0; l4 < 16; l4++){
    float4 dtv = *(const float4*)&sdt[chl * 68 + l4 * 4];
    float4 uv  = *(const float4*)&su[chl * 68 + l4 * 4];
    float4 Bv  = *(const float4*)&sB[s * 68 + l4 * 4];
    float4 Cv  = *(const float4*)&sC[s * 68 + l4 * 4];
#pragma unroll
    for (int j = 0; j < 4; j++){
      float dt = (&dtv.x)[j];
      float a = __expf(dt * A1);
      h = fmaf(a, h, dt * (&Bv.x)[j] * (&uv.x)[j]);
      float p = h * (&Cv.x)[j];
      p += __shfl_xor(p, 1);
      p += __shfl_xor(p, 2);
      p += __shfl_xor(p, 4);
      p += __shfl_xor(p, 8);
      if (s == 0){
        float y = p + (&uv.x)[j] * Dn;
        float zv = sz[chl * 68 + l4 * 4 + j];
        y = y * (zv * sigmoidf_(zv));
        sy[chl * 68 + l4 * 4 + j] = y;
      }
    }
  }
  __syncthreads();
  for (int i = tid; i < 1024; i += 256){
    int ch = i & 15, l = i >> 4;
    Yp[(base + l) * 128 + cg * 16 + ch] = sy[ch * 68 + l];
  }
}

// ---------------- out_proj: (16k,128) @ (128,64)^T ----------------
__global__ __launch_bounds__(256) void k_outproj(const float* __restrict__ Y,
                                                 const float* __restrict__ W,
                                                 float* __restrict__ OUT){
  __shared__ float yl[16 * 128];
  __shared__ float wT[128 * 65];
  int tid = threadIdx.x;
  size_t t0 = (size_t)blockIdx.x * 16;
  for (int i = tid; i < 2048; i += 256) yl[i] = Y[t0 * 128 + i];
  for (int i = tid; i < 8192; i += 256){
    int k = i & 127, j = i >> 7;
    wT[k * 65 + j] = W[j * 128 + k];
  }
  __syncthreads();
  int j = tid & 63;
  int tg = tid >> 6;
  float acc[4] = {0.f, 0.f, 0.f, 0.f};
  for (int k = 0; k < 128; k += 4){
    float w0 = wT[k * 65 + j], w1 = wT[(k+1) * 65 + j];
    float w2 = wT[(k+2) * 65 + j], w3 = wT[(k+3) * 65 + j];
#pragma unroll
    for (int t = 0; t < 4; t++){
      float4 yv = *(const float4*)&yl[(tg * 4 + t) * 128 + k];
      acc[t] = fmaf(w0, yv.x, fmaf(w1, yv.y, fmaf(w2, yv.z, fmaf(w3, yv.w, acc[t]))));
    }
  }
#pragma unroll
  for (int t = 0; t < 4; t++)
    OUT[(t0 + tg * 4 + t) * 64 + j] = acc[t];
}

// ---------------- softmax over L: partial pass ----------------
__global__ void k_smA(const float* __restrict__ G, float* __restrict__ P){
  int bid = blockIdx.x; // 64 = b(4) x lc(16)
  int b = bid >> 4, lc = bid & 15;
  int tid = threadIdx.x;
  int j = tid & 63, part = tid >> 6;
  size_t base = (size_t)b * 4096 + lc * 256;
  float mx = -3.4e38f;
  for (int i = 0; i < 64; i++){
    int l = part + i * 4;
    mx = fmaxf(mx, G[(base + l) * 64 + j]);
  }
  float sm = 0.f;
  for (int i = 0; i < 64; i++){
    int l = part + i * 4;
    sm += __expf(G[(base + l) * 64 + j] - mx);
  }
  __shared__ float sM[256], sS[256];
  sM[tid] = mx; sS[tid] = sm;
  __syncthreads();
  if (tid < 64){
    float M = sM[tid], S = sS[tid];
    for (int p = 1; p < 4; p++){
      float m2 = sM[p * 64 + tid], s2 = sS[p * 64 + tid];
      float Mn = fmaxf(M, m2);
      S = S * __expf(M - Mn) + s2 * __expf(m2 - Mn);
      M = Mn;
    }
    P[(bid * 64 + tid) * 2] = M;
    P[(bid * 64 + tid) * 2 + 1] = S;
  }
}

__global__ void k_smB(const float* __restrict__ P, float* __restrict__ F){
  int tid = threadIdx.x; // 256 = b(4) x j(64)
  int b = tid >> 6, j = tid & 63;
  float M = -3.4e38f, S = 0.f;
  for (int lc = 0; lc < 16; lc++){
    int idx = ((b * 16 + lc) * 64 + j) * 2;
    float m2 = P[idx], s2 = P[idx + 1];
    float Mn = fmaxf(M, m2);
    S = S * __expf(M - Mn) + s2 * __expf(m2 - Mn);
    M = Mn;
  }
  F[(b * 64 + j) * 2] = M;
  F[(b * 64 + j) * 2 + 1] = S;
}

// ---------------- combine + transpose to (b,c,64,64) ----------------
__global__ void k_combine(const float* __restrict__ T, const float* __restrict__ MAIN,
                          const float* __restrict__ G, const float* __restrict__ F,
                          float* __restrict__ FEAT){
  int bid = blockIdx.x; // 256 = b(4) x row(64)
  int b = bid >> 6, row = bid & 63;
  int tid = threadIdx.x;
  int j = tid & 63, ls = tid >> 6;
  __shared__ float tile[64 * 65];
  float M = F[(b * 64 + j) * 2], invS = 1.f / F[(b * 64 + j) * 2 + 1];
  size_t lbase = (size_t)b * 4096 + row * 64;
  for (int i = 0; i < 16; i++){
    int col = ls + i * 4;
    size_t off = (lbase + col) * 64 + j;
    float g = __expf(G[off] - M) * invS;
    tile[col * 65 + j] = T[off] + g * MAIN[off];
  }
  __syncthreads();
  int colw = tid & 63, jr = tid >> 6;
  for (int jj = jr; jj < 64; jj += 4)
    FEAT[(((size_t)b * 64 + jj) * 64 + row) * 64 + colw] = tile[colw * 65 + jj];
}

// ---------------- bilinear upsample 64->128 ----------------
__global__ void k_up(const float* __restrict__ FEAT, float* __restrict__ UP){
  size_t idx = (size_t)blockIdx.x * 256 + threadIdx.x; // 4*64*128*128
  int x = idx & 127;
  int y = (idx >> 7) & 127;
  size_t bc = idx >> 14;
  float ay = 0.5f * y - 0.25f;
  float ax = 0.5f * x - 0.25f;
  int fy = (int)floorf(ay); float wy = ay - fy;
  int fx = (int)floorf(ax); float wx = ax - fx;
  int y0 = fy < 0 ? 0 : fy, y1 = fy + 1 > 63 ? 63 : fy + 1;
  int x0 = fx < 0 ? 0 : fx, x1 = fx + 1 > 63 ? 63 : fx + 1;
  const float* p = FEAT + bc * 4096;
  float v = (1.f - wy) * ((1.f - wx) * p[y0 * 64 + x0] + wx * p[y0 * 64 + x1])
          +        wy  * ((1.f - wx) * p[y1 * 64 + x0] + wx * p[y1 * 64 + x1]);
  UP[idx] = v;
}

// ---------------- host launcher ----------------
extern "C" void kernel_launch(void* const* d_in, const int* in_sizes, int n_in,
                              void* d_out, int out_size, void* d_ws, size_t ws_size,
                              hipStream_t stream) {
  // workspace layout (float offsets)
  const size_t C1 = 0, XR = 4194304;
  const size_t MB0 = 0, MB1 = 10027008;
  const size_t O_LN = 0, O_XC = 1048576, O_Z = 3145728, O_U = 5242880,
               O_DT = 7340032, O_DBL = 9437184; // block size 10027008
  const size_t TOK = 20054016, OUT0 = 21102592, OUT1 = 22151168;
  const size_t SMP = 23199744, SMF = 23207936, FEAT = 23208448;
  const size_t UP = 0, CT = 4194304;
  const size_t TOTAL = 24257024;
  if (ws_size < TOTAL * 4) return;

  float* ws = (float*)d_ws;
  const float* X   = (const float*)d_in[0];
  const float* CB1 = (const float*)d_in[1];
  const float* CB2 = (const float*)d_in[2];
  const float* SW1 = (const float*)d_in[3];
  const float* SW2 = (const float*)d_in[4];
  const float* LNW[2] = { (const float*)d_in[5], (const float*)d_in[7] };
  const float* LNB[2] = { (const float*)d_in[6], (const float*)d_in[8] };
  const float *INW[2], *CW[2], *CBb[2], *XPW[2], *DTW[2], *DTB[2], *AL[2], *DD[2], *OW[2];
  for (int m = 0; m < 2; m++){
    int p = 9 + m * 9;
    INW[m] = (const float*)d_in[p + 0];
    CW[m]  = (const float*)d_in[p + 1];
    CBb[m] = (const float*)d_in[p + 2];
    XPW[m] = (const float*)d_in[p + 3];
    DTW[m] = (const float*)d_in[p + 4];
    DTB[m] = (const float*)d_in[p + 5];
    AL[m]  = (const float*)d_in[p + 6];
    DD[m]  = (const float*)d_in[p + 7];
    OW[m]  = (const float*)d_in[p + 8];
  }
  size_t mb[2] = { MB0, MB1 };

  // phase 1: conv block + tokenize
  k_conv<<<dim3(8, 8, 16), 256, 0, stream>>>(X, CB1, nullptr, ws + C1, 1);
  k_conv<<<dim3(8, 8, 16), 256, 0, stream>>>(ws + C1, CB2, X, ws + XR, 0);
  k_tok<<<4096, 256, 0, stream>>>(ws + XR, ws + TOK);

  // phase 2: per-mamba pre-scan
  for (int m = 0; m < 2; m++){
    size_t B = mb[m];
    k_ln<<<4096, 256, 0, stream>>>(ws + TOK, LNW[m], LNB[m], ws + B + O_LN);
    k_inproj<<<dim3(1024, 2), 256, 0, stream>>>(ws + B + O_LN, INW[m], ws + B + O_XC, ws + B + O_Z);
    k_dwconv<<<8192, 256, 0, stream>>>(ws + B + O_XC, CW[m], CBb[m], ws + B + O_U);
    k_xproj<<<4096, 256, 0, stream>>>(ws + B + O_U, XPW[m], ws + B + O_DBL);
    k_dt<<<8192, 256, 0, stream>>>(ws + B + O_DBL, DTW[m], DTB[m], ws + B + O_DT);
  }

  float* HF  = ws + MB0 + O_XC;
  float* AP  = ws + MB0 + O_XC + 1048576;
  float* HIN = ws + MB0 + O_LN;

  k_scanA<<<4096, 256, 0, stream>>>(
      ws + MB0 + O_DT, ws + MB0 + O_DBL, ws + MB0 + O_U, AL[0],
      ws + MB1 + O_DT, ws + MB1 + O_DBL, ws + MB1 + O_U, AL[1],
      HF, AP);
  k_scanB<<<64, 256, 0, stream>>>(HF, AP, HIN);
  k_scanC<<<4096, 256, 0, stream>>>(
      ws + MB0 + O_DT, ws + MB0 + O_DBL, ws + MB0 + O_U, ws + MB0 + O_Z, AL[0], DD[0], ws + MB0 + O_XC,
      ws + MB1 + O_DT, ws + MB1 + O_DBL, ws + MB1 + O_U, ws + MB1 + O_Z, AL[1], DD[1], ws + MB1 + O_XC,
      HIN);

  k_outproj<<<1024, 256, 0, stream>>>(ws + MB0 + O_XC, OW[0], ws + OUT0);
  k_outproj<<<1024, 256, 0, stream>>>(ws + MB1 + O_XC, OW[1], ws + OUT1);

  // gate softmax + combine + transpose
  k_smA<<<64, 256, 0, stream>>>(ws + OUT1, ws + SMP);
  k_smB<<<1, 256, 0, stream>>>(ws + SMP, ws + SMF);
  k_combine<<<256, 256, 0, stream>>>(ws + TOK, ws + OUT0, ws + OUT1, ws + SMF, ws + FEAT);

  // phase 3: upsample + final conv block
  k_up<<<16384, 256, 0, stream>>>(ws + FEAT, ws + UP);
  k_conv<<<dim3(8, 8, 16), 256, 0, stream>>>(ws + UP, SW1, nullptr, ws + CT, 1);
  k_conv<<<dim3(8, 8, 16), 256, 0, stream>>>(ws + CT, SW2, nullptr, (float*)d_out, 0);
}

// Round 5
// 677.523 us; speedup vs baseline: 3.6597x; 1.7550x over previous
//
#include <hip/hip_runtime.h>

typedef unsigned int u32;
typedef unsigned short u16;
typedef __attribute__((ext_vector_type(8))) short short8;
typedef __attribute__((ext_vector_type(4))) float f32x4;

__device__ __forceinline__ float sigmoidf_(float x){
  return 1.f / (1.f + __expf(-x));
}
__device__ __forceinline__ u16 f2bf(float f){
  union { float f; u32 i; } v; v.f = f;
  u32 r = v.i + 0x7fffu + ((v.i >> 16) & 1u);
  return (u16)(r >> 16);
}
__device__ __forceinline__ float bf2f(u32 u){
  union { float f; u32 i; } v; v.i = (u & 0xffffu) << 16; return v.f;
}

// ---------------- zero fill (border init for padded bf16 buffers) ----------------
__global__ void k_zero(float4* __restrict__ p, int n4){
  int i = blockIdx.x * 256 + threadIdx.x;
  if (i < n4) p[i] = make_float4(0.f, 0.f, 0.f, 0.f);
}

// ---------------- prep: NCHW fp32 -> padded NHWC bf16 hi/lo ----------------
// grid (130, 4): one padded row per block. out dims [4][130][130][64].
__global__ __launch_bounds__(256) void k_prep(const float* __restrict__ src,
                                              u16* __restrict__ PH, u16* __restrict__ PL){
  __shared__ float ld[64 * 128];
  int yp = blockIdx.x;          // padded row 0..129
  int b  = blockIdx.y;
  int ys = yp - 1;
  int tid = threadIdx.x;
  if ((u32)ys < 128u){
    for (int i = tid; i < 8192; i += 256){
      int c = i >> 7, x = i & 127;
      ld[i] = src[((size_t)(b * 64 + c) * 128 + ys) * 128 + x];
    }
  }
  __syncthreads();
  for (int i = tid; i < 130 * 64; i += 256){
    int xp = i >> 6, c = i & 63;
    float v = 0.f;
    if ((u32)ys < 128u && (u32)(xp - 1) < 128u) v = ld[c * 128 + (xp - 1)];
    u16 h = f2bf(v);
    u16 l = f2bf(v - bf2f(h));
    size_t o = (((size_t)b * 130 + yp) * 130 + xp) * 64 + c;
    PH[o] = h; PL[o] = l;
  }
}

// ---------------- weight swizzle: [oc][ic][3][3] fp32 -> B-frag order bf16 hi/lo ----
// layout: [t 9][kc 2][nt 4][lane 64][j 8];  B[k=ic][n=oc], k = kc*32 + quad*8 + j,
// n = nt*16 + (lane&15).
__global__ void k_wswz(const float* __restrict__ w, u16* __restrict__ WH, u16* __restrict__ WL){
  int idx = blockIdx.x * 256 + threadIdx.x;
  if (idx >= 36864) return;
  int j    = idx & 7;
  int lane = (idx >> 3) & 63;
  int nt   = (idx >> 9) & 3;
  int kc   = (idx >> 11) & 1;
  int t    = idx >> 12;           // 0..8
  int ic = kc * 32 + ((lane >> 4) & 3) * 8 + j;
  int oc = nt * 16 + (lane & 15);
  float v = w[(oc * 64 + ic) * 9 + t];
  u16 h = f2bf(v);
  u16 l = f2bf(v - bf2f(h));
  WH[idx] = h; WL[idx] = l;
}

// ---------------- MFMA conv3x3 64->64 ----------------
// grid (8,8,4): 16x16 px tile per block, all 64 oc. block 256 = 4 waves.
// Wave w: rows w*4..w*4+3, each row = one m-tile (16 cols).
// mode 0: out = relu -> padded NHWC bf16 h/l (OBH/OBL).
// mode 1: out = fp32 NCHW (+resid) (OUTF).
__global__ __launch_bounds__(256) void k_convm(
    const u16* __restrict__ PH, const u16* __restrict__ PL,
    const u16* __restrict__ WH, const u16* __restrict__ WL,
    const float* __restrict__ resid,
    u16* __restrict__ OBH, u16* __restrict__ OBL,
    float* __restrict__ OUTF, int mode)
{
  __shared__ __align__(16) u32 smem[10368];    // 41.5 KB, unioned
  u16* Ah_s = (u16*)smem;                      // 10368 elems
  u16* Al_s = Ah_s + 10368;
  int tid = threadIdx.x;
  int lane = tid & 63, w = tid >> 6;
  int quad = lane >> 4, lcol = lane & 15;
  int b = blockIdx.z, y0 = blockIdx.y * 16, x0 = blockIdx.x * 16;

  f32x4 acc[4][4];
#pragma unroll
  for (int mt = 0; mt < 4; mt++)
#pragma unroll
    for (int nt = 0; nt < 4; nt++)
      acc[mt][nt] = (f32x4){0.f, 0.f, 0.f, 0.f};

  for (int kc = 0; kc < 2; kc++){
    __syncthreads();
    // stage A tile: 18x18 px halo x 32 ic, hi+lo
    for (int i = tid; i < 1296; i += 256){
      int q = i & 3;
      int rc = i >> 2;
      int r = rc / 18, c = rc - r * 18;
      size_t so = (((size_t)b * 130 + y0 + r) * 130 + (x0 + c)) * 64 + kc * 32 + q * 8;
      int de = (r * 18 + c) * 32 + q * 8;
      *(uint4*)(Ah_s + de) = *(const uint4*)(PH + so);
      *(uint4*)(Al_s + de) = *(const uint4*)(PL + so);
    }
    __syncthreads();
    // preload B frags for t=0
    short8 bh[2][4], bl[2][4];
#pragma unroll
    for (int nt = 0; nt < 4; nt++){
      int o = (kc * 4 + nt) * 512 + lane * 8;
      bh[0][nt] = *(const short8*)(WH + o);
      bl[0][nt] = *(const short8*)(WL + o);
    }
    for (int t = 0; t < 9; t++){
      int cur = t & 1, nxt = cur ^ 1;
      if (t < 8){
#pragma unroll
        for (int nt = 0; nt < 4; nt++){
          int o = (((t + 1) * 2 + kc) * 4 + nt) * 512 + lane * 8;
          bh[nxt][nt] = *(const short8*)(WH + o);
          bl[nxt][nt] = *(const short8*)(WL + o);
        }
      }
      int dy = t / 3, dx = t - dy * 3;   // 0..2; halo +1 cancels the -1
      short8 ah[4], al[4];
#pragma unroll
      for (int mt = 0; mt < 4; mt++){
        int e = ((w * 4 + mt + dy) * 18 + (lcol + dx)) * 32 + quad * 8;
        ah[mt] = *(const short8*)(Ah_s + e);
        al[mt] = *(const short8*)(Al_s + e);
      }
#pragma unroll
      for (int mt = 0; mt < 4; mt++)
#pragma unroll
        for (int nt = 0; nt < 4; nt++){
          acc[mt][nt] = __builtin_amdgcn_mfma_f32_16x16x32_bf16(ah[mt], bh[cur][nt], acc[mt][nt], 0, 0, 0);
          acc[mt][nt] = __builtin_amdgcn_mfma_f32_16x16x32_bf16(ah[mt], bl[cur][nt], acc[mt][nt], 0, 0, 0);
          acc[mt][nt] = __builtin_amdgcn_mfma_f32_16x16x32_bf16(al[mt], bh[cur][nt], acc[mt][nt], 0, 0, 0);
        }
    }
  }

  // epilogue. C-frag: col(lane&15)=oc-in-tile, row(quad*4+reg)=px-col.
  if (mode == 0){
    u32* epi = smem;   // [row8 8][c_loc 16][oc 66]
    for (int half = 0; half < 2; half++){
      __syncthreads();
#pragma unroll
      for (int mtl = 0; mtl < 2; mtl++){
        int mt = half * 2 + mtl;
#pragma unroll
        for (int nt = 0; nt < 4; nt++){
#pragma unroll
          for (int reg = 0; reg < 4; reg++){
            float v = fmaxf(acc[mt][nt][reg], 0.f);
            u32 h = f2bf(v);
            u32 l = f2bf(v - bf2f(h));
            int c_loc = quad * 4 + reg;
            int oc = nt * 16 + lcol;
            epi[((w * 2 + mtl) * 16 + c_loc) * 66 + oc] = h | (l << 16);
          }
        }
      }
      __syncthreads();
      for (int i = tid; i < 8192; i += 256){
        int px = i >> 6, oc = i & 63;
        int row8 = px >> 4, c_loc = px & 15;
        int r_loc = (row8 >> 1) * 4 + half * 2 + (row8 & 1);
        u32 pk = epi[(row8 * 16 + c_loc) * 66 + oc];
        size_t o = (((size_t)b * 130 + y0 + r_loc + 1) * 130 + (x0 + c_loc + 1)) * 64 + oc;
        OBH[o] = (u16)pk;
        OBL[o] = (u16)(pk >> 16);
      }
    }
  } else {
    float* epi = (float*)smem;  // [oc 64][px 130]
    for (int half = 0; half < 2; half++){
      __syncthreads();
#pragma unroll
      for (int mtl = 0; mtl < 2; mtl++){
        int mt = half * 2 + mtl;
#pragma unroll
        for (int nt = 0; nt < 4; nt++){
#pragma unroll
          for (int reg = 0; reg < 4; reg++){
            int px = (w * 2 + mtl) * 16 + quad * 4 + reg;
            int oc = nt * 16 + lcol;
            epi[oc * 130 + px] = acc[mt][nt][reg];
          }
        }
      }
      __syncthreads();
      for (int i = tid; i < 8192; i += 256){
        int oc = i >> 7, px = i & 127;
        int row8 = px >> 4, c = px & 15;
        int r_loc = (row8 >> 1) * 4 + half * 2 + (row8 & 1);
        size_t o = (((size_t)b * 64 + oc) * 128 + y0 + r_loc) * 128 + x0 + c;
        float v = epi[oc * 130 + px];
        if (resid) v += resid[o];
        OUTF[o] = v;
      }
    }
  }
}

// ---------------- 2x2 avg downsample + NCHW->(b,l,c) tokenize ----------------
__global__ void k_tok(const float* __restrict__ xr, float* __restrict__ T){
  int idx = blockIdx.x * 256 + threadIdx.x; // 4*4096*64
  int c = idx & 63;
  int l = (idx >> 6) & 4095;
  int b = idx >> 18;
  int r = l >> 6, cl = l & 63;
  const float* p = xr + (((size_t)(b * 64 + c) * 128 + 2 * r) * 128 + 2 * cl);
  T[idx] = 0.25f * (p[0] + p[1] + p[128] + p[129]);
}

// ---------------- layernorm over c=64 ----------------
__global__ void k_ln(const float* __restrict__ T, const float* __restrict__ w,
                     const float* __restrict__ b, float* __restrict__ out){
  int row = blockIdx.x * 4 + (threadIdx.x >> 6);
  int c = threadIdx.x & 63;
  float v = T[row * 64 + c];
  float s = v;
  for (int m = 32; m; m >>= 1) s += __shfl_xor(s, m);
  float mu = s * (1.f / 64.f);
  float d = v - mu;
  float q = d * d;
  for (int m = 32; m; m >>= 1) q += __shfl_xor(q, m);
  float var = q * (1.f / 64.f);
  out[row * 64 + c] = d * rsqrtf(var + 1e-5f) * w[c] + b[c];
}

// ---------------- in_proj ----------------
__global__ __launch_bounds__(256) void k_inproj(const float* __restrict__ LN,
                                                const float* __restrict__ W,
                                                float* __restrict__ XC, float* __restrict__ Z){
  __shared__ float wL[64 * 132];
  __shared__ float ln[16 * 64];
  int tid = threadIdx.x;
  int t0 = blockIdx.x * 16;
  int j0 = blockIdx.y * 128;
  for (int i = tid; i < 1024; i += 256) ln[i] = LN[(size_t)t0 * 64 + i];
  for (int i = tid; i < 8192; i += 256){
    int jl = i >> 6, k = i & 63;
    wL[k * 132 + jl] = W[(size_t)(j0 + jl) * 64 + k];
  }
  __syncthreads();
  int j = tid & 127, th = tid >> 7;
  float acc[8];
#pragma unroll
  for (int t = 0; t < 8; t++) acc[t] = 0.f;
#pragma unroll
  for (int k4 = 0; k4 < 16; k4++){
    int k = k4 * 4;
    float w0 = wL[k * 132 + j];
    float w1 = wL[(k + 1) * 132 + j];
    float w2 = wL[(k + 2) * 132 + j];
    float w3 = wL[(k + 3) * 132 + j];
#pragma unroll
    for (int t = 0; t < 8; t++){
      float4 lv = *(const float4*)&ln[(th * 8 + t) * 64 + k];
      acc[t] = fmaf(w0, lv.x, fmaf(w1, lv.y, fmaf(w2, lv.z, fmaf(w3, lv.w, acc[t]))));
    }
  }
  int J = j0 + j;
#pragma unroll
  for (int t = 0; t < 8; t++){
    size_t tg = t0 + th * 8 + t;
    if (J < 128) XC[tg * 128 + J] = acc[t];
    else         Z[tg * 128 + J - 128] = acc[t];
  }
}

// ---------------- causal depthwise conv(4) + bias + silu ----------------
__global__ void k_dwconv(const float* __restrict__ XC, const float* __restrict__ cw,
                         const float* __restrict__ cb, float* __restrict__ U){
  int idx = blockIdx.x * 256 + threadIdx.x; // 4*4096*128
  int n = idx & 127;
  int l = (idx >> 7) & 4095;
  float4 wv = *(const float4*)(cw + n * 4);
  float a = cb[n];
  a = fmaf(wv.w, XC[idx], a);
  if (l >= 1) a = fmaf(wv.z, XC[idx - 128], a);
  if (l >= 2) a = fmaf(wv.y, XC[idx - 256], a);
  if (l >= 3) a = fmaf(wv.x, XC[idx - 384], a);
  U[idx] = a * sigmoidf_(a);
}

// ---------------- x_proj ----------------
__global__ __launch_bounds__(256) void k_xproj(const float* __restrict__ U,
                                               const float* __restrict__ XW,
                                               float* __restrict__ DBL){
  __shared__ float xp[128 * 36]; // [k][j]
  int tid = threadIdx.x;
  for (int i = tid; i < 4608; i += 256){
    int k = i / 36, j = i - k * 36;
    xp[i] = XW[j * 128 + k];
  }
  __syncthreads();
  int wv = tid >> 6, j = tid & 63;
  size_t tg = (size_t)blockIdx.x * 4 + wv;
  if (j < 36){
    float acc = 0.f;
    const float4* up = (const float4*)(U + tg * 128);
#pragma unroll
    for (int k4 = 0; k4 < 32; k4++){
      float4 u = up[k4];
      const float* x0 = &xp[(k4 * 4) * 36 + j];
      acc = fmaf(u.x, x0[0],   acc);
      acc = fmaf(u.y, x0[36],  acc);
      acc = fmaf(u.z, x0[72],  acc);
      acc = fmaf(u.w, x0[108], acc);
    }
    DBL[tg * 36 + j] = acc;
  }
}

// ---------------- dt = softplus ----------------
__global__ void k_dt(const float* __restrict__ DBL, const float* __restrict__ DW,
                     const float* __restrict__ DB, float* __restrict__ DT){
  int idx = blockIdx.x * 256 + threadIdx.x; // 4*4096*128
  int n = idx & 127;
  size_t tg = (size_t)(idx >> 7);
  float4 d = *(const float4*)(DBL + tg * 36);
  float4 wv = *(const float4*)(DW + n * 4);
  float x = DB[n];
  x = fmaf(wv.x, d.x, x); x = fmaf(wv.y, d.y, x); x = fmaf(wv.z, d.z, x); x = fmaf(wv.w, d.w, x);
  DT[idx] = fmaxf(x, 0.f) + log1pf(__expf(-fabsf(x)));
}

// ================= chunked parallel scan =================
__global__ __launch_bounds__(256) void k_scanA(
    const float* __restrict__ DT0, const float* __restrict__ DBL0, const float* __restrict__ U0,
    const float* __restrict__ AL0,
    const float* __restrict__ DT1, const float* __restrict__ DBL1, const float* __restrict__ U1,
    const float* __restrict__ AL1,
    float* __restrict__ HF, float* __restrict__ AP)
{
  __shared__ float sdt[16*68], su[16*68], sB[16*68];
  int bid = blockIdx.x;
  int cg = bid & 7;
  int c  = (bid >> 3) & 63;
  int b  = (bid >> 9) & 3;
  int m  = bid >> 11;
  const float* DTp  = m ? DT1  : DT0;
  const float* DBLp = m ? DBL1 : DBL0;
  const float* Up   = m ? U1   : U0;
  const float* ALp  = m ? AL1  : AL0;
  int tid = threadIdx.x;
  int s = tid & 15;
  int chl = tid >> 4;
  int n = cg * 16 + chl;
  size_t base = (size_t)b * 4096 + c * 64;
  for (int i = tid; i < 1024; i += 256){
    int ch = i & 15, l = i >> 4;
    size_t off = (base + l) * 128 + cg * 16 + ch;
    sdt[ch * 68 + l] = DTp[off];
    su[ch * 68 + l]  = Up[off];
    sB[ch * 68 + l]  = DBLp[(base + l) * 36 + 4 + ch];
  }
  float A1 = -__expf(ALp[n * 16 + s]);
  __syncthreads();
  float h = 0.f, ap = 1.f;
#pragma unroll
  for (int l4 = 0; l4 < 16; l4++){
    float4 dtv = *(const float4*)&sdt[chl * 68 + l4 * 4];
    float4 uv  = *(const float4*)&su[chl * 68 + l4 * 4];
    float4 Bv  = *(const float4*)&sB[s * 68 + l4 * 4];
#pragma unroll
    for (int j = 0; j < 4; j++){
      float dt = (&dtv.x)[j];
      float a = __expf(dt * A1);
      h = fmaf(a, h, dt * (&Bv.x)[j] * (&uv.x)[j]);
      ap *= a;
    }
  }
  size_t o = (size_t)(bid >> 3) * 2048 + n * 16 + s;
  HF[o] = h;
  AP[o] = ap;
}

__global__ __launch_bounds__(256) void k_scanB(
    const float* __restrict__ HF, const float* __restrict__ AP, float* __restrict__ HIN)
{
  int r = blockIdx.x * 256 + threadIdx.x;
  int q = r >> 11;        // (m*4+b)
  int p = r & 2047;       // n*16+s
  float h = 0.f;
  for (int c = 0; c < 64; c++){
    size_t o = (size_t)(q * 64 + c) * 2048 + p;
    HIN[o] = h;
    h = fmaf(AP[o], h, HF[o]);
  }
}

__global__ __launch_bounds__(256) void k_scanC(
    const float* __restrict__ DT0, const float* __restrict__ DBL0, const float* __restrict__ U0,
    const float* __restrict__ Z0, const float* __restrict__ AL0, const float* __restrict__ D0,
    float* __restrict__ Y0,
    const float* __restrict__ DT1, const float* __restrict__ DBL1, const float* __restrict__ U1,
    const float* __restrict__ Z1, const float* __restrict__ AL1, const float* __restrict__ D1,
    float* __restrict__ Y1,
    const float* __restrict__ HIN)
{
  __shared__ float sdt[16*68], su[16*68], sz[16*68], sB[16*68], sC[16*68], sy[16*68];
  int bid = blockIdx.x;
  int cg = bid & 7;
  int c  = (bid >> 3) & 63;
  int b  = (bid >> 9) & 3;
  int m  = bid >> 11;
  const float* DTp  = m ? DT1  : DT0;
  const float* DBLp = m ? DBL1 : DBL0;
  const float* Up   = m ? U1   : U0;
  const float* Zp   = m ? Z1   : Z0;
  const float* ALp  = m ? AL1  : AL0;
  const float* Dp   = m ? D1   : D0;
  float*       Yp   = m ? Y1   : Y0;
  int tid = threadIdx.x;
  int s = tid & 15;
  int chl = tid >> 4;
  int n = cg * 16 + chl;
  size_t base = (size_t)b * 4096 + c * 64;
  for (int i = tid; i < 1024; i += 256){
    int ch = i & 15, l = i >> 4;
    size_t off = (base + l) * 128 + cg * 16 + ch;
    sdt[ch * 68 + l] = DTp[off];
    su[ch * 68 + l]  = Up[off];
    sz[ch * 68 + l]  = Zp[off];
    size_t ob = (base + l) * 36;
    sB[ch * 68 + l] = DBLp[ob + 4 + ch];
    sC[ch * 68 + l] = DBLp[ob + 20 + ch];
  }
  float A1 = -__expf(ALp[n * 16 + s]);
  float Dn = Dp[n];
  float h = HIN[(size_t)(bid >> 3) * 2048 + n * 16 + s];
  __syncthreads();
#pragma unroll
  for (int l4 = 0; l4 < 16; l4++){
    float4 dtv = *(const float4*)&sdt[chl * 68 + l4 * 4];
    float4 uv  = *(const float4*)&su[chl * 68 + l4 * 4];
    float4 Bv  = *(const float4*)&sB[s * 68 + l4 * 4];
    float4 Cv  = *(const float4*)&sC[s * 68 + l4 * 4];
#pragma unroll
    for (int j = 0; j < 4; j++){
      float dt = (&dtv.x)[j];
      float a = __expf(dt * A1);
      h = fmaf(a, h, dt * (&Bv.x)[j] * (&uv.x)[j]);
      float p = h * (&Cv.x)[j];
      p += __shfl_xor(p, 1);
      p += __shfl_xor(p, 2);
      p += __shfl_xor(p, 4);
      p += __shfl_xor(p, 8);
      if (s == 0){
        float y = p + (&uv.x)[j] * Dn;
        float zv = sz[chl * 68 + l4 * 4 + j];
        y = y * (zv * sigmoidf_(zv));
        sy[chl * 68 + l4 * 4 + j] = y;
      }
    }
  }
  __syncthreads();
  for (int i = tid; i < 1024; i += 256){
    int ch = i & 15, l = i >> 4;
    Yp[(base + l) * 128 + cg * 16 + ch] = sy[ch * 68 + l];
  }
}

// ---------------- out_proj ----------------
__global__ __launch_bounds__(256) void k_outproj(const float* __restrict__ Y,
                                                 const float* __restrict__ W,
                                                 float* __restrict__ OUT){
  __shared__ float yl[16 * 128];
  __shared__ float wT[128 * 65];
  int tid = threadIdx.x;
  size_t t0 = (size_t)blockIdx.x * 16;
  for (int i = tid; i < 2048; i += 256) yl[i] = Y[t0 * 128 + i];
  for (int i = tid; i < 8192; i += 256){
    int k = i & 127, j = i >> 7;
    wT[k * 65 + j] = W[j * 128 + k];
  }
  __syncthreads();
  int j = tid & 63;
  int tg = tid >> 6;
  float acc[4] = {0.f, 0.f, 0.f, 0.f};
  for (int k = 0; k < 128; k += 4){
    float w0 = wT[k * 65 + j], w1 = wT[(k+1) * 65 + j];
    float w2 = wT[(k+2) * 65 + j], w3 = wT[(k+3) * 65 + j];
#pragma unroll
    for (int t = 0; t < 4; t++){
      float4 yv = *(const float4*)&yl[(tg * 4 + t) * 128 + k];
      acc[t] = fmaf(w0, yv.x, fmaf(w1, yv.y, fmaf(w2, yv.z, fmaf(w3, yv.w, acc[t]))));
    }
  }
#pragma unroll
  for (int t = 0; t < 4; t++)
    OUT[(t0 + tg * 4 + t) * 64 + j] = acc[t];
}

// ---------------- softmax over L ----------------
__global__ void k_smA(const float* __restrict__ G, float* __restrict__ P){
  int bid = blockIdx.x; // 64 = b(4) x lc(16)
  int b = bid >> 4, lc = bid & 15;
  int tid = threadIdx.x;
  int j = tid & 63, part = tid >> 6;
  size_t base = (size_t)b * 4096 + lc * 256;
  float mx = -3.4e38f;
  for (int i = 0; i < 64; i++){
    int l = part + i * 4;
    mx = fmaxf(mx, G[(base + l) * 64 + j]);
  }
  float sm = 0.f;
  for (int i = 0; i < 64; i++){
    int l = part + i * 4;
    sm += __expf(G[(base + l) * 64 + j] - mx);
  }
  __shared__ float sM[256], sS[256];
  sM[tid] = mx; sS[tid] = sm;
  __syncthreads();
  if (tid < 64){
    float M = sM[tid], S = sS[tid];
    for (int p = 1; p < 4; p++){
      float m2 = sM[p * 64 + tid], s2 = sS[p * 64 + tid];
      float Mn = fmaxf(M, m2);
      S = S * __expf(M - Mn) + s2 * __expf(m2 - Mn);
      M = Mn;
    }
    P[(bid * 64 + tid) * 2] = M;
    P[(bid * 64 + tid) * 2 + 1] = S;
  }
}

__global__ void k_smB(const float* __restrict__ P, float* __restrict__ F){
  int tid = threadIdx.x; // 256 = b(4) x j(64)
  int b = tid >> 6, j = tid & 63;
  float M = -3.4e38f, S = 0.f;
  for (int lc = 0; lc < 16; lc++){
    int idx = ((b * 16 + lc) * 64 + j) * 2;
    float m2 = P[idx], s2 = P[idx + 1];
    float Mn = fmaxf(M, m2);
    S = S * __expf(M - Mn) + s2 * __expf(m2 - Mn);
    M = Mn;
  }
  F[(b * 64 + j) * 2] = M;
  F[(b * 64 + j) * 2 + 1] = S;
}

// ---------------- combine + transpose to (b,c,64,64) ----------------
__global__ void k_combine(const float* __restrict__ T, const float* __restrict__ MAIN,
                          const float* __restrict__ G, const float* __restrict__ F,
                          float* __restrict__ FEAT){
  int bid = blockIdx.x; // 256 = b(4) x row(64)
  int b = bid >> 6, row = bid & 63;
  int tid = threadIdx.x;
  int j = tid & 63, ls = tid >> 6;
  __shared__ float tile[64 * 65];
  float M = F[(b * 64 + j) * 2], invS = 1.f / F[(b * 64 + j) * 2 + 1];
  size_t lbase = (size_t)b * 4096 + row * 64;
  for (int i = 0; i < 16; i++){
    int col = ls + i * 4;
    size_t off = (lbase + col) * 64 + j;
    float g = __expf(G[off] - M) * invS;
    tile[col * 65 + j] = T[off] + g * MAIN[off];
  }
  __syncthreads();
  int colw = tid & 63, jr = tid >> 6;
  for (int jj = jr; jj < 64; jj += 4)
    FEAT[(((size_t)b * 64 + jj) * 64 + row) * 64 + colw] = tile[colw * 65 + jj];
}

// ---------------- bilinear upsample 64->128 ----------------
__global__ void k_up(const float* __restrict__ FEAT, float* __restrict__ UP){
  size_t idx = (size_t)blockIdx.x * 256 + threadIdx.x; // 4*64*128*128
  int x = idx & 127;
  int y = (idx >> 7) & 127;
  size_t bc = idx >> 14;
  float ay = 0.5f * y - 0.25f;
  float ax = 0.5f * x - 0.25f;
  int fy = (int)floorf(ay); float wy = ay - fy;
  int fx = (int)floorf(ax); float wx = ax - fx;
  int y0 = fy < 0 ? 0 : fy, y1 = fy + 1 > 63 ? 63 : fy + 1;
  int x0 = fx < 0 ? 0 : fx, x1 = fx + 1 > 63 ? 63 : fx + 1;
  const float* p = FEAT + bc * 4096;
  float v = (1.f - wy) * ((1.f - wx) * p[y0 * 64 + x0] + wx * p[y0 * 64 + x1])
          +        wy  * ((1.f - wx) * p[y1 * 64 + x0] + wx * p[y1 * 64 + x1]);
  UP[idx] = v;
}

// ---------------- host launcher ----------------
extern "C" void kernel_launch(void* const* d_in, const int* in_sizes, int n_in,
                              void* d_out, int out_size, void* d_ws, size_t ws_size,
                              hipStream_t stream) {
  // workspace layout (float offsets)
  // phase 1: PA(h,l) @0 (4,326,400), PB(h,l) @4,326,400, XR @8,652,800 (4,194,304)
  const size_t P1A = 0, P1B = 4326400, XR = 8652800;
  // phase 2: mamba blocks
  const size_t MB0 = 0, MB1 = 10027008;
  const size_t O_LN = 0, O_XC = 1048576, O_Z = 3145728, O_U = 5242880,
               O_DT = 7340032, O_DBL = 9437184;
  const size_t TOK = 20054016, OUT0 = 21102592, OUT1 = 22151168;
  const size_t SMP = 23199744, SMF = 23207936, FEAT = 23208448;
  // phase 3: UP @0 (4,194,304), PA @4,194,304, PB @8,520,704
  const size_t UPO = 0, P3A = 4194304, P3B = 8520704;
  // weight swizzle slots (rewritten per phase; mamba overwrites between)
  const size_t WA_H = 19000000, WA_L = 19018432, WB_H = 19036864, WB_L = 19055296;
  const size_t PADN = 2163200;   // elems of one padded bf16 array in float-slots
  const size_t TOTAL = 24257024;
  if (ws_size < TOTAL * 4) return;

  float* ws = (float*)d_ws;
  const float* X   = (const float*)d_in[0];
  const float* CB1 = (const float*)d_in[1];
  const float* CB2 = (const float*)d_in[2];
  const float* SW1 = (const float*)d_in[3];
  const float* SW2 = (const float*)d_in[4];
  const float* LNW[2] = { (const float*)d_in[5], (const float*)d_in[7] };
  const float* LNB[2] = { (const float*)d_in[6], (const float*)d_in[8] };
  const float *INW[2], *CW[2], *CBb[2], *XPW[2], *DTW[2], *DTB[2], *AL[2], *DD[2], *OW[2];
  for (int m = 0; m < 2; m++){
    int p = 9 + m * 9;
    INW[m] = (const float*)d_in[p + 0];
    CW[m]  = (const float*)d_in[p + 1];
    CBb[m] = (const float*)d_in[p + 2];
    XPW[m] = (const float*)d_in[p + 3];
    DTW[m] = (const float*)d_in[p + 4];
    DTB[m] = (const float*)d_in[p + 5];
    AL[m]  = (const float*)d_in[p + 6];
    DD[m]  = (const float*)d_in[p + 7];
    OW[m]  = (const float*)d_in[p + 8];
  }
  size_t mb[2] = { MB0, MB1 };

  u16* wah = (u16*)(ws + WA_H); u16* wal = (u16*)(ws + WA_L);
  u16* wbh = (u16*)(ws + WB_H); u16* wbl = (u16*)(ws + WB_L);

  // ---- phase 1: conv block (MFMA) + tokenize ----
  {
    u16* pah = (u16*)(ws + P1A); u16* pal = pah + PADN * 2;
    u16* pbh = (u16*)(ws + P1B); u16* pbl = pbh + PADN * 2;
    k_wswz<<<144, 256, 0, stream>>>(CB1, wah, wal);
    k_wswz<<<144, 256, 0, stream>>>(CB2, wbh, wbl);
    k_prep<<<dim3(130, 4), 256, 0, stream>>>(X, pah, pal);
    k_zero<<<4225, 256, 0, stream>>>((float4*)(ws + P1B), 1081600);
    k_convm<<<dim3(8, 8, 4), 256, 0, stream>>>(pah, pal, wah, wal, nullptr, pbh, pbl, nullptr, 0);
    k_convm<<<dim3(8, 8, 4), 256, 0, stream>>>(pbh, pbl, wbh, wbl, X, nullptr, nullptr, ws + XR, 1);
    k_tok<<<4096, 256, 0, stream>>>(ws + XR, ws + TOK);
  }

  // ---- phase 2: mamba x2 ----
  for (int m = 0; m < 2; m++){
    size_t B = mb[m];
    k_ln<<<4096, 256, 0, stream>>>(ws + TOK, LNW[m], LNB[m], ws + B + O_LN);
    k_inproj<<<dim3(1024, 2), 256, 0, stream>>>(ws + B + O_LN, INW[m], ws + B + O_XC, ws + B + O_Z);
    k_dwconv<<<8192, 256, 0, stream>>>(ws + B + O_XC, CW[m], CBb[m], ws + B + O_U);
    k_xproj<<<4096, 256, 0, stream>>>(ws + B + O_U, XPW[m], ws + B + O_DBL);
    k_dt<<<8192, 256, 0, stream>>>(ws + B + O_DBL, DTW[m], DTB[m], ws + B + O_DT);
  }

  float* HF  = ws + MB0 + O_XC;
  float* AP  = ws + MB0 + O_XC + 1048576;
  float* HIN = ws + MB0 + O_LN;

  k_scanA<<<4096, 256, 0, stream>>>(
      ws + MB0 + O_DT, ws + MB0 + O_DBL, ws + MB0 + O_U, AL[0],
      ws + MB1 + O_DT, ws + MB1 + O_DBL, ws + MB1 + O_U, AL[1],
      HF, AP);
  k_scanB<<<64, 256, 0, stream>>>(HF, AP, HIN);
  k_scanC<<<4096, 256, 0, stream>>>(
      ws + MB0 + O_DT, ws + MB0 + O_DBL, ws + MB0 + O_U, ws + MB0 + O_Z, AL[0], DD[0], ws + MB0 + O_XC,
      ws + MB1 + O_DT, ws + MB1 + O_DBL, ws + MB1 + O_U, ws + MB1 + O_Z, AL[1], DD[1], ws + MB1 + O_XC,
      HIN);

  k_outproj<<<1024, 256, 0, stream>>>(ws + MB0 + O_XC, OW[0], ws + OUT0);
  k_outproj<<<1024, 256, 0, stream>>>(ws + MB1 + O_XC, OW[1], ws + OUT1);

  k_smA<<<64, 256, 0, stream>>>(ws + OUT1, ws + SMP);
  k_smB<<<1, 256, 0, stream>>>(ws + SMP, ws + SMF);
  k_combine<<<256, 256, 0, stream>>>(ws + TOK, ws + OUT0, ws + OUT1, ws + SMF, ws + FEAT);

  // ---- phase 3: upsample + conv block (MFMA) ----
  {
    u16* pah = (u16*)(ws + P3A); u16* pal = pah + PADN * 2;
    u16* pbh = (u16*)(ws + P3B); u16* pbl = pbh + PADN * 2;
    k_up<<<16384, 256, 0, stream>>>(ws + FEAT, ws + UPO);
    k_wswz<<<144, 256, 0, stream>>>(SW1, wah, wal);
    k_wswz<<<144, 256, 0, stream>>>(SW2, wbh, wbl);
    k_prep<<<dim3(130, 4), 256, 0, stream>>>(ws + UPO, pah, pal);
    k_zero<<<4225, 256, 0, stream>>>((float4*)(ws + P3B), 1081600);
    k_convm<<<dim3(8, 8, 4), 256, 0, stream>>>(pah, pal, wah, wal, nullptr, pbh, pbl, nullptr, 0);
    k_convm<<<dim3(8, 8, 4), 256, 0, stream>>>(pbh, pbl, wbh, wbl, nullptr, nullptr, nullptr, (float*)d_out, 1);
  }
}

// Round 6
// 638.100 us; speedup vs baseline: 3.8858x; 1.0618x over previous
//
#include <hip/hip_runtime.h>

typedef unsigned int u32;
typedef unsigned short u16;
typedef __attribute__((ext_vector_type(8))) short short8;
typedef __attribute__((ext_vector_type(4))) float f32x4;

__device__ __forceinline__ float sigmoidf_(float x){
  return 1.f / (1.f + __expf(-x));
}
__device__ __forceinline__ u16 f2bf(float f){
  union { float f; u32 i; } v; v.f = f;
  u32 r = v.i + 0x7fffu + ((v.i >> 16) & 1u);
  return (u16)(r >> 16);
}
__device__ __forceinline__ float bf2f(u32 u){
  union { float f; u32 i; } v; v.i = (u & 0xffffu) << 16; return v.f;
}

// ---------------- zero fill ----------------
__global__ void k_zero(float4* __restrict__ p, int n4){
  int i = blockIdx.x * 256 + threadIdx.x;
  if (i < n4) p[i] = make_float4(0.f, 0.f, 0.f, 0.f);
}

// ---------------- prep: NCHW fp32 -> padded NHWC bf16 hi/lo ----------------
__global__ __launch_bounds__(256) void k_prep(const float* __restrict__ src,
                                              u16* __restrict__ PH, u16* __restrict__ PL){
  __shared__ float ld[64 * 128];
  int yp = blockIdx.x;          // padded row 0..129
  int b  = blockIdx.y;
  int ys = yp - 1;
  int tid = threadIdx.x;
  if ((u32)ys < 128u){
    for (int i = tid; i < 8192; i += 256){
      int c = i >> 7, x = i & 127;
      ld[i] = src[((size_t)(b * 64 + c) * 128 + ys) * 128 + x];
    }
  }
  __syncthreads();
  for (int i = tid; i < 130 * 64; i += 256){
    int xp = i >> 6, c = i & 63;
    float v = 0.f;
    if ((u32)ys < 128u && (u32)(xp - 1) < 128u) v = ld[c * 128 + (xp - 1)];
    u16 h = f2bf(v);
    u16 l = f2bf(v - bf2f(h));
    size_t o = (((size_t)b * 130 + yp) * 130 + xp) * 64 + c;
    PH[o] = h; PL[o] = l;
  }
}

// ---------------- weight swizzle ----------------
__global__ void k_wswz(const float* __restrict__ w, u16* __restrict__ WH, u16* __restrict__ WL){
  int idx = blockIdx.x * 256 + threadIdx.x;
  if (idx >= 36864) return;
  int j    = idx & 7;
  int lane = (idx >> 3) & 63;
  int nt   = (idx >> 9) & 3;
  int kc   = (idx >> 11) & 1;
  int t    = idx >> 12;           // 0..8
  int ic = kc * 32 + ((lane >> 4) & 3) * 8 + j;
  int oc = nt * 16 + (lane & 15);
  float v = w[(oc * 64 + ic) * 9 + t];
  u16 h = f2bf(v);
  u16 l = f2bf(v - bf2f(h));
  WH[idx] = h; WL[idx] = l;
}

// ---------------- MFMA conv3x3 64->64 ----------------
__global__ __launch_bounds__(256) void k_convm(
    const u16* __restrict__ PH, const u16* __restrict__ PL,
    const u16* __restrict__ WH, const u16* __restrict__ WL,
    const float* __restrict__ resid,
    u16* __restrict__ OBH, u16* __restrict__ OBL,
    float* __restrict__ OUTF, int mode)
{
  __shared__ __align__(16) u32 smem[10368];
  u16* Ah_s = (u16*)smem;
  u16* Al_s = Ah_s + 10368;
  int tid = threadIdx.x;
  int lane = tid & 63, w = tid >> 6;
  int quad = lane >> 4, lcol = lane & 15;
  int b = blockIdx.z, y0 = blockIdx.y * 16, x0 = blockIdx.x * 16;

  f32x4 acc[4][4];
#pragma unroll
  for (int mt = 0; mt < 4; mt++)
#pragma unroll
    for (int nt = 0; nt < 4; nt++)
      acc[mt][nt] = (f32x4){0.f, 0.f, 0.f, 0.f};

  for (int kc = 0; kc < 2; kc++){
    __syncthreads();
    for (int i = tid; i < 1296; i += 256){
      int q = i & 3;
      int rc = i >> 2;
      int r = rc / 18, c = rc - r * 18;
      size_t so = (((size_t)b * 130 + y0 + r) * 130 + (x0 + c)) * 64 + kc * 32 + q * 8;
      int de = (r * 18 + c) * 32 + q * 8;
      *(uint4*)(Ah_s + de) = *(const uint4*)(PH + so);
      *(uint4*)(Al_s + de) = *(const uint4*)(PL + so);
    }
    __syncthreads();
    short8 bh[2][4], bl[2][4];
#pragma unroll
    for (int nt = 0; nt < 4; nt++){
      int o = (kc * 4 + nt) * 512 + lane * 8;
      bh[0][nt] = *(const short8*)(WH + o);
      bl[0][nt] = *(const short8*)(WL + o);
    }
    for (int t = 0; t < 9; t++){
      int cur = t & 1, nxt = cur ^ 1;
      if (t < 8){
#pragma unroll
        for (int nt = 0; nt < 4; nt++){
          int o = (((t + 1) * 2 + kc) * 4 + nt) * 512 + lane * 8;
          bh[nxt][nt] = *(const short8*)(WH + o);
          bl[nxt][nt] = *(const short8*)(WL + o);
        }
      }
      int dy = t / 3, dx = t - dy * 3;
      short8 ah[4], al[4];
#pragma unroll
      for (int mt = 0; mt < 4; mt++){
        int e = ((w * 4 + mt + dy) * 18 + (lcol + dx)) * 32 + quad * 8;
        ah[mt] = *(const short8*)(Ah_s + e);
        al[mt] = *(const short8*)(Al_s + e);
      }
#pragma unroll
      for (int mt = 0; mt < 4; mt++)
#pragma unroll
        for (int nt = 0; nt < 4; nt++){
          acc[mt][nt] = __builtin_amdgcn_mfma_f32_16x16x32_bf16(ah[mt], bh[cur][nt], acc[mt][nt], 0, 0, 0);
          acc[mt][nt] = __builtin_amdgcn_mfma_f32_16x16x32_bf16(ah[mt], bl[cur][nt], acc[mt][nt], 0, 0, 0);
          acc[mt][nt] = __builtin_amdgcn_mfma_f32_16x16x32_bf16(al[mt], bh[cur][nt], acc[mt][nt], 0, 0, 0);
        }
    }
  }

  if (mode == 0){
    u32* epi = smem;
    for (int half = 0; half < 2; half++){
      __syncthreads();
#pragma unroll
      for (int mtl = 0; mtl < 2; mtl++){
        int mt = half * 2 + mtl;
#pragma unroll
        for (int nt = 0; nt < 4; nt++){
#pragma unroll
          for (int reg = 0; reg < 4; reg++){
            float v = fmaxf(acc[mt][nt][reg], 0.f);
            u32 h = f2bf(v);
            u32 l = f2bf(v - bf2f(h));
            int c_loc = quad * 4 + reg;
            int oc = nt * 16 + lcol;
            epi[((w * 2 + mtl) * 16 + c_loc) * 66 + oc] = h | (l << 16);
          }
        }
      }
      __syncthreads();
      for (int i = tid; i < 8192; i += 256){
        int px = i >> 6, oc = i & 63;
        int row8 = px >> 4, c_loc = px & 15;
        int r_loc = (row8 >> 1) * 4 + half * 2 + (row8 & 1);
        u32 pk = epi[(row8 * 16 + c_loc) * 66 + oc];
        size_t o = (((size_t)b * 130 + y0 + r_loc + 1) * 130 + (x0 + c_loc + 1)) * 64 + oc;
        OBH[o] = (u16)pk;
        OBL[o] = (u16)(pk >> 16);
      }
    }
  } else {
    float* epi = (float*)smem;
    for (int half = 0; half < 2; half++){
      __syncthreads();
#pragma unroll
      for (int mtl = 0; mtl < 2; mtl++){
        int mt = half * 2 + mtl;
#pragma unroll
        for (int nt = 0; nt < 4; nt++){
#pragma unroll
          for (int reg = 0; reg < 4; reg++){
            int px = (w * 2 + mtl) * 16 + quad * 4 + reg;
            int oc = nt * 16 + lcol;
            epi[oc * 130 + px] = acc[mt][nt][reg];
          }
        }
      }
      __syncthreads();
      for (int i = tid; i < 8192; i += 256){
        int oc = i >> 7, px = i & 127;
        int row8 = px >> 4, c = px & 15;
        int r_loc = (row8 >> 1) * 4 + half * 2 + (row8 & 1);
        size_t o = (((size_t)b * 64 + oc) * 128 + y0 + r_loc) * 128 + x0 + c;
        float v = epi[oc * 130 + px];
        if (resid) v += resid[o];
        OUTF[o] = v;
      }
    }
  }
}

// ---------------- tokenize (2x2 avg) + fused layernorm stats ----------------
// each 64-lane wave = one token row (c = low 6 bits). writes raw token + normalized.
__global__ void k_tok(const float* __restrict__ xr, float* __restrict__ T,
                      float* __restrict__ NT){
  int idx = blockIdx.x * 256 + threadIdx.x; // 4*4096*64
  int c = idx & 63;
  int l = (idx >> 6) & 4095;
  int b = idx >> 18;
  int r = l >> 6, cl = l & 63;
  const float* p = xr + (((size_t)(b * 64 + c) * 128 + 2 * r) * 128 + 2 * cl);
  float t = 0.25f * (p[0] + p[1] + p[128] + p[129]);
  float s = t;
  for (int m = 32; m; m >>= 1) s += __shfl_xor(s, m);
  float mu = s * (1.f / 64.f);
  float d = t - mu;
  float q = d * d;
  for (int m = 32; m; m >>= 1) q += __shfl_xor(q, m);
  float var = q * (1.f / 64.f);
  T[idx] = t;
  NT[idx] = d * rsqrtf(var + 1e-5f);
}

// ---------------- fold LN gamma/beta into in_proj weights ----------------
// W2[j,k] = W[j,k]*lnw[k];  B2[j] = sum_k W[j,k]*lnb[k]
__global__ __launch_bounds__(256) void k_fold(const float* __restrict__ W,
                                              const float* __restrict__ lnw,
                                              const float* __restrict__ lnb,
                                              float* __restrict__ W2, float* __restrict__ B2){
  __shared__ float gw[64], gb[64];
  int j = threadIdx.x;
  if (j < 64){ gw[j] = lnw[j]; gb[j] = lnb[j]; }
  __syncthreads();
  float bias = 0.f;
#pragma unroll
  for (int k4 = 0; k4 < 16; k4++){
    float4 wv = *(const float4*)&W[j * 64 + k4 * 4];
    W2[j * 64 + k4 * 4 + 0] = wv.x * gw[k4 * 4 + 0];
    W2[j * 64 + k4 * 4 + 1] = wv.y * gw[k4 * 4 + 1];
    W2[j * 64 + k4 * 4 + 2] = wv.z * gw[k4 * 4 + 2];
    W2[j * 64 + k4 * 4 + 3] = wv.w * gw[k4 * 4 + 3];
    bias = fmaf(wv.x, gb[k4 * 4 + 0], bias);
    bias = fmaf(wv.y, gb[k4 * 4 + 1], bias);
    bias = fmaf(wv.z, gb[k4 * 4 + 2], bias);
    bias = fmaf(wv.w, gb[k4 * 4 + 3], bias);
  }
  B2[j] = bias;
}

// ---------------- in_proj: NT(16k,64) @ W2(256,64)^T + B2 -> XC | Z ----------------
__global__ __launch_bounds__(256) void k_inproj(const float* __restrict__ NT,
                                                const float* __restrict__ W2,
                                                const float* __restrict__ B2,
                                                float* __restrict__ XC, float* __restrict__ Z){
  __shared__ float wL[64 * 132];
  __shared__ float ln[16 * 64];
  int tid = threadIdx.x;
  int t0 = blockIdx.x * 16;
  int j0 = blockIdx.y * 128;
  for (int i = tid; i < 1024; i += 256) ln[i] = NT[(size_t)t0 * 64 + i];
  for (int i = tid; i < 8192; i += 256){
    int jl = i >> 6, k = i & 63;
    wL[k * 132 + jl] = W2[(size_t)(j0 + jl) * 64 + k];
  }
  __syncthreads();
  int j = tid & 127, th = tid >> 7;
  int J = j0 + j;
  float bias = B2[J];
  float acc[8];
#pragma unroll
  for (int t = 0; t < 8; t++) acc[t] = bias;
#pragma unroll
  for (int k4 = 0; k4 < 16; k4++){
    int k = k4 * 4;
    float w0 = wL[k * 132 + j];
    float w1 = wL[(k + 1) * 132 + j];
    float w2 = wL[(k + 2) * 132 + j];
    float w3 = wL[(k + 3) * 132 + j];
#pragma unroll
    for (int t = 0; t < 8; t++){
      float4 lv = *(const float4*)&ln[(th * 8 + t) * 64 + k];
      acc[t] = fmaf(w0, lv.x, fmaf(w1, lv.y, fmaf(w2, lv.z, fmaf(w3, lv.w, acc[t]))));
    }
  }
#pragma unroll
  for (int t = 0; t < 8; t++){
    size_t tg = t0 + th * 8 + t;
    if (J < 128) XC[tg * 128 + J] = acc[t];
    else         Z[tg * 128 + J - 128] = acc[t];
  }
}

// ---------------- causal depthwise conv(4) + bias + silu ----------------
__global__ void k_dwconv(const float* __restrict__ XC, const float* __restrict__ cw,
                         const float* __restrict__ cb, float* __restrict__ U){
  int idx = blockIdx.x * 256 + threadIdx.x; // 4*4096*128
  int n = idx & 127;
  int l = (idx >> 7) & 4095;
  float4 wv = *(const float4*)(cw + n * 4);
  float a = cb[n];
  a = fmaf(wv.w, XC[idx], a);
  if (l >= 1) a = fmaf(wv.z, XC[idx - 128], a);
  if (l >= 2) a = fmaf(wv.y, XC[idx - 256], a);
  if (l >= 3) a = fmaf(wv.x, XC[idx - 384], a);
  U[idx] = a * sigmoidf_(a);
}

// ---------------- x_proj ----------------
__global__ __launch_bounds__(256) void k_xproj(const float* __restrict__ U,
                                               const float* __restrict__ XW,
                                               float* __restrict__ DBL){
  __shared__ float xp[128 * 36];
  int tid = threadIdx.x;
  for (int i = tid; i < 4608; i += 256){
    int k = i / 36, j = i - k * 36;
    xp[i] = XW[j * 128 + k];
  }
  __syncthreads();
  int wv = tid >> 6, j = tid & 63;
  size_t tg = (size_t)blockIdx.x * 4 + wv;
  if (j < 36){
    float acc = 0.f;
    const float4* up = (const float4*)(U + tg * 128);
#pragma unroll
    for (int k4 = 0; k4 < 32; k4++){
      float4 u = up[k4];
      const float* x0 = &xp[(k4 * 4) * 36 + j];
      acc = fmaf(u.x, x0[0],   acc);
      acc = fmaf(u.y, x0[36],  acc);
      acc = fmaf(u.z, x0[72],  acc);
      acc = fmaf(u.w, x0[108], acc);
    }
    DBL[tg * 36 + j] = acc;
  }
}

// ---------------- dt = softplus ----------------
__global__ void k_dt(const float* __restrict__ DBL, const float* __restrict__ DW,
                     const float* __restrict__ DB, float* __restrict__ DT){
  int idx = blockIdx.x * 256 + threadIdx.x;
  int n = idx & 127;
  size_t tg = (size_t)(idx >> 7);
  float4 d = *(const float4*)(DBL + tg * 36);
  float4 wv = *(const float4*)(DW + n * 4);
  float x = DB[n];
  x = fmaf(wv.x, d.x, x); x = fmaf(wv.y, d.y, x); x = fmaf(wv.z, d.z, x); x = fmaf(wv.w, d.w, x);
  DT[idx] = fmaxf(x, 0.f) + log1pf(__expf(-fabsf(x)));
}

// ================= chunked parallel scan (4 states/thread) =================
// grid 1024: bid = ((m*4+b)*64+c)*2 + cg.  block 256 = 4 waves.
// wave lane: lcol = lane&15 (channel), q = lane>>4 (state quad).
// channel n = cg*64 + w*16 + lcol; states s = q*4..q*4+3.

__global__ __launch_bounds__(256) void k_scanA(
    const float* __restrict__ DT0, const float* __restrict__ DBL0, const float* __restrict__ U0,
    const float* __restrict__ AL0,
    const float* __restrict__ DT1, const float* __restrict__ DBL1, const float* __restrict__ U1,
    const float* __restrict__ AL1,
    float* __restrict__ HF, float* __restrict__ AP)
{
  __shared__ float sdt[64 * 65], su[64 * 65], sB[16 * 68];
  int bid = blockIdx.x;
  int cg = bid & 1;
  int c  = (bid >> 1) & 63;
  int b  = (bid >> 7) & 3;
  int m  = bid >> 9;
  const float* DTp  = m ? DT1  : DT0;
  const float* DBLp = m ? DBL1 : DBL0;
  const float* Up   = m ? U1   : U0;
  const float* ALp  = m ? AL1  : AL0;
  int tid = threadIdx.x;
  int lane = tid & 63, w = tid >> 6;
  int lcol = lane & 15, q = lane >> 4;
  int chL = w * 16 + lcol;
  int n = cg * 64 + chL;
  size_t base = (size_t)b * 4096 + c * 64;
  for (int i = tid; i < 4096; i += 256){
    int ch = i & 63, l = i >> 6;
    size_t off = (base + l) * 128 + cg * 64 + ch;
    sdt[l * 65 + ch] = DTp[off];
    su[l * 65 + ch]  = Up[off];
  }
  for (int i = tid; i < 1024; i += 256){
    int s = i & 15, l = i >> 4;
    sB[s * 68 + l] = DBLp[(base + l) * 36 + 4 + s];
  }
  float A1[4];
#pragma unroll
  for (int j = 0; j < 4; j++) A1[j] = -__expf(ALp[n * 16 + q * 4 + j]);
  __syncthreads();
  float h[4] = {0.f, 0.f, 0.f, 0.f};
  float ap[4] = {1.f, 1.f, 1.f, 1.f};
#pragma unroll
  for (int l4 = 0; l4 < 16; l4++){
    float4 Bv[4];
#pragma unroll
    for (int j = 0; j < 4; j++) Bv[j] = *(const float4*)&sB[(q * 4 + j) * 68 + l4 * 4];
#pragma unroll
    for (int jj = 0; jj < 4; jj++){
      int l = l4 * 4 + jj;
      float dt = sdt[l * 65 + chL];
      float u  = su[l * 65 + chL];
      float dtu = dt * u;
#pragma unroll
      for (int j = 0; j < 4; j++){
        float a = __expf(dt * A1[j]);
        h[j] = fmaf(a, h[j], dtu * (&Bv[j].x)[jj]);
        ap[j] *= a;
      }
    }
  }
  size_t o = ((size_t)((m * 4 + b) * 64 + c)) * 2048 + n * 16 + q * 4;
  *(float4*)&HF[o] = make_float4(h[0], h[1], h[2], h[3]);
  *(float4*)&AP[o] = make_float4(ap[0], ap[1], ap[2], ap[3]);
}

// Phase B. grid 256 x 64 = 16384 recurrences; 64 chunks each.
__global__ __launch_bounds__(64) void k_scanB(
    const float* __restrict__ HF, const float* __restrict__ AP, float* __restrict__ HIN)
{
  int r = blockIdx.x * 64 + threadIdx.x;
  int q = r >> 11;        // (m*4+b)
  int p = r & 2047;       // n*16+s
  float h = 0.f;
  for (int c = 0; c < 64; c++){
    size_t o = (size_t)(q * 64 + c) * 2048 + p;
    HIN[o] = h;
    h = fmaf(AP[o], h, HF[o]);
  }
}

// Phase C: seeded scan + reduce over states; y = p + u*D (gate applied in outproj).
__global__ __launch_bounds__(256) void k_scanC(
    const float* __restrict__ DT0, const float* __restrict__ DBL0, const float* __restrict__ U0,
    const float* __restrict__ AL0, const float* __restrict__ D0, float* __restrict__ Y0,
    const float* __restrict__ DT1, const float* __restrict__ DBL1, const float* __restrict__ U1,
    const float* __restrict__ AL1, const float* __restrict__ D1, float* __restrict__ Y1,
    const float* __restrict__ HIN)
{
  __shared__ float sdt[64 * 65], su[64 * 65], sB[16 * 68], sC[16 * 68];
  int bid = blockIdx.x;
  int cg = bid & 1;
  int c  = (bid >> 1) & 63;
  int b  = (bid >> 7) & 3;
  int m  = bid >> 9;
  const float* DTp  = m ? DT1  : DT0;
  const float* DBLp = m ? DBL1 : DBL0;
  const float* Up   = m ? U1   : U0;
  const float* ALp  = m ? AL1  : AL0;
  const float* Dp   = m ? D1   : D0;
  float*       Yp   = m ? Y1   : Y0;
  int tid = threadIdx.x;
  int lane = tid & 63, w = tid >> 6;
  int lcol = lane & 15, q = lane >> 4;
  int chL = w * 16 + lcol;
  int n = cg * 64 + chL;
  size_t base = (size_t)b * 4096 + c * 64;
  for (int i = tid; i < 4096; i += 256){
    int ch = i & 63, l = i >> 6;
    size_t off = (base + l) * 128 + cg * 64 + ch;
    sdt[l * 65 + ch] = DTp[off];
    su[l * 65 + ch]  = Up[off];
  }
  for (int i = tid; i < 1024; i += 256){
    int s = i & 15, l = i >> 4;
    size_t ob = (base + l) * 36;
    sB[s * 68 + l] = DBLp[ob + 4 + s];
    sC[s * 68 + l] = DBLp[ob + 20 + s];
  }
  float A1[4];
#pragma unroll
  for (int j = 0; j < 4; j++) A1[j] = -__expf(ALp[n * 16 + q * 4 + j]);
  float Dn = Dp[n];
  float4 hv = *(const float4*)&HIN[((size_t)((m * 4 + b) * 64 + c)) * 2048 + n * 16 + q * 4];
  float h[4] = {hv.x, hv.y, hv.z, hv.w};
  __syncthreads();
#pragma unroll
  for (int l4 = 0; l4 < 16; l4++){
    float4 Bv[4], Cv[4];
#pragma unroll
    for (int j = 0; j < 4; j++){
      Bv[j] = *(const float4*)&sB[(q * 4 + j) * 68 + l4 * 4];
      Cv[j] = *(const float4*)&sC[(q * 4 + j) * 68 + l4 * 4];
    }
#pragma unroll
    for (int jj = 0; jj < 4; jj++){
      int l = l4 * 4 + jj;
      float dt = sdt[l * 65 + chL];
      float u  = su[l * 65 + chL];
      float dtu = dt * u;
      float p = 0.f;
#pragma unroll
      for (int j = 0; j < 4; j++){
        float a = __expf(dt * A1[j]);
        h[j] = fmaf(a, h[j], dtu * (&Bv[j].x)[jj]);
        p = fmaf(h[j], (&Cv[j].x)[jj], p);
      }
      p += __shfl_xor(p, 16);
      p += __shfl_xor(p, 32);
      if (q == 0)
        Yp[(base + l) * 128 + n] = fmaf(u, Dn, p);
    }
  }
}

// ---------------- out_proj: ((Y)*silu(Z))(16k,128) @ (128,64)^T ----------------
__global__ __launch_bounds__(256) void k_outproj(const float* __restrict__ Y,
                                                 const float* __restrict__ Zg,
                                                 const float* __restrict__ W,
                                                 float* __restrict__ OUT){
  __shared__ float yl[16 * 128];
  __shared__ float wT[128 * 65];
  int tid = threadIdx.x;
  size_t t0 = (size_t)blockIdx.x * 16;
  for (int i = tid; i < 2048; i += 256){
    float z = Zg[t0 * 128 + i];
    yl[i] = Y[t0 * 128 + i] * (z * sigmoidf_(z));
  }
  for (int i = tid; i < 8192; i += 256){
    int k = i & 127, j = i >> 7;
    wT[k * 65 + j] = W[j * 128 + k];
  }
  __syncthreads();
  int j = tid & 63;
  int tg = tid >> 6;
  float acc[4] = {0.f, 0.f, 0.f, 0.f};
  for (int k = 0; k < 128; k += 4){
    float w0 = wT[k * 65 + j], w1 = wT[(k+1) * 65 + j];
    float w2 = wT[(k+2) * 65 + j], w3 = wT[(k+3) * 65 + j];
#pragma unroll
    for (int t = 0; t < 4; t++){
      float4 yv = *(const float4*)&yl[(tg * 4 + t) * 128 + k];
      acc[t] = fmaf(w0, yv.x, fmaf(w1, yv.y, fmaf(w2, yv.z, fmaf(w3, yv.w, acc[t]))));
    }
  }
#pragma unroll
  for (int t = 0; t < 4; t++)
    OUT[(t0 + tg * 4 + t) * 64 + j] = acc[t];
}

// ---------------- softmax over L: partial pass (grid 256 = b4 x lc64) ----------------
__global__ void k_smA(const float* __restrict__ G, float* __restrict__ P){
  int bid = blockIdx.x;
  int b = bid >> 6, lc = bid & 63;
  int tid = threadIdx.x;
  int j = tid & 63, part = tid >> 6;
  size_t base = (size_t)b * 4096 + lc * 64;
  float mx = -3.4e38f;
  for (int i = 0; i < 16; i++){
    int l = part + i * 4;
    mx = fmaxf(mx, G[(base + l) * 64 + j]);
  }
  float sm = 0.f;
  for (int i = 0; i < 16; i++){
    int l = part + i * 4;
    sm += __expf(G[(base + l) * 64 + j] - mx);
  }
  __shared__ float sM[256], sS[256];
  sM[tid] = mx; sS[tid] = sm;
  __syncthreads();
  if (tid < 64){
    float M = sM[tid], S = sS[tid];
    for (int p = 1; p < 4; p++){
      float m2 = sM[p * 64 + tid], s2 = sS[p * 64 + tid];
      float Mn = fmaxf(M, m2);
      S = S * __expf(M - Mn) + s2 * __expf(m2 - Mn);
      M = Mn;
    }
    P[(bid * 64 + tid) * 2] = M;
    P[(bid * 64 + tid) * 2 + 1] = S;
  }
}

__global__ void k_smB(const float* __restrict__ P, float* __restrict__ F){
  int tid = threadIdx.x; // 256 = b(4) x j(64)
  int b = tid >> 6, j = tid & 63;
  float M = -3.4e38f, S = 0.f;
  for (int lc = 0; lc < 64; lc++){
    int idx = ((b * 64 + lc) * 64 + j) * 2;
    float m2 = P[idx], s2 = P[idx + 1];
    float Mn = fmaxf(M, m2);
    S = S * __expf(M - Mn) + s2 * __expf(m2 - Mn);
    M = Mn;
  }
  F[(b * 64 + j) * 2] = M;
  F[(b * 64 + j) * 2 + 1] = S;
}

// ---------------- combine + transpose to (b,c,64,64) ----------------
__global__ void k_combine(const float* __restrict__ T, const float* __restrict__ MAIN,
                          const float* __restrict__ G, const float* __restrict__ F,
                          float* __restrict__ FEAT){
  int bid = blockIdx.x;
  int b = bid >> 6, row = bid & 63;
  int tid = threadIdx.x;
  int j = tid & 63, ls = tid >> 6;
  __shared__ float tile[64 * 65];
  float M = F[(b * 64 + j) * 2], invS = 1.f / F[(b * 64 + j) * 2 + 1];
  size_t lbase = (size_t)b * 4096 + row * 64;
  for (int i = 0; i < 16; i++){
    int col = ls + i * 4;
    size_t off = (lbase + col) * 64 + j;
    float g = __expf(G[off] - M) * invS;
    tile[col * 65 + j] = T[off] + g * MAIN[off];
  }
  __syncthreads();
  int colw = tid & 63, jr = tid >> 6;
  for (int jj = jr; jj < 64; jj += 4)
    FEAT[(((size_t)b * 64 + jj) * 64 + row) * 64 + colw] = tile[colw * 65 + jj];
}

// ---------------- bilinear upsample 64->128 ----------------
__global__ void k_up(const float* __restrict__ FEAT, float* __restrict__ UP){
  size_t idx = (size_t)blockIdx.x * 256 + threadIdx.x;
  int x = idx & 127;
  int y = (idx >> 7) & 127;
  size_t bc = idx >> 14;
  float ay = 0.5f * y - 0.25f;
  float ax = 0.5f * x - 0.25f;
  int fy = (int)floorf(ay); float wy = ay - fy;
  int fx = (int)floorf(ax); float wx = ax - fx;
  int y0 = fy < 0 ? 0 : fy, y1 = fy + 1 > 63 ? 63 : fy + 1;
  int x0 = fx < 0 ? 0 : fx, x1 = fx + 1 > 63 ? 63 : fx + 1;
  const float* p = FEAT + bc * 4096;
  float v = (1.f - wy) * ((1.f - wx) * p[y0 * 64 + x0] + wx * p[y0 * 64 + x1])
          +        wy  * ((1.f - wx) * p[y1 * 64 + x0] + wx * p[y1 * 64 + x1]);
  UP[idx] = v;
}

// ---------------- host launcher ----------------
extern "C" void kernel_launch(void* const* d_in, const int* in_sizes, int n_in,
                              void* d_out, int out_size, void* d_ws, size_t ws_size,
                              hipStream_t stream) {
  // workspace layout (float offsets)
  const size_t P1A = 0, P1B = 4326400, XR = 8652800;
  const size_t MB0 = 0, MB1 = 10027008;
  const size_t O_LN = 0, O_XC = 1048576, O_Z = 3145728, O_U = 5242880,
               O_DT = 7340032, O_DBL = 9437184;
  const size_t TOK = 20054016, OUT0 = 21102592, OUT1 = 22151168;
  const size_t FEAT = 23208448;
  const size_t UPO = 0, P3A = 4194304, P3B = 8520704;
  const size_t WA_H = 19000000, WA_L = 19018432, WB_H = 19036864, WB_L = 19055296;
  const size_t PADN = 2163200;
  // softmax scratch lives in dead MB0 region (HIN dead after scanC)
  const size_t SMP = 0, SMF = 65536;
  // folded in_proj weights live in OUT0 slot (outproj overwrites later)
  const size_t W2_0 = 21102592, B2_0 = 21118976, W2_1 = 21119232, B2_1 = 21135616;
  const size_t TOTAL = 24257024;
  if (ws_size < TOTAL * 4) return;

  float* ws = (float*)d_ws;
  const float* X   = (const float*)d_in[0];
  const float* CB1 = (const float*)d_in[1];
  const float* CB2 = (const float*)d_in[2];
  const float* SW1 = (const float*)d_in[3];
  const float* SW2 = (const float*)d_in[4];
  const float* LNW[2] = { (const float*)d_in[5], (const float*)d_in[7] };
  const float* LNB[2] = { (const float*)d_in[6], (const float*)d_in[8] };
  const float *INW[2], *CW[2], *CBb[2], *XPW[2], *DTW[2], *DTB[2], *AL[2], *DD[2], *OW[2];
  for (int m = 0; m < 2; m++){
    int p = 9 + m * 9;
    INW[m] = (const float*)d_in[p + 0];
    CW[m]  = (const float*)d_in[p + 1];
    CBb[m] = (const float*)d_in[p + 2];
    XPW[m] = (const float*)d_in[p + 3];
    DTW[m] = (const float*)d_in[p + 4];
    DTB[m] = (const float*)d_in[p + 5];
    AL[m]  = (const float*)d_in[p + 6];
    DD[m]  = (const float*)d_in[p + 7];
    OW[m]  = (const float*)d_in[p + 8];
  }
  size_t mb[2] = { MB0, MB1 };
  size_t w2o[2] = { W2_0, W2_1 };
  size_t b2o[2] = { B2_0, B2_1 };

  u16* wah = (u16*)(ws + WA_H); u16* wal = (u16*)(ws + WA_L);
  u16* wbh = (u16*)(ws + WB_H); u16* wbl = (u16*)(ws + WB_L);

  // ---- phase 1: conv block (MFMA) + tokenize (+LN stats) ----
  {
    u16* pah = (u16*)(ws + P1A); u16* pal = pah + PADN * 2;
    u16* pbh = (u16*)(ws + P1B); u16* pbl = pbh + PADN * 2;
    k_wswz<<<144, 256, 0, stream>>>(CB1, wah, wal);
    k_wswz<<<144, 256, 0, stream>>>(CB2, wbh, wbl);
    k_prep<<<dim3(130, 4), 256, 0, stream>>>(X, pah, pal);
    k_zero<<<4225, 256, 0, stream>>>((float4*)(ws + P1B), 1081600);
    k_convm<<<dim3(8, 8, 4), 256, 0, stream>>>(pah, pal, wah, wal, nullptr, pbh, pbl, nullptr, 0);
    k_convm<<<dim3(8, 8, 4), 256, 0, stream>>>(pbh, pbl, wbh, wbl, X, nullptr, nullptr, ws + XR, 1);
    k_tok<<<4096, 256, 0, stream>>>(ws + XR, ws + TOK, ws + MB0 + O_LN);
  }

  // ---- phase 2: mamba x2 ----
  for (int m = 0; m < 2; m++)
    k_fold<<<1, 256, 0, stream>>>(INW[m], LNW[m], LNB[m], ws + w2o[m], ws + b2o[m]);
  for (int m = 0; m < 2; m++){
    size_t B = mb[m];
    k_inproj<<<dim3(1024, 2), 256, 0, stream>>>(ws + MB0 + O_LN, ws + w2o[m], ws + b2o[m],
                                                ws + B + O_XC, ws + B + O_Z);
    k_dwconv<<<8192, 256, 0, stream>>>(ws + B + O_XC, CW[m], CBb[m], ws + B + O_U);
    k_xproj<<<4096, 256, 0, stream>>>(ws + B + O_U, XPW[m], ws + B + O_DBL);
    k_dt<<<8192, 256, 0, stream>>>(ws + B + O_DBL, DTW[m], DTB[m], ws + B + O_DT);
  }

  float* HF  = ws + MB0 + O_XC;
  float* AP  = ws + MB0 + O_XC + 1048576;
  float* HIN = ws + MB0 + O_LN;

  k_scanA<<<1024, 256, 0, stream>>>(
      ws + MB0 + O_DT, ws + MB0 + O_DBL, ws + MB0 + O_U, AL[0],
      ws + MB1 + O_DT, ws + MB1 + O_DBL, ws + MB1 + O_U, AL[1],
      HF, AP);
  k_scanB<<<256, 64, 0, stream>>>(HF, AP, HIN);
  k_scanC<<<1024, 256, 0, stream>>>(
      ws + MB0 + O_DT, ws + MB0 + O_DBL, ws + MB0 + O_U, AL[0], DD[0], ws + MB0 + O_XC,
      ws + MB1 + O_DT, ws + MB1 + O_DBL, ws + MB1 + O_U, AL[1], DD[1], ws + MB1 + O_XC,
      HIN);

  k_outproj<<<1024, 256, 0, stream>>>(ws + MB0 + O_XC, ws + MB0 + O_Z, OW[0], ws + OUT0);
  k_outproj<<<1024, 256, 0, stream>>>(ws + MB1 + O_XC, ws + MB1 + O_Z, OW[1], ws + OUT1);

  k_smA<<<256, 256, 0, stream>>>(ws + OUT1, ws + SMP);
  k_smB<<<1, 256, 0, stream>>>(ws + SMP, ws + SMF);
  k_combine<<<256, 256, 0, stream>>>(ws + TOK, ws + OUT0, ws + OUT1, ws + SMF, ws + FEAT);

  // ---- phase 3: upsample + conv block (MFMA) ----
  {
    u16* pah = (u16*)(ws + P3A); u16* pal = pah + PADN * 2;
    u16* pbh = (u16*)(ws + P3B); u16* pbl = pbh + PADN * 2;
    k_up<<<16384, 256, 0, stream>>>(ws + FEAT, ws + UPO);
    k_wswz<<<144, 256, 0, stream>>>(SW1, wah, wal);
    k_wswz<<<144, 256, 0, stream>>>(SW2, wbh, wbl);
    k_prep<<<dim3(130, 4), 256, 0, stream>>>(ws + UPO, pah, pal);
    k_zero<<<4225, 256, 0, stream>>>((float4*)(ws + P3B), 1081600);
    k_convm<<<dim3(8, 8, 4), 256, 0, stream>>>(pah, pal, wah, wal, nullptr, pbh, pbl, nullptr, 0);
    k_convm<<<dim3(8, 8, 4), 256, 0, stream>>>(pbh, pbl, wbh, wbl, nullptr, nullptr, nullptr, (float*)d_out, 1);
  }
}

// Round 7
// 560.553 us; speedup vs baseline: 4.4234x; 1.1383x over previous
//
#include <hip/hip_runtime.h>

typedef unsigned int u32;
typedef unsigned short u16;
typedef __attribute__((ext_vector_type(8))) short short8;
typedef __attribute__((ext_vector_type(4))) float f32x4;

__device__ __forceinline__ float sigmoidf_(float x){
  return 1.f / (1.f + __expf(-x));
}
__device__ __forceinline__ u16 f2bf(float f){
  union { float f; u32 i; } v; v.f = f;
  u32 r = v.i + 0x7fffu + ((v.i >> 16) & 1u);
  return (u16)(r >> 16);
}
__device__ __forceinline__ float bf2f(u32 u){
  union { float f; u32 i; } v; v.i = (u & 0xffffu) << 16; return v.f;
}

// ---------------- border zero for padded NHWC bf16 h/l buffers ----------------
// buffer dims [4][130][130][64] u16. zero rows 0/129 and cols 0/129.
__global__ void k_bord(u16* __restrict__ PH, u16* __restrict__ PL){
  int i = blockIdx.x * 256 + threadIdx.x;   // 4 * 516 = 2064 border pixels
  if (i >= 2064) return;
  int b = i / 516, p = i - b * 516;
  int y, x;
  if (p < 130){ y = 0; x = p; }
  else if (p < 260){ y = 129; x = p - 130; }
  else if (p < 388){ y = p - 260 + 1; x = 0; }
  else { y = p - 388 + 1; x = 129; }
  size_t o = (((size_t)b * 130 + y) * 130 + x) * 64;
  uint4 z = make_uint4(0, 0, 0, 0);
#pragma unroll
  for (int q = 0; q < 8; q++){
    *(uint4*)(PH + o + q * 8) = z;
    *(uint4*)(PL + o + q * 8) = z;
  }
}

// ---------------- prep: NCHW fp32 -> padded NHWC bf16 hi/lo ----------------
__global__ __launch_bounds__(256) void k_prep(const float* __restrict__ src,
                                              u16* __restrict__ PH, u16* __restrict__ PL){
  __shared__ float ld[64 * 128];
  int yp = blockIdx.x;          // padded row 0..129
  int b  = blockIdx.y;
  int ys = yp - 1;
  int tid = threadIdx.x;
  if ((u32)ys < 128u){
    for (int i = tid; i < 8192; i += 256){
      int c = i >> 7, x = i & 127;
      ld[i] = src[((size_t)(b * 64 + c) * 128 + ys) * 128 + x];
    }
  }
  __syncthreads();
  for (int i = tid; i < 130 * 64; i += 256){
    int xp = i >> 6, c = i & 63;
    float v = 0.f;
    if ((u32)ys < 128u && (u32)(xp - 1) < 128u) v = ld[c * 128 + (xp - 1)];
    u16 h = f2bf(v);
    u16 l = f2bf(v - bf2f(h));
    size_t o = (((size_t)b * 130 + yp) * 130 + xp) * 64 + c;
    PH[o] = h; PL[o] = l;
  }
}

// ---------------- weight swizzle ----------------
__global__ void k_wswz(const float* __restrict__ w, u16* __restrict__ WH, u16* __restrict__ WL){
  int idx = blockIdx.x * 256 + threadIdx.x;
  if (idx >= 36864) return;
  int j    = idx & 7;
  int lane = (idx >> 3) & 63;
  int nt   = (idx >> 9) & 3;
  int kc   = (idx >> 11) & 1;
  int t    = idx >> 12;           // 0..8
  int ic = kc * 32 + ((lane >> 4) & 3) * 8 + j;
  int oc = nt * 16 + (lane & 15);
  float v = w[(oc * 64 + ic) * 9 + t];
  u16 h = f2bf(v);
  u16 l = f2bf(v - bf2f(h));
  WH[idx] = h; WL[idx] = l;
}

// ---------------- MFMA conv3x3 64->64 ----------------
__global__ __launch_bounds__(256) void k_convm(
    const u16* __restrict__ PH, const u16* __restrict__ PL,
    const u16* __restrict__ WH, const u16* __restrict__ WL,
    const float* __restrict__ resid,
    u16* __restrict__ OBH, u16* __restrict__ OBL,
    float* __restrict__ OUTF, int mode)
{
  __shared__ __align__(16) u32 smem[10368];
  u16* Ah_s = (u16*)smem;
  u16* Al_s = Ah_s + 10368;
  int tid = threadIdx.x;
  int lane = tid & 63, w = tid >> 6;
  int quad = lane >> 4, lcol = lane & 15;
  int b = blockIdx.z, y0 = blockIdx.y * 16, x0 = blockIdx.x * 16;

  f32x4 acc[4][4];
#pragma unroll
  for (int mt = 0; mt < 4; mt++)
#pragma unroll
    for (int nt = 0; nt < 4; nt++)
      acc[mt][nt] = (f32x4){0.f, 0.f, 0.f, 0.f};

  for (int kc = 0; kc < 2; kc++){
    __syncthreads();
    for (int i = tid; i < 1296; i += 256){
      int q = i & 3;
      int rc = i >> 2;
      int r = rc / 18, c = rc - r * 18;
      size_t so = (((size_t)b * 130 + y0 + r) * 130 + (x0 + c)) * 64 + kc * 32 + q * 8;
      int de = (r * 18 + c) * 32 + q * 8;
      *(uint4*)(Ah_s + de) = *(const uint4*)(PH + so);
      *(uint4*)(Al_s + de) = *(const uint4*)(PL + so);
    }
    __syncthreads();
    short8 bh[2][4], bl[2][4];
#pragma unroll
    for (int nt = 0; nt < 4; nt++){
      int o = (kc * 4 + nt) * 512 + lane * 8;
      bh[0][nt] = *(const short8*)(WH + o);
      bl[0][nt] = *(const short8*)(WL + o);
    }
    for (int t = 0; t < 9; t++){
      int cur = t & 1, nxt = cur ^ 1;
      if (t < 8){
#pragma unroll
        for (int nt = 0; nt < 4; nt++){
          int o = (((t + 1) * 2 + kc) * 4 + nt) * 512 + lane * 8;
          bh[nxt][nt] = *(const short8*)(WH + o);
          bl[nxt][nt] = *(const short8*)(WL + o);
        }
      }
      int dy = t / 3, dx = t - dy * 3;
      short8 ah[4], al[4];
#pragma unroll
      for (int mt = 0; mt < 4; mt++){
        int e = ((w * 4 + mt + dy) * 18 + (lcol + dx)) * 32 + quad * 8;
        ah[mt] = *(const short8*)(Ah_s + e);
        al[mt] = *(const short8*)(Al_s + e);
      }
#pragma unroll
      for (int mt = 0; mt < 4; mt++)
#pragma unroll
        for (int nt = 0; nt < 4; nt++){
          acc[mt][nt] = __builtin_amdgcn_mfma_f32_16x16x32_bf16(ah[mt], bh[cur][nt], acc[mt][nt], 0, 0, 0);
          acc[mt][nt] = __builtin_amdgcn_mfma_f32_16x16x32_bf16(ah[mt], bl[cur][nt], acc[mt][nt], 0, 0, 0);
          acc[mt][nt] = __builtin_amdgcn_mfma_f32_16x16x32_bf16(al[mt], bh[cur][nt], acc[mt][nt], 0, 0, 0);
        }
    }
  }

  if (mode == 0){
    u32* epi = smem;
    for (int half = 0; half < 2; half++){
      __syncthreads();
#pragma unroll
      for (int mtl = 0; mtl < 2; mtl++){
        int mt = half * 2 + mtl;
#pragma unroll
        for (int nt = 0; nt < 4; nt++){
#pragma unroll
          for (int reg = 0; reg < 4; reg++){
            float v = fmaxf(acc[mt][nt][reg], 0.f);
            u32 h = f2bf(v);
            u32 l = f2bf(v - bf2f(h));
            int c_loc = quad * 4 + reg;
            int oc = nt * 16 + lcol;
            epi[((w * 2 + mtl) * 16 + c_loc) * 66 + oc] = h | (l << 16);
          }
        }
      }
      __syncthreads();
      for (int i = tid; i < 8192; i += 256){
        int px = i >> 6, oc = i & 63;
        int row8 = px >> 4, c_loc = px & 15;
        int r_loc = (row8 >> 1) * 4 + half * 2 + (row8 & 1);
        u32 pk = epi[(row8 * 16 + c_loc) * 66 + oc];
        size_t o = (((size_t)b * 130 + y0 + r_loc + 1) * 130 + (x0 + c_loc + 1)) * 64 + oc;
        OBH[o] = (u16)pk;
        OBL[o] = (u16)(pk >> 16);
      }
    }
  } else {
    float* epi = (float*)smem;
    for (int half = 0; half < 2; half++){
      __syncthreads();
#pragma unroll
      for (int mtl = 0; mtl < 2; mtl++){
        int mt = half * 2 + mtl;
#pragma unroll
        for (int nt = 0; nt < 4; nt++){
#pragma unroll
          for (int reg = 0; reg < 4; reg++){
            int px = (w * 2 + mtl) * 16 + quad * 4 + reg;
            int oc = nt * 16 + lcol;
            epi[oc * 130 + px] = acc[mt][nt][reg];
          }
        }
      }
      __syncthreads();
      for (int i = tid; i < 8192; i += 256){
        int oc = i >> 7, px = i & 127;
        int row8 = px >> 4, c = px & 15;
        int r_loc = (row8 >> 1) * 4 + half * 2 + (row8 & 1);
        size_t o = (((size_t)b * 64 + oc) * 128 + y0 + r_loc) * 128 + x0 + c;
        float v = epi[oc * 130 + px];
        if (resid) v += resid[o];
        OUTF[o] = v;
      }
    }
  }
}

// ---------------- tokenize (2x2 avg) + fused layernorm stats ----------------
__global__ void k_tok(const float* __restrict__ xr, float* __restrict__ T,
                      float* __restrict__ NT){
  int idx = blockIdx.x * 256 + threadIdx.x; // 4*4096*64
  int c = idx & 63;
  int l = (idx >> 6) & 4095;
  int b = idx >> 18;
  int r = l >> 6, cl = l & 63;
  const float* p = xr + (((size_t)(b * 64 + c) * 128 + 2 * r) * 128 + 2 * cl);
  float t = 0.25f * (p[0] + p[1] + p[128] + p[129]);
  float s = t;
  for (int m = 32; m; m >>= 1) s += __shfl_xor(s, m);
  float mu = s * (1.f / 64.f);
  float d = t - mu;
  float q = d * d;
  for (int m = 32; m; m >>= 1) q += __shfl_xor(q, m);
  float var = q * (1.f / 64.f);
  T[idx] = t;
  NT[idx] = d * rsqrtf(var + 1e-5f);
}

// ---------------- fold LN gamma/beta into in_proj weights ----------------
__global__ __launch_bounds__(256) void k_fold(const float* __restrict__ W,
                                              const float* __restrict__ lnw,
                                              const float* __restrict__ lnb,
                                              float* __restrict__ W2, float* __restrict__ B2){
  __shared__ float gw[64], gb[64];
  int j = threadIdx.x;
  if (j < 64){ gw[j] = lnw[j]; gb[j] = lnb[j]; }
  __syncthreads();
  float bias = 0.f;
#pragma unroll
  for (int k4 = 0; k4 < 16; k4++){
    float4 wv = *(const float4*)&W[j * 64 + k4 * 4];
    W2[j * 64 + k4 * 4 + 0] = wv.x * gw[k4 * 4 + 0];
    W2[j * 64 + k4 * 4 + 1] = wv.y * gw[k4 * 4 + 1];
    W2[j * 64 + k4 * 4 + 2] = wv.z * gw[k4 * 4 + 2];
    W2[j * 64 + k4 * 4 + 3] = wv.w * gw[k4 * 4 + 3];
    bias = fmaf(wv.x, gb[k4 * 4 + 0], bias);
    bias = fmaf(wv.y, gb[k4 * 4 + 1], bias);
    bias = fmaf(wv.z, gb[k4 * 4 + 2], bias);
    bias = fmaf(wv.w, gb[k4 * 4 + 3], bias);
  }
  B2[j] = bias;
}

// ---------------- in_proj: NT(16k,64) @ W2(256,64)^T + B2 -> XC | Z ----------------
__global__ __launch_bounds__(256) void k_inproj(const float* __restrict__ NT,
                                                const float* __restrict__ W2,
                                                const float* __restrict__ B2,
                                                float* __restrict__ XC, float* __restrict__ Z){
  __shared__ float wL[64 * 132];
  __shared__ float ln[16 * 64];
  int tid = threadIdx.x;
  int t0 = blockIdx.x * 16;
  int j0 = blockIdx.y * 128;
  for (int i = tid; i < 1024; i += 256) ln[i] = NT[(size_t)t0 * 64 + i];
  for (int i = tid; i < 8192; i += 256){
    int jl = i >> 6, k = i & 63;
    wL[k * 132 + jl] = W2[(size_t)(j0 + jl) * 64 + k];
  }
  __syncthreads();
  int j = tid & 127, th = tid >> 7;
  int J = j0 + j;
  float bias = B2[J];
  float acc[8];
#pragma unroll
  for (int t = 0; t < 8; t++) acc[t] = bias;
#pragma unroll
  for (int k4 = 0; k4 < 16; k4++){
    int k = k4 * 4;
    float w0 = wL[k * 132 + j];
    float w1 = wL[(k + 1) * 132 + j];
    float w2 = wL[(k + 2) * 132 + j];
    float w3 = wL[(k + 3) * 132 + j];
#pragma unroll
    for (int t = 0; t < 8; t++){
      float4 lv = *(const float4*)&ln[(th * 8 + t) * 64 + k];
      acc[t] = fmaf(w0, lv.x, fmaf(w1, lv.y, fmaf(w2, lv.z, fmaf(w3, lv.w, acc[t]))));
    }
  }
#pragma unroll
  for (int t = 0; t < 8; t++){
    size_t tg = t0 + th * 8 + t;
    if (J < 128) XC[tg * 128 + J] = acc[t];
    else         Z[tg * 128 + J - 128] = acc[t];
  }
}

// ---------------- causal depthwise conv(4) + bias + silu ----------------
__global__ void k_dwconv(const float* __restrict__ XC, const float* __restrict__ cw,
                         const float* __restrict__ cb, float* __restrict__ U){
  int idx = blockIdx.x * 256 + threadIdx.x; // 4*4096*128
  int n = idx & 127;
  int l = (idx >> 7) & 4095;
  float4 wv = *(const float4*)(cw + n * 4);
  float a = cb[n];
  a = fmaf(wv.w, XC[idx], a);
  if (l >= 1) a = fmaf(wv.z, XC[idx - 128], a);
  if (l >= 2) a = fmaf(wv.y, XC[idx - 256], a);
  if (l >= 3) a = fmaf(wv.x, XC[idx - 384], a);
  U[idx] = a * sigmoidf_(a);
}

// ---------------- fused x_proj + dt (both mambas) ----------------
// grid 256: m = bid>>7, blk = bid&127 (128 tokens per block).
// thread: slot = tid>>2 (64 slots), jq = tid&3 (9 j's each); 2 tokens/thread.
__global__ __launch_bounds__(256) void k_xprojdt(
    const float* __restrict__ U0, const float* __restrict__ XW0,
    const float* __restrict__ DTW0, const float* __restrict__ DTB0,
    float* __restrict__ DBL0, float* __restrict__ DT0,
    const float* __restrict__ U1, const float* __restrict__ XW1,
    const float* __restrict__ DTW1, const float* __restrict__ DTB1,
    float* __restrict__ DBL1, float* __restrict__ DT1)
{
  __shared__ float xw[36 * 132];   // [j][k] pad 132 -> conflict-free float4 reads
  __shared__ float sdtr[128 * 4];
  int bid = blockIdx.x;
  int m = bid >> 7, blk = bid & 127;
  const float* Up   = m ? U1   : U0;
  const float* XWp  = m ? XW1  : XW0;
  const float* DTWp = m ? DTW1 : DTW0;
  const float* DTBp = m ? DTB1 : DTB0;
  float* DBLp = m ? DBL1 : DBL0;
  float* DTp  = m ? DT1  : DT0;
  int tid = threadIdx.x;
  for (int i = tid; i < 4608; i += 256)
    xw[(i >> 7) * 132 + (i & 127)] = XWp[i];
  __syncthreads();
  int slot = tid >> 2, jq = tid & 3;
  size_t tgA = (size_t)blk * 128 + slot;
  size_t tgB = tgA + 64;
  const float4* upA = (const float4*)(Up + tgA * 128);
  const float4* upB = (const float4*)(Up + tgB * 128);
  float accA[9], accB[9];
#pragma unroll
  for (int jj = 0; jj < 9; jj++){ accA[jj] = 0.f; accB[jj] = 0.f; }
  for (int k4 = 0; k4 < 32; k4++){
    float4 uA = upA[k4];
    float4 uB = upB[k4];
#pragma unroll
    for (int jj = 0; jj < 9; jj++){
      float4 w = *(const float4*)&xw[(jq * 9 + jj) * 132 + k4 * 4];
      accA[jj] = fmaf(w.x, uA.x, fmaf(w.y, uA.y, fmaf(w.z, uA.z, fmaf(w.w, uA.w, accA[jj]))));
      accB[jj] = fmaf(w.x, uB.x, fmaf(w.y, uB.y, fmaf(w.z, uB.z, fmaf(w.w, uB.w, accB[jj]))));
    }
  }
#pragma unroll
  for (int jj = 0; jj < 9; jj++){
    DBLp[tgA * 36 + jq * 9 + jj] = accA[jj];
    DBLp[tgB * 36 + jq * 9 + jj] = accB[jj];
  }
  if (jq == 0){
#pragma unroll
    for (int jj = 0; jj < 4; jj++){
      sdtr[slot * 4 + jj] = accA[jj];
      sdtr[(slot + 64) * 4 + jj] = accB[jj];
    }
  }
  __syncthreads();
  int ch = tid & 127, half = tid >> 7;
  float4 wv = *(const float4*)(DTWp + ch * 4);
  float bias = DTBp[ch];
  for (int i = 0; i < 64; i++){
    int tl = half * 64 + i;
    float4 d = *(const float4*)&sdtr[tl * 4];
    float x = bias;
    x = fmaf(wv.x, d.x, x); x = fmaf(wv.y, d.y, x);
    x = fmaf(wv.z, d.z, x); x = fmaf(wv.w, d.w, x);
    x = fmaxf(x, 0.f) + log1pf(__expf(-fabsf(x)));
    DTp[((size_t)blk * 128 + tl) * 128 + ch] = x;
  }
}

// ================= chunked parallel scan (4 states/thread) =================
__global__ __launch_bounds__(256) void k_scanA(
    const float* __restrict__ DT0, const float* __restrict__ DBL0, const float* __restrict__ U0,
    const float* __restrict__ AL0,
    const float* __restrict__ DT1, const float* __restrict__ DBL1, const float* __restrict__ U1,
    const float* __restrict__ AL1,
    float* __restrict__ HF, float* __restrict__ AP)
{
  __shared__ float sdt[64 * 65], su[64 * 65], sB[16 * 68];
  int bid = blockIdx.x;
  int cg = bid & 1;
  int c  = (bid >> 1) & 63;
  int b  = (bid >> 7) & 3;
  int m  = bid >> 9;
  const float* DTp  = m ? DT1  : DT0;
  const float* DBLp = m ? DBL1 : DBL0;
  const float* Up   = m ? U1   : U0;
  const float* ALp  = m ? AL1  : AL0;
  int tid = threadIdx.x;
  int lane = tid & 63, w = tid >> 6;
  int lcol = lane & 15, q = lane >> 4;
  int chL = w * 16 + lcol;
  int n = cg * 64 + chL;
  size_t base = (size_t)b * 4096 + c * 64;
  for (int i = tid; i < 4096; i += 256){
    int ch = i & 63, l = i >> 6;
    size_t off = (base + l) * 128 + cg * 64 + ch;
    sdt[l * 65 + ch] = DTp[off];
    su[l * 65 + ch]  = Up[off];
  }
  for (int i = tid; i < 1024; i += 256){
    int s = i & 15, l = i >> 4;
    sB[s * 68 + l] = DBLp[(base + l) * 36 + 4 + s];
  }
  float A1[4];
#pragma unroll
  for (int j = 0; j < 4; j++) A1[j] = -__expf(ALp[n * 16 + q * 4 + j]);
  __syncthreads();
  float h[4] = {0.f, 0.f, 0.f, 0.f};
  float ap[4] = {1.f, 1.f, 1.f, 1.f};
#pragma unroll
  for (int l4 = 0; l4 < 16; l4++){
    float4 Bv[4];
#pragma unroll
    for (int j = 0; j < 4; j++) Bv[j] = *(const float4*)&sB[(q * 4 + j) * 68 + l4 * 4];
#pragma unroll
    for (int jj = 0; jj < 4; jj++){
      int l = l4 * 4 + jj;
      float dt = sdt[l * 65 + chL];
      float u  = su[l * 65 + chL];
      float dtu = dt * u;
#pragma unroll
      for (int j = 0; j < 4; j++){
        float a = __expf(dt * A1[j]);
        h[j] = fmaf(a, h[j], dtu * (&Bv[j].x)[jj]);
        ap[j] *= a;
      }
    }
  }
  size_t o = ((size_t)((m * 4 + b) * 64 + c)) * 2048 + n * 16 + q * 4;
  *(float4*)&HF[o] = make_float4(h[0], h[1], h[2], h[3]);
  *(float4*)&AP[o] = make_float4(ap[0], ap[1], ap[2], ap[3]);
}

__global__ __launch_bounds__(64) void k_scanB(
    const float* __restrict__ HF, const float* __restrict__ AP, float* __restrict__ HIN)
{
  int r = blockIdx.x * 64 + threadIdx.x;
  int q = r >> 11;        // (m*4+b)
  int p = r & 2047;       // n*16+s
  float h = 0.f;
  for (int c = 0; c < 64; c++){
    size_t o = (size_t)(q * 64 + c) * 2048 + p;
    HIN[o] = h;
    h = fmaf(AP[o], h, HF[o]);
  }
}

__global__ __launch_bounds__(256) void k_scanC(
    const float* __restrict__ DT0, const float* __restrict__ DBL0, const float* __restrict__ U0,
    const float* __restrict__ AL0, const float* __restrict__ D0, float* __restrict__ Y0,
    const float* __restrict__ DT1, const float* __restrict__ DBL1, const float* __restrict__ U1,
    const float* __restrict__ AL1, const float* __restrict__ D1, float* __restrict__ Y1,
    const float* __restrict__ HIN)
{
  __shared__ float sdt[64 * 65], su[64 * 65], sB[16 * 68], sC[16 * 68];
  int bid = blockIdx.x;
  int cg = bid & 1;
  int c  = (bid >> 1) & 63;
  int b  = (bid >> 7) & 3;
  int m  = bid >> 9;
  const float* DTp  = m ? DT1  : DT0;
  const float* DBLp = m ? DBL1 : DBL0;
  const float* Up   = m ? U1   : U0;
  const float* ALp  = m ? AL1  : AL0;
  const float* Dp   = m ? D1   : D0;
  float*       Yp   = m ? Y1   : Y0;
  int tid = threadIdx.x;
  int lane = tid & 63, w = tid >> 6;
  int lcol = lane & 15, q = lane >> 4;
  int chL = w * 16 + lcol;
  int n = cg * 64 + chL;
  size_t base = (size_t)b * 4096 + c * 64;
  for (int i = tid; i < 4096; i += 256){
    int ch = i & 63, l = i >> 6;
    size_t off = (base + l) * 128 + cg * 64 + ch;
    sdt[l * 65 + ch] = DTp[off];
    su[l * 65 + ch]  = Up[off];
  }
  for (int i = tid; i < 1024; i += 256){
    int s = i & 15, l = i >> 4;
    size_t ob = (base + l) * 36;
    sB[s * 68 + l] = DBLp[ob + 4 + s];
    sC[s * 68 + l] = DBLp[ob + 20 + s];
  }
  float A1[4];
#pragma unroll
  for (int j = 0; j < 4; j++) A1[j] = -__expf(ALp[n * 16 + q * 4 + j]);
  float Dn = Dp[n];
  float4 hv = *(const float4*)&HIN[((size_t)((m * 4 + b) * 64 + c)) * 2048 + n * 16 + q * 4];
  float h[4] = {hv.x, hv.y, hv.z, hv.w};
  __syncthreads();
#pragma unroll
  for (int l4 = 0; l4 < 16; l4++){
    float4 Bv[4], Cv[4];
#pragma unroll
    for (int j = 0; j < 4; j++){
      Bv[j] = *(const float4*)&sB[(q * 4 + j) * 68 + l4 * 4];
      Cv[j] = *(const float4*)&sC[(q * 4 + j) * 68 + l4 * 4];
    }
#pragma unroll
    for (int jj = 0; jj < 4; jj++){
      int l = l4 * 4 + jj;
      float dt = sdt[l * 65 + chL];
      float u  = su[l * 65 + chL];
      float dtu = dt * u;
      float p = 0.f;
#pragma unroll
      for (int j = 0; j < 4; j++){
        float a = __expf(dt * A1[j]);
        h[j] = fmaf(a, h[j], dtu * (&Bv[j].x)[jj]);
        p = fmaf(h[j], (&Cv[j].x)[jj], p);
      }
      p += __shfl_xor(p, 16);
      p += __shfl_xor(p, 32);
      if (q == 0)
        Yp[(base + l) * 128 + n] = fmaf(u, Dn, p);
    }
  }
}

// ---------------- out_proj: ((Y)*silu(Z))(16k,128) @ (128,64)^T ----------------
__global__ __launch_bounds__(256) void k_outproj(const float* __restrict__ Y,
                                                 const float* __restrict__ Zg,
                                                 const float* __restrict__ W,
                                                 float* __restrict__ OUT){
  __shared__ float yl[16 * 128];
  __shared__ float wT[128 * 65];
  int tid = threadIdx.x;
  size_t t0 = (size_t)blockIdx.x * 16;
  for (int i = tid; i < 2048; i += 256){
    float z = Zg[t0 * 128 + i];
    yl[i] = Y[t0 * 128 + i] * (z * sigmoidf_(z));
  }
  for (int i = tid; i < 8192; i += 256){
    int k = i & 127, j = i >> 7;
    wT[k * 65 + j] = W[j * 128 + k];
  }
  __syncthreads();
  int j = tid & 63;
  int tg = tid >> 6;
  float acc[4] = {0.f, 0.f, 0.f, 0.f};
  for (int k = 0; k < 128; k += 4){
    float w0 = wT[k * 65 + j], w1 = wT[(k+1) * 65 + j];
    float w2 = wT[(k+2) * 65 + j], w3 = wT[(k+3) * 65 + j];
#pragma unroll
    for (int t = 0; t < 4; t++){
      float4 yv = *(const float4*)&yl[(tg * 4 + t) * 128 + k];
      acc[t] = fmaf(w0, yv.x, fmaf(w1, yv.y, fmaf(w2, yv.z, fmaf(w3, yv.w, acc[t]))));
    }
  }
#pragma unroll
  for (int t = 0; t < 4; t++)
    OUT[(t0 + tg * 4 + t) * 64 + j] = acc[t];
}

// ---------------- softmax over L: partial pass (grid 256 = b4 x lc64) ----------------
__global__ void k_smA(const float* __restrict__ G, float* __restrict__ P){
  int bid = blockIdx.x;
  int b = bid >> 6, lc = bid & 63;
  int tid = threadIdx.x;
  int j = tid & 63, part = tid >> 6;
  size_t base = (size_t)b * 4096 + lc * 64;
  float mx = -3.4e38f;
  for (int i = 0; i < 16; i++){
    int l = part + i * 4;
    mx = fmaxf(mx, G[(base + l) * 64 + j]);
  }
  float sm = 0.f;
  for (int i = 0; i < 16; i++){
    int l = part + i * 4;
    sm += __expf(G[(base + l) * 64 + j] - mx);
  }
  __shared__ float sM[256], sS[256];
  sM[tid] = mx; sS[tid] = sm;
  __syncthreads();
  if (tid < 64){
    float M = sM[tid], S = sS[tid];
    for (int p = 1; p < 4; p++){
      float m2 = sM[p * 64 + tid], s2 = sS[p * 64 + tid];
      float Mn = fmaxf(M, m2);
      S = S * __expf(M - Mn) + s2 * __expf(m2 - Mn);
      M = Mn;
    }
    P[(bid * 64 + tid) * 2] = M;
    P[(bid * 64 + tid) * 2 + 1] = S;
  }
}

__global__ void k_smB(const float* __restrict__ P, float* __restrict__ F){
  int tid = threadIdx.x; // 256 = b(4) x j(64)
  int b = tid >> 6, j = tid & 63;
  float M = -3.4e38f, S = 0.f;
  for (int lc = 0; lc < 64; lc++){
    int idx = ((b * 64 + lc) * 64 + j) * 2;
    float m2 = P[idx], s2 = P[idx + 1];
    float Mn = fmaxf(M, m2);
    S = S * __expf(M - Mn) + s2 * __expf(m2 - Mn);
    M = Mn;
  }
  F[(b * 64 + j) * 2] = M;
  F[(b * 64 + j) * 2 + 1] = S;
}

// ---------------- combine + transpose to (b,c,64,64) ----------------
__global__ void k_combine(const float* __restrict__ T, const float* __restrict__ MAIN,
                          const float* __restrict__ G, const float* __restrict__ F,
                          float* __restrict__ FEAT){
  int bid = blockIdx.x;
  int b = bid >> 6, row = bid & 63;
  int tid = threadIdx.x;
  int j = tid & 63, ls = tid >> 6;
  __shared__ float tile[64 * 65];
  float M = F[(b * 64 + j) * 2], invS = 1.f / F[(b * 64 + j) * 2 + 1];
  size_t lbase = (size_t)b * 4096 + row * 64;
  for (int i = 0; i < 16; i++){
    int col = ls + i * 4;
    size_t off = (lbase + col) * 64 + j;
    float g = __expf(G[off] - M) * invS;
    tile[col * 65 + j] = T[off] + g * MAIN[off];
  }
  __syncthreads();
  int colw = tid & 63, jr = tid >> 6;
  for (int jj = jr; jj < 64; jj += 4)
    FEAT[(((size_t)b * 64 + jj) * 64 + row) * 64 + colw] = tile[colw * 65 + jj];
}

// ---------------- bilinear upsample 64->128 ----------------
__global__ void k_up(const float* __restrict__ FEAT, float* __restrict__ UP){
  size_t idx = (size_t)blockIdx.x * 256 + threadIdx.x;
  int x = idx & 127;
  int y = (idx >> 7) & 127;
  size_t bc = idx >> 14;
  float ay = 0.5f * y - 0.25f;
  float ax = 0.5f * x - 0.25f;
  int fy = (int)floorf(ay); float wy = ay - fy;
  int fx = (int)floorf(ax); float wx = ax - fx;
  int y0 = fy < 0 ? 0 : fy, y1 = fy + 1 > 63 ? 63 : fy + 1;
  int x0 = fx < 0 ? 0 : fx, x1 = fx + 1 > 63 ? 63 : fx + 1;
  const float* p = FEAT + bc * 4096;
  float v = (1.f - wy) * ((1.f - wx) * p[y0 * 64 + x0] + wx * p[y0 * 64 + x1])
          +        wy  * ((1.f - wx) * p[y1 * 64 + x0] + wx * p[y1 * 64 + x1]);
  UP[idx] = v;
}

// ---------------- host launcher ----------------
extern "C" void kernel_launch(void* const* d_in, const int* in_sizes, int n_in,
                              void* d_out, int out_size, void* d_ws, size_t ws_size,
                              hipStream_t stream) {
  // workspace layout (float offsets)
  const size_t P1A = 0, P1B = 4326400, XR = 8652800;
  const size_t MB0 = 0, MB1 = 10027008;
  const size_t O_LN = 0, O_XC = 1048576, O_Z = 3145728, O_U = 5242880,
               O_DT = 7340032, O_DBL = 9437184;
  const size_t TOK = 20054016, OUT0 = 21102592, OUT1 = 22151168;
  const size_t FEAT = 23208448;
  const size_t UPO = 0, P3A = 4194304, P3B = 8520704;
  const size_t WA_H = 19000000, WA_L = 19018432, WB_H = 19036864, WB_L = 19055296;
  const size_t PADN = 2163200;
  const size_t SMP = 0, SMF = 65536;
  const size_t W2_0 = 21102592, B2_0 = 21118976, W2_1 = 21119232, B2_1 = 21135616;
  const size_t TOTAL = 24257024;
  if (ws_size < TOTAL * 4) return;

  float* ws = (float*)d_ws;
  const float* X   = (const float*)d_in[0];
  const float* CB1 = (const float*)d_in[1];
  const float* CB2 = (const float*)d_in[2];
  const float* SW1 = (const float*)d_in[3];
  const float* SW2 = (const float*)d_in[4];
  const float* LNW[2] = { (const float*)d_in[5], (const float*)d_in[7] };
  const float* LNB[2] = { (const float*)d_in[6], (const float*)d_in[8] };
  const float *INW[2], *CW[2], *CBb[2], *XPW[2], *DTW[2], *DTB[2], *AL[2], *DD[2], *OW[2];
  for (int m = 0; m < 2; m++){
    int p = 9 + m * 9;
    INW[m] = (const float*)d_in[p + 0];
    CW[m]  = (const float*)d_in[p + 1];
    CBb[m] = (const float*)d_in[p + 2];
    XPW[m] = (const float*)d_in[p + 3];
    DTW[m] = (const float*)d_in[p + 4];
    DTB[m] = (const float*)d_in[p + 5];
    AL[m]  = (const float*)d_in[p + 6];
    DD[m]  = (const float*)d_in[p + 7];
    OW[m]  = (const float*)d_in[p + 8];
  }
  size_t mb[2] = { MB0, MB1 };
  size_t w2o[2] = { W2_0, W2_1 };
  size_t b2o[2] = { B2_0, B2_1 };

  u16* wah = (u16*)(ws + WA_H); u16* wal = (u16*)(ws + WA_L);
  u16* wbh = (u16*)(ws + WB_H); u16* wbl = (u16*)(ws + WB_L);

  // ---- phase 1: conv block (MFMA) + tokenize (+LN stats) ----
  {
    u16* pah = (u16*)(ws + P1A); u16* pal = pah + PADN * 2;
    u16* pbh = (u16*)(ws + P1B); u16* pbl = pbh + PADN * 2;
    k_wswz<<<144, 256, 0, stream>>>(CB1, wah, wal);
    k_wswz<<<144, 256, 0, stream>>>(CB2, wbh, wbl);
    k_prep<<<dim3(130, 4), 256, 0, stream>>>(X, pah, pal);
    k_bord<<<9, 256, 0, stream>>>(pbh, pbl);
    k_convm<<<dim3(8, 8, 4), 256, 0, stream>>>(pah, pal, wah, wal, nullptr, pbh, pbl, nullptr, 0);
    k_convm<<<dim3(8, 8, 4), 256, 0, stream>>>(pbh, pbl, wbh, wbl, X, nullptr, nullptr, ws + XR, 1);
    k_tok<<<4096, 256, 0, stream>>>(ws + XR, ws + TOK, ws + MB0 + O_LN);
  }

  // ---- phase 2: mamba x2 ----
  for (int m = 0; m < 2; m++)
    k_fold<<<1, 256, 0, stream>>>(INW[m], LNW[m], LNB[m], ws + w2o[m], ws + b2o[m]);
  for (int m = 0; m < 2; m++){
    size_t B = mb[m];
    k_inproj<<<dim3(1024, 2), 256, 0, stream>>>(ws + MB0 + O_LN, ws + w2o[m], ws + b2o[m],
                                                ws + B + O_XC, ws + B + O_Z);
    k_dwconv<<<8192, 256, 0, stream>>>(ws + B + O_XC, CW[m], CBb[m], ws + B + O_U);
  }
  k_xprojdt<<<256, 256, 0, stream>>>(
      ws + MB0 + O_U, XPW[0], DTW[0], DTB[0], ws + MB0 + O_DBL, ws + MB0 + O_DT,
      ws + MB1 + O_U, XPW[1], DTW[1], DTB[1], ws + MB1 + O_DBL, ws + MB1 + O_DT);

  float* HF  = ws + MB0 + O_XC;
  float* AP  = ws + MB0 + O_XC + 1048576;
  float* HIN = ws + MB0 + O_LN;

  k_scanA<<<1024, 256, 0, stream>>>(
      ws + MB0 + O_DT, ws + MB0 + O_DBL, ws + MB0 + O_U, AL[0],
      ws + MB1 + O_DT, ws + MB1 + O_DBL, ws + MB1 + O_U, AL[1],
      HF, AP);
  k_scanB<<<256, 64, 0, stream>>>(HF, AP, HIN);
  k_scanC<<<1024, 256, 0, stream>>>(
      ws + MB0 + O_DT, ws + MB0 + O_DBL, ws + MB0 + O_U, AL[0], DD[0], ws + MB0 + O_XC,
      ws + MB1 + O_DT, ws + MB1 + O_DBL, ws + MB1 + O_U, AL[1], DD[1], ws + MB1 + O_XC,
      HIN);

  k_outproj<<<1024, 256, 0, stream>>>(ws + MB0 + O_XC, ws + MB0 + O_Z, OW[0], ws + OUT0);
  k_outproj<<<1024, 256, 0, stream>>>(ws + MB1 + O_XC, ws + MB1 + O_Z, OW[1], ws + OUT1);

  k_smA<<<256, 256, 0, stream>>>(ws + OUT1, ws + SMP);
  k_smB<<<1, 256, 0, stream>>>(ws + SMP, ws + SMF);
  k_combine<<<256, 256, 0, stream>>>(ws + TOK, ws + OUT0, ws + OUT1, ws + SMF, ws + FEAT);

  // ---- phase 3: upsample + conv block (MFMA) ----
  {
    u16* pah = (u16*)(ws + P3A); u16* pal = pah + PADN * 2;
    u16* pbh = (u16*)(ws + P3B); u16* pbl = pbh + PADN * 2;
    k_up<<<16384, 256, 0, stream>>>(ws + FEAT, ws + UPO);
    k_wswz<<<144, 256, 0, stream>>>(SW1, wah, wal);
    k_wswz<<<144, 256, 0, stream>>>(SW2, wbh, wbl);
    k_prep<<<dim3(130, 4), 256, 0, stream>>>(ws + UPO, pah, pal);
    k_bord<<<9, 256, 0, stream>>>(pbh, pbl);
    k_convm<<<dim3(8, 8, 4), 256, 0, stream>>>(pah, pal, wah, wal, nullptr, pbh, pbl, nullptr, 0);
    k_convm<<<dim3(8, 8, 4), 256, 0, stream>>>(pbh, pbl, wbh, wbl, nullptr, nullptr, nullptr, (float*)d_out, 1);
  }
}

// Round 8
// 496.377 us; speedup vs baseline: 4.9953x; 1.1293x over previous
//
#include <hip/hip_runtime.h>

typedef unsigned int u32;
typedef unsigned short u16;
typedef __attribute__((ext_vector_type(8))) short short8;
typedef __attribute__((ext_vector_type(4))) float f32x4;

__device__ __forceinline__ float sigmoidf_(float x){
  return 1.f / (1.f + __expf(-x));
}
__device__ __forceinline__ u16 f2bf(float f){
  union { float f; u32 i; } v; v.f = f;
  u32 r = v.i + 0x7fffu + ((v.i >> 16) & 1u);
  return (u16)(r >> 16);
}
__device__ __forceinline__ float bf2f(u32 u){
  union { float f; u32 i; } v; v.i = (u & 0xffffu) << 16; return v.f;
}

// ---------------- border zero for padded NHWC bf16 h/l buffers ----------------
__global__ void k_bord(u16* __restrict__ PH, u16* __restrict__ PL){
  int i = blockIdx.x * 256 + threadIdx.x;   // 4 * 516 = 2064 border pixels
  if (i >= 2064) return;
  int b = i / 516, p = i - b * 516;
  int y, x;
  if (p < 130){ y = 0; x = p; }
  else if (p < 260){ y = 129; x = p - 130; }
  else if (p < 388){ y = p - 260 + 1; x = 0; }
  else { y = p - 388 + 1; x = 129; }
  size_t o = (((size_t)b * 130 + y) * 130 + x) * 64;
  uint4 z = make_uint4(0, 0, 0, 0);
#pragma unroll
  for (int q = 0; q < 8; q++){
    *(uint4*)(PH + o + q * 8) = z;
    *(uint4*)(PL + o + q * 8) = z;
  }
}

// ---------------- prep: NCHW fp32 -> padded NHWC bf16 hi/lo ----------------
__global__ __launch_bounds__(256) void k_prep(const float* __restrict__ src,
                                              u16* __restrict__ PH, u16* __restrict__ PL){
  __shared__ float ld[64 * 128];
  int yp = blockIdx.x;          // padded row 0..129
  int b  = blockIdx.y;
  int ys = yp - 1;
  int tid = threadIdx.x;
  if ((u32)ys < 128u){
    for (int i = tid; i < 8192; i += 256){
      int c = i >> 7, x = i & 127;
      ld[i] = src[((size_t)(b * 64 + c) * 128 + ys) * 128 + x];
    }
  }
  __syncthreads();
  for (int i = tid; i < 130 * 64; i += 256){
    int xp = i >> 6, c = i & 63;
    float v = 0.f;
    if ((u32)ys < 128u && (u32)(xp - 1) < 128u) v = ld[c * 128 + (xp - 1)];
    u16 h = f2bf(v);
    u16 l = f2bf(v - bf2f(h));
    size_t o = (((size_t)b * 130 + yp) * 130 + xp) * 64 + c;
    PH[o] = h; PL[o] = l;
  }
}

// ---------------- weight swizzle ----------------
__global__ void k_wswz(const float* __restrict__ w, u16* __restrict__ WH, u16* __restrict__ WL){
  int idx = blockIdx.x * 256 + threadIdx.x;
  if (idx >= 36864) return;
  int j    = idx & 7;
  int lane = (idx >> 3) & 63;
  int nt   = (idx >> 9) & 3;
  int kc   = (idx >> 11) & 1;
  int t    = idx >> 12;           // 0..8
  int ic = kc * 32 + ((lane >> 4) & 3) * 8 + j;
  int oc = nt * 16 + (lane & 15);
  float v = w[(oc * 64 + ic) * 9 + t];
  u16 h = f2bf(v);
  u16 l = f2bf(v - bf2f(h));
  WH[idx] = h; WL[idx] = l;
}

// ---------------- MFMA conv3x3 64->64 ----------------
__global__ __launch_bounds__(256) void k_convm(
    const u16* __restrict__ PH, const u16* __restrict__ PL,
    const u16* __restrict__ WH, const u16* __restrict__ WL,
    const float* __restrict__ resid,
    u16* __restrict__ OBH, u16* __restrict__ OBL,
    float* __restrict__ OUTF, int mode)
{
  __shared__ __align__(16) u32 smem[10368];
  u16* Ah_s = (u16*)smem;
  u16* Al_s = Ah_s + 10368;
  int tid = threadIdx.x;
  int lane = tid & 63, w = tid >> 6;
  int quad = lane >> 4, lcol = lane & 15;
  int b = blockIdx.z, y0 = blockIdx.y * 16, x0 = blockIdx.x * 16;

  f32x4 acc[4][4];
#pragma unroll
  for (int mt = 0; mt < 4; mt++)
#pragma unroll
    for (int nt = 0; nt < 4; nt++)
      acc[mt][nt] = (f32x4){0.f, 0.f, 0.f, 0.f};

  for (int kc = 0; kc < 2; kc++){
    __syncthreads();
    for (int i = tid; i < 1296; i += 256){
      int q = i & 3;
      int rc = i >> 2;
      int r = rc / 18, c = rc - r * 18;
      size_t so = (((size_t)b * 130 + y0 + r) * 130 + (x0 + c)) * 64 + kc * 32 + q * 8;
      int de = (r * 18 + c) * 32 + q * 8;
      *(uint4*)(Ah_s + de) = *(const uint4*)(PH + so);
      *(uint4*)(Al_s + de) = *(const uint4*)(PL + so);
    }
    __syncthreads();
    short8 bh[2][4], bl[2][4];
#pragma unroll
    for (int nt = 0; nt < 4; nt++){
      int o = (kc * 4 + nt) * 512 + lane * 8;
      bh[0][nt] = *(const short8*)(WH + o);
      bl[0][nt] = *(const short8*)(WL + o);
    }
    for (int t = 0; t < 9; t++){
      int cur = t & 1, nxt = cur ^ 1;
      if (t < 8){
#pragma unroll
        for (int nt = 0; nt < 4; nt++){
          int o = (((t + 1) * 2 + kc) * 4 + nt) * 512 + lane * 8;
          bh[nxt][nt] = *(const short8*)(WH + o);
          bl[nxt][nt] = *(const short8*)(WL + o);
        }
      }
      int dy = t / 3, dx = t - dy * 3;
      short8 ah[4], al[4];
#pragma unroll
      for (int mt = 0; mt < 4; mt++){
        int e = ((w * 4 + mt + dy) * 18 + (lcol + dx)) * 32 + quad * 8;
        ah[mt] = *(const short8*)(Ah_s + e);
        al[mt] = *(const short8*)(Al_s + e);
      }
#pragma unroll
      for (int mt = 0; mt < 4; mt++)
#pragma unroll
        for (int nt = 0; nt < 4; nt++){
          acc[mt][nt] = __builtin_amdgcn_mfma_f32_16x16x32_bf16(ah[mt], bh[cur][nt], acc[mt][nt], 0, 0, 0);
          acc[mt][nt] = __builtin_amdgcn_mfma_f32_16x16x32_bf16(ah[mt], bl[cur][nt], acc[mt][nt], 0, 0, 0);
          acc[mt][nt] = __builtin_amdgcn_mfma_f32_16x16x32_bf16(al[mt], bh[cur][nt], acc[mt][nt], 0, 0, 0);
        }
    }
  }

  if (mode == 0){
    u32* epi = smem;
    for (int half = 0; half < 2; half++){
      __syncthreads();
#pragma unroll
      for (int mtl = 0; mtl < 2; mtl++){
        int mt = half * 2 + mtl;
#pragma unroll
        for (int nt = 0; nt < 4; nt++){
#pragma unroll
          for (int reg = 0; reg < 4; reg++){
            float v = fmaxf(acc[mt][nt][reg], 0.f);
            u32 h = f2bf(v);
            u32 l = f2bf(v - bf2f(h));
            int c_loc = quad * 4 + reg;
            int oc = nt * 16 + lcol;
            epi[((w * 2 + mtl) * 16 + c_loc) * 66 + oc] = h | (l << 16);
          }
        }
      }
      __syncthreads();
      for (int i = tid; i < 8192; i += 256){
        int px = i >> 6, oc = i & 63;
        int row8 = px >> 4, c_loc = px & 15;
        int r_loc = (row8 >> 1) * 4 + half * 2 + (row8 & 1);
        u32 pk = epi[(row8 * 16 + c_loc) * 66 + oc];
        size_t o = (((size_t)b * 130 + y0 + r_loc + 1) * 130 + (x0 + c_loc + 1)) * 64 + oc;
        OBH[o] = (u16)pk;
        OBL[o] = (u16)(pk >> 16);
      }
    }
  } else {
    float* epi = (float*)smem;
    for (int half = 0; half < 2; half++){
      __syncthreads();
#pragma unroll
      for (int mtl = 0; mtl < 2; mtl++){
        int mt = half * 2 + mtl;
#pragma unroll
        for (int nt = 0; nt < 4; nt++){
#pragma unroll
          for (int reg = 0; reg < 4; reg++){
            int px = (w * 2 + mtl) * 16 + quad * 4 + reg;
            int oc = nt * 16 + lcol;
            epi[oc * 130 + px] = acc[mt][nt][reg];
          }
        }
      }
      __syncthreads();
      for (int i = tid; i < 8192; i += 256){
        int oc = i >> 7, px = i & 127;
        int row8 = px >> 4, c = px & 15;
        int r_loc = (row8 >> 1) * 4 + half * 2 + (row8 & 1);
        size_t o = (((size_t)b * 64 + oc) * 128 + y0 + r_loc) * 128 + x0 + c;
        float v = epi[oc * 130 + px];
        if (resid) v += resid[o];
        OUTF[o] = v;
      }
    }
  }
}

// ---------------- tokenize (2x2 avg) + fused layernorm stats ----------------
__global__ void k_tok(const float* __restrict__ xr, float* __restrict__ T,
                      float* __restrict__ NT){
  int idx = blockIdx.x * 256 + threadIdx.x; // 4*4096*64
  int c = idx & 63;
  int l = (idx >> 6) & 4095;
  int b = idx >> 18;
  int r = l >> 6, cl = l & 63;
  const float* p = xr + (((size_t)(b * 64 + c) * 128 + 2 * r) * 128 + 2 * cl);
  float t = 0.25f * (p[0] + p[1] + p[128] + p[129]);
  float s = t;
  for (int m = 32; m; m >>= 1) s += __shfl_xor(s, m);
  float mu = s * (1.f / 64.f);
  float d = t - mu;
  float q = d * d;
  for (int m = 32; m; m >>= 1) q += __shfl_xor(q, m);
  float var = q * (1.f / 64.f);
  T[idx] = t;
  NT[idx] = d * rsqrtf(var + 1e-5f);
}

// ---------------- fold LN gamma/beta into in_proj weights ----------------
__global__ __launch_bounds__(256) void k_fold(const float* __restrict__ W,
                                              const float* __restrict__ lnw,
                                              const float* __restrict__ lnb,
                                              float* __restrict__ W2, float* __restrict__ B2){
  __shared__ float gw[64], gb[64];
  int j = threadIdx.x;
  if (j < 64){ gw[j] = lnw[j]; gb[j] = lnb[j]; }
  __syncthreads();
  float bias = 0.f;
#pragma unroll
  for (int k4 = 0; k4 < 16; k4++){
    float4 wv = *(const float4*)&W[j * 64 + k4 * 4];
    W2[j * 64 + k4 * 4 + 0] = wv.x * gw[k4 * 4 + 0];
    W2[j * 64 + k4 * 4 + 1] = wv.y * gw[k4 * 4 + 1];
    W2[j * 64 + k4 * 4 + 2] = wv.z * gw[k4 * 4 + 2];
    W2[j * 64 + k4 * 4 + 3] = wv.w * gw[k4 * 4 + 3];
    bias = fmaf(wv.x, gb[k4 * 4 + 0], bias);
    bias = fmaf(wv.y, gb[k4 * 4 + 1], bias);
    bias = fmaf(wv.z, gb[k4 * 4 + 2], bias);
    bias = fmaf(wv.w, gb[k4 * 4 + 3], bias);
  }
  B2[j] = bias;
}

// ---------------- in_proj (both mambas): NT(16k,64) @ W2(256,64)^T + B2 ----------------
// grid (256, 4, 2): x = 64-token tile, y = 64-col quarter, z = mamba.
// block 256 = tq(16 token groups of 4) x cg(16). thread: 4 tokens x 4 cols
// (cols j0 + cg + 16c -> LDS stride-68 reads are 2-way aliased = free; stores
// 64B-contiguous per quad). NT read from global (lane-broadcast, L1-resident).
__global__ __launch_bounds__(256) void k_inproj(
    const float* __restrict__ NT,
    const float* __restrict__ W2a, const float* __restrict__ B2a,
    float* __restrict__ XCa, float* __restrict__ Za,
    const float* __restrict__ W2b, const float* __restrict__ B2b,
    float* __restrict__ XCb, float* __restrict__ Zb)
{
  __shared__ float wL[64 * 68];
  int mz = blockIdx.z;
  const float* W2 = mz ? W2b : W2a;
  const float* B2 = mz ? B2b : B2a;
  float* XC = mz ? XCb : XCa;
  float* Z  = mz ? Zb  : Za;
  int tid = threadIdx.x;
  int t0 = blockIdx.x * 64;
  int j0 = blockIdx.y * 64;
  for (int i = tid; i < 4096; i += 256){
    int jl = i >> 6, k = i & 63;
    wL[jl * 68 + k] = W2[(size_t)(j0 + jl) * 64 + k];
  }
  __syncthreads();
  int tq = tid >> 4, cg = tid & 15;
  const float* ntp = NT + (size_t)(t0 + tq * 4) * 64;
  float acc[4][4];
#pragma unroll
  for (int c = 0; c < 4; c++){
    float bias = B2[j0 + cg + c * 16];
#pragma unroll
    for (int t = 0; t < 4; t++) acc[t][c] = bias;
  }
#pragma unroll 4
  for (int k4 = 0; k4 < 16; k4++){
    float4 lv[4];
#pragma unroll
    for (int t = 0; t < 4; t++)
      lv[t] = *(const float4*)(ntp + t * 64 + k4 * 4);
    float4 wv[4];
#pragma unroll
    for (int c = 0; c < 4; c++)
      wv[c] = *(const float4*)&wL[(cg + c * 16) * 68 + k4 * 4];
#pragma unroll
    for (int t = 0; t < 4; t++)
#pragma unroll
      for (int c = 0; c < 4; c++){
        acc[t][c] = fmaf(lv[t].x, wv[c].x, acc[t][c]);
        acc[t][c] = fmaf(lv[t].y, wv[c].y, acc[t][c]);
        acc[t][c] = fmaf(lv[t].z, wv[c].z, acc[t][c]);
        acc[t][c] = fmaf(lv[t].w, wv[c].w, acc[t][c]);
      }
  }
  if (j0 < 128){
#pragma unroll
    for (int t = 0; t < 4; t++){
      size_t tg = t0 + tq * 4 + t;
#pragma unroll
      for (int c = 0; c < 4; c++)
        XC[tg * 128 + j0 + cg + c * 16] = acc[t][c];
    }
  } else {
#pragma unroll
    for (int t = 0; t < 4; t++){
      size_t tg = t0 + tq * 4 + t;
#pragma unroll
      for (int c = 0; c < 4; c++)
        Z[tg * 128 + (j0 - 128) + cg + c * 16] = acc[t][c];
    }
  }
}

// ---------------- causal depthwise conv(4) + bias + silu ----------------
__global__ void k_dwconv(const float* __restrict__ XC, const float* __restrict__ cw,
                         const float* __restrict__ cb, float* __restrict__ U){
  int idx = blockIdx.x * 256 + threadIdx.x; // 4*4096*128
  int n = idx & 127;
  int l = (idx >> 7) & 4095;
  float4 wv = *(const float4*)(cw + n * 4);
  float a = cb[n];
  a = fmaf(wv.w, XC[idx], a);
  if (l >= 1) a = fmaf(wv.z, XC[idx - 128], a);
  if (l >= 2) a = fmaf(wv.y, XC[idx - 256], a);
  if (l >= 3) a = fmaf(wv.x, XC[idx - 384], a);
  U[idx] = a * sigmoidf_(a);
}

// ---------------- fused x_proj + dt (both mambas) ----------------
__global__ __launch_bounds__(256) void k_xprojdt(
    const float* __restrict__ U0, const float* __restrict__ XW0,
    const float* __restrict__ DTW0, const float* __restrict__ DTB0,
    float* __restrict__ DBL0, float* __restrict__ DT0,
    const float* __restrict__ U1, const float* __restrict__ XW1,
    const float* __restrict__ DTW1, const float* __restrict__ DTB1,
    float* __restrict__ DBL1, float* __restrict__ DT1)
{
  __shared__ float xw[36 * 132];
  __shared__ float sdtr[128 * 4];
  int bid = blockIdx.x;
  int m = bid >> 7, blk = bid & 127;
  const float* Up   = m ? U1   : U0;
  const float* XWp  = m ? XW1  : XW0;
  const float* DTWp = m ? DTW1 : DTW0;
  const float* DTBp = m ? DTB1 : DTB0;
  float* DBLp = m ? DBL1 : DBL0;
  float* DTp  = m ? DT1  : DT0;
  int tid = threadIdx.x;
  for (int i = tid; i < 4608; i += 256)
    xw[(i >> 7) * 132 + (i & 127)] = XWp[i];
  __syncthreads();
  int slot = tid >> 2, jq = tid & 3;
  size_t tgA = (size_t)blk * 128 + slot;
  size_t tgB = tgA + 64;
  const float4* upA = (const float4*)(Up + tgA * 128);
  const float4* upB = (const float4*)(Up + tgB * 128);
  float accA[9], accB[9];
#pragma unroll
  for (int jj = 0; jj < 9; jj++){ accA[jj] = 0.f; accB[jj] = 0.f; }
  for (int k4 = 0; k4 < 32; k4++){
    float4 uA = upA[k4];
    float4 uB = upB[k4];
#pragma unroll
    for (int jj = 0; jj < 9; jj++){
      float4 w = *(const float4*)&xw[(jq * 9 + jj) * 132 + k4 * 4];
      accA[jj] = fmaf(w.x, uA.x, fmaf(w.y, uA.y, fmaf(w.z, uA.z, fmaf(w.w, uA.w, accA[jj]))));
      accB[jj] = fmaf(w.x, uB.x, fmaf(w.y, uB.y, fmaf(w.z, uB.z, fmaf(w.w, uB.w, accB[jj]))));
    }
  }
#pragma unroll
  for (int jj = 0; jj < 9; jj++){
    DBLp[tgA * 36 + jq * 9 + jj] = accA[jj];
    DBLp[tgB * 36 + jq * 9 + jj] = accB[jj];
  }
  if (jq == 0){
#pragma unroll
    for (int jj = 0; jj < 4; jj++){
      sdtr[slot * 4 + jj] = accA[jj];
      sdtr[(slot + 64) * 4 + jj] = accB[jj];
    }
  }
  __syncthreads();
  int ch = tid & 127, half = tid >> 7;
  float4 wv = *(const float4*)(DTWp + ch * 4);
  float bias = DTBp[ch];
  for (int i = 0; i < 64; i++){
    int tl = half * 64 + i;
    float4 d = *(const float4*)&sdtr[tl * 4];
    float x = bias;
    x = fmaf(wv.x, d.x, x); x = fmaf(wv.y, d.y, x);
    x = fmaf(wv.z, d.z, x); x = fmaf(wv.w, d.w, x);
    x = fmaxf(x, 0.f) + log1pf(__expf(-fabsf(x)));
    DTp[((size_t)blk * 128 + tl) * 128 + ch] = x;
  }
}

// ================= chunked parallel scan (4 states/thread) =================
__global__ __launch_bounds__(256) void k_scanA(
    const float* __restrict__ DT0, const float* __restrict__ DBL0, const float* __restrict__ U0,
    const float* __restrict__ AL0,
    const float* __restrict__ DT1, const float* __restrict__ DBL1, const float* __restrict__ U1,
    const float* __restrict__ AL1,
    float* __restrict__ HF, float* __restrict__ AP)
{
  __shared__ float sdt[64 * 65], su[64 * 65], sB[16 * 68];
  int bid = blockIdx.x;
  int cg = bid & 1;
  int c  = (bid >> 1) & 63;
  int b  = (bid >> 7) & 3;
  int m  = bid >> 9;
  const float* DTp  = m ? DT1  : DT0;
  const float* DBLp = m ? DBL1 : DBL0;
  const float* Up   = m ? U1   : U0;
  const float* ALp  = m ? AL1  : AL0;
  int tid = threadIdx.x;
  int lane = tid & 63, w = tid >> 6;
  int lcol = lane & 15, q = lane >> 4;
  int chL = w * 16 + lcol;
  int n = cg * 64 + chL;
  size_t base = (size_t)b * 4096 + c * 64;
  for (int i = tid; i < 4096; i += 256){
    int ch = i & 63, l = i >> 6;
    size_t off = (base + l) * 128 + cg * 64 + ch;
    sdt[l * 65 + ch] = DTp[off];
    su[l * 65 + ch]  = Up[off];
  }
  for (int i = tid; i < 1024; i += 256){
    int s = i & 15, l = i >> 4;
    sB[s * 68 + l] = DBLp[(base + l) * 36 + 4 + s];
  }
  float A1[4];
#pragma unroll
  for (int j = 0; j < 4; j++) A1[j] = -__expf(ALp[n * 16 + q * 4 + j]);
  __syncthreads();
  float h[4] = {0.f, 0.f, 0.f, 0.f};
  float ap[4] = {1.f, 1.f, 1.f, 1.f};
#pragma unroll
  for (int l4 = 0; l4 < 16; l4++){
    float4 Bv[4];
#pragma unroll
    for (int j = 0; j < 4; j++) Bv[j] = *(const float4*)&sB[(q * 4 + j) * 68 + l4 * 4];
#pragma unroll
    for (int jj = 0; jj < 4; jj++){
      int l = l4 * 4 + jj;
      float dt = sdt[l * 65 + chL];
      float u  = su[l * 65 + chL];
      float dtu = dt * u;
#pragma unroll
      for (int j = 0; j < 4; j++){
        float a = __expf(dt * A1[j]);
        h[j] = fmaf(a, h[j], dtu * (&Bv[j].x)[jj]);
        ap[j] *= a;
      }
    }
  }
  size_t o = ((size_t)((m * 4 + b) * 64 + c)) * 2048 + n * 16 + q * 4;
  *(float4*)&HF[o] = make_float4(h[0], h[1], h[2], h[3]);
  *(float4*)&AP[o] = make_float4(ap[0], ap[1], ap[2], ap[3]);
}

__global__ __launch_bounds__(64) void k_scanB(
    const float* __restrict__ HF, const float* __restrict__ AP, float* __restrict__ HIN)
{
  int r = blockIdx.x * 64 + threadIdx.x;
  int q = r >> 11;        // (m*4+b)
  int p = r & 2047;       // n*16+s
  float h = 0.f;
  for (int c = 0; c < 64; c++){
    size_t o = (size_t)(q * 64 + c) * 2048 + p;
    HIN[o] = h;
    h = fmaf(AP[o], h, HF[o]);
  }
}

__global__ __launch_bounds__(256) void k_scanC(
    const float* __restrict__ DT0, const float* __restrict__ DBL0, const float* __restrict__ U0,
    const float* __restrict__ AL0, const float* __restrict__ D0, float* __restrict__ Y0,
    const float* __restrict__ DT1, const float* __restrict__ DBL1, const float* __restrict__ U1,
    const float* __restrict__ AL1, const float* __restrict__ D1, float* __restrict__ Y1,
    const float* __restrict__ HIN)
{
  __shared__ float sdt[64 * 65], su[64 * 65], sB[16 * 68], sC[16 * 68];
  int bid = blockIdx.x;
  int cg = bid & 1;
  int c  = (bid >> 1) & 63;
  int b  = (bid >> 7) & 3;
  int m  = bid >> 9;
  const float* DTp  = m ? DT1  : DT0;
  const float* DBLp = m ? DBL1 : DBL0;
  const float* Up   = m ? U1   : U0;
  const float* ALp  = m ? AL1  : AL0;
  const float* Dp   = m ? D1   : D0;
  float*       Yp   = m ? Y1   : Y0;
  int tid = threadIdx.x;
  int lane = tid & 63, w = tid >> 6;
  int lcol = lane & 15, q = lane >> 4;
  int chL = w * 16 + lcol;
  int n = cg * 64 + chL;
  size_t base = (size_t)b * 4096 + c * 64;
  for (int i = tid; i < 4096; i += 256){
    int ch = i & 63, l = i >> 6;
    size_t off = (base + l) * 128 + cg * 64 + ch;
    sdt[l * 65 + ch] = DTp[off];
    su[l * 65 + ch]  = Up[off];
  }
  for (int i = tid; i < 1024; i += 256){
    int s = i & 15, l = i >> 4;
    size_t ob = (base + l) * 36;
    sB[s * 68 + l] = DBLp[ob + 4 + s];
    sC[s * 68 + l] = DBLp[ob + 20 + s];
  }
  float A1[4];
#pragma unroll
  for (int j = 0; j < 4; j++) A1[j] = -__expf(ALp[n * 16 + q * 4 + j]);
  float Dn = Dp[n];
  float4 hv = *(const float4*)&HIN[((size_t)((m * 4 + b) * 64 + c)) * 2048 + n * 16 + q * 4];
  float h[4] = {hv.x, hv.y, hv.z, hv.w};
  __syncthreads();
#pragma unroll
  for (int l4 = 0; l4 < 16; l4++){
    float4 Bv[4], Cv[4];
#pragma unroll
    for (int j = 0; j < 4; j++){
      Bv[j] = *(const float4*)&sB[(q * 4 + j) * 68 + l4 * 4];
      Cv[j] = *(const float4*)&sC[(q * 4 + j) * 68 + l4 * 4];
    }
#pragma unroll
    for (int jj = 0; jj < 4; jj++){
      int l = l4 * 4 + jj;
      float dt = sdt[l * 65 + chL];
      float u  = su[l * 65 + chL];
      float dtu = dt * u;
      float p = 0.f;
#pragma unroll
      for (int j = 0; j < 4; j++){
        float a = __expf(dt * A1[j]);
        h[j] = fmaf(a, h[j], dtu * (&Bv[j].x)[jj]);
        p = fmaf(h[j], (&Cv[j].x)[jj], p);
      }
      p += __shfl_xor(p, 16);
      p += __shfl_xor(p, 32);
      if (q == 0)
        Yp[(base + l) * 128 + n] = fmaf(u, Dn, p);
    }
  }
}

// ---------------- out_proj: ((Y)*silu(Z))(16k,128) @ (128,64)^T ----------------
__global__ __launch_bounds__(256) void k_outproj(const float* __restrict__ Y,
                                                 const float* __restrict__ Zg,
                                                 const float* __restrict__ W,
                                                 float* __restrict__ OUT){
  __shared__ float yl[16 * 128];
  __shared__ float wT[128 * 65];
  int tid = threadIdx.x;
  size_t t0 = (size_t)blockIdx.x * 16;
  for (int i = tid; i < 2048; i += 256){
    float z = Zg[t0 * 128 + i];
    yl[i] = Y[t0 * 128 + i] * (z * sigmoidf_(z));
  }
  for (int i = tid; i < 8192; i += 256){
    int k = i & 127, j = i >> 7;
    wT[k * 65 + j] = W[j * 128 + k];
  }
  __syncthreads();
  int j = tid & 63;
  int tg = tid >> 6;
  float acc[4] = {0.f, 0.f, 0.f, 0.f};
  for (int k = 0; k < 128; k += 4){
    float w0 = wT[k * 65 + j], w1 = wT[(k+1) * 65 + j];
    float w2 = wT[(k+2) * 65 + j], w3 = wT[(k+3) * 65 + j];
#pragma unroll
    for (int t = 0; t < 4; t++){
      float4 yv = *(const float4*)&yl[(tg * 4 + t) * 128 + k];
      acc[t] = fmaf(w0, yv.x, fmaf(w1, yv.y, fmaf(w2, yv.z, fmaf(w3, yv.w, acc[t]))));
    }
  }
#pragma unroll
  for (int t = 0; t < 4; t++)
    OUT[(t0 + tg * 4 + t) * 64 + j] = acc[t];
}

// ---------------- softmax over L: partial pass (grid 256 = b4 x lc64) ----------------
__global__ void k_smA(const float* __restrict__ G, float* __restrict__ P){
  int bid = blockIdx.x;
  int b = bid >> 6, lc = bid & 63;
  int tid = threadIdx.x;
  int j = tid & 63, part = tid >> 6;
  size_t base = (size_t)b * 4096 + lc * 64;
  float mx = -3.4e38f;
  for (int i = 0; i < 16; i++){
    int l = part + i * 4;
    mx = fmaxf(mx, G[(base + l) * 64 + j]);
  }
  float sm = 0.f;
  for (int i = 0; i < 16; i++){
    int l = part + i * 4;
    sm += __expf(G[(base + l) * 64 + j] - mx);
  }
  __shared__ float sM[256], sS[256];
  sM[tid] = mx; sS[tid] = sm;
  __syncthreads();
  if (tid < 64){
    float M = sM[tid], S = sS[tid];
    for (int p = 1; p < 4; p++){
      float m2 = sM[p * 64 + tid], s2 = sS[p * 64 + tid];
      float Mn = fmaxf(M, m2);
      S = S * __expf(M - Mn) + s2 * __expf(m2 - Mn);
      M = Mn;
    }
    P[(bid * 64 + tid) * 2] = M;
    P[(bid * 64 + tid) * 2 + 1] = S;
  }
}

__global__ void k_smB(const float* __restrict__ P, float* __restrict__ F){
  int tid = threadIdx.x; // 256 = b(4) x j(64)
  int b = tid >> 6, j = tid & 63;
  float M = -3.4e38f, S = 0.f;
  for (int lc = 0; lc < 64; lc++){
    int idx = ((b * 64 + lc) * 64 + j) * 2;
    float m2 = P[idx], s2 = P[idx + 1];
    float Mn = fmaxf(M, m2);
    S = S * __expf(M - Mn) + s2 * __expf(m2 - Mn);
    M = Mn;
  }
  F[(b * 64 + j) * 2] = M;
  F[(b * 64 + j) * 2 + 1] = S;
}

// ---------------- combine + transpose to (b,c,64,64) ----------------
__global__ void k_combine(const float* __restrict__ T, const float* __restrict__ MAIN,
                          const float* __restrict__ G, const float* __restrict__ F,
                          float* __restrict__ FEAT){
  int bid = blockIdx.x;
  int b = bid >> 6, row = bid & 63;
  int tid = threadIdx.x;
  int j = tid & 63, ls = tid >> 6;
  __shared__ float tile[64 * 65];
  float M = F[(b * 64 + j) * 2], invS = 1.f / F[(b * 64 + j) * 2 + 1];
  size_t lbase = (size_t)b * 4096 + row * 64;
  for (int i = 0; i < 16; i++){
    int col = ls + i * 4;
    size_t off = (lbase + col) * 64 + j;
    float g = __expf(G[off] - M) * invS;
    tile[col * 65 + j] = T[off] + g * MAIN[off];
  }
  __syncthreads();
  int colw = tid & 63, jr = tid >> 6;
  for (int jj = jr; jj < 64; jj += 4)
    FEAT[(((size_t)b * 64 + jj) * 64 + row) * 64 + colw] = tile[colw * 65 + jj];
}

// ---------------- bilinear upsample 64->128 ----------------
__global__ void k_up(const float* __restrict__ FEAT, float* __restrict__ UP){
  size_t idx = (size_t)blockIdx.x * 256 + threadIdx.x;
  int x = idx & 127;
  int y = (idx >> 7) & 127;
  size_t bc = idx >> 14;
  float ay = 0.5f * y - 0.25f;
  float ax = 0.5f * x - 0.25f;
  int fy = (int)floorf(ay); float wy = ay - fy;
  int fx = (int)floorf(ax); float wx = ax - fx;
  int y0 = fy < 0 ? 0 : fy, y1 = fy + 1 > 63 ? 63 : fy + 1;
  int x0 = fx < 0 ? 0 : fx, x1 = fx + 1 > 63 ? 63 : fx + 1;
  const float* p = FEAT + bc * 4096;
  float v = (1.f - wy) * ((1.f - wx) * p[y0 * 64 + x0] + wx * p[y0 * 64 + x1])
          +        wy  * ((1.f - wx) * p[y1 * 64 + x0] + wx * p[y1 * 64 + x1]);
  UP[idx] = v;
}

// ---------------- host launcher ----------------
extern "C" void kernel_launch(void* const* d_in, const int* in_sizes, int n_in,
                              void* d_out, int out_size, void* d_ws, size_t ws_size,
                              hipStream_t stream) {
  // workspace layout (float offsets)
  const size_t P1A = 0, P1B = 4326400, XR = 8652800;
  const size_t MB0 = 0, MB1 = 10027008;
  const size_t O_LN = 0, O_XC = 1048576, O_Z = 3145728, O_U = 5242880,
               O_DT = 7340032, O_DBL = 9437184;
  const size_t TOK = 20054016, OUT0 = 21102592, OUT1 = 22151168;
  const size_t FEAT = 23208448;
  const size_t UPO = 0, P3A = 4194304, P3B = 8520704;
  const size_t WA_H = 19000000, WA_L = 19018432, WB_H = 19036864, WB_L = 19055296;
  const size_t PADN = 2163200;
  const size_t SMP = 0, SMF = 65536;
  const size_t W2_0 = 21102592, B2_0 = 21118976, W2_1 = 21119232, B2_1 = 21135616;
  const size_t TOTAL = 24257024;
  if (ws_size < TOTAL * 4) return;

  float* ws = (float*)d_ws;
  const float* X   = (const float*)d_in[0];
  const float* CB1 = (const float*)d_in[1];
  const float* CB2 = (const float*)d_in[2];
  const float* SW1 = (const float*)d_in[3];
  const float* SW2 = (const float*)d_in[4];
  const float* LNW[2] = { (const float*)d_in[5], (const float*)d_in[7] };
  const float* LNB[2] = { (const float*)d_in[6], (const float*)d_in[8] };
  const float *INW[2], *CW[2], *CBb[2], *XPW[2], *DTW[2], *DTB[2], *AL[2], *DD[2], *OW[2];
  for (int m = 0; m < 2; m++){
    int p = 9 + m * 9;
    INW[m] = (const float*)d_in[p + 0];
    CW[m]  = (const float*)d_in[p + 1];
    CBb[m] = (const float*)d_in[p + 2];
    XPW[m] = (const float*)d_in[p + 3];
    DTW[m] = (const float*)d_in[p + 4];
    DTB[m] = (const float*)d_in[p + 5];
    AL[m]  = (const float*)d_in[p + 6];
    DD[m]  = (const float*)d_in[p + 7];
    OW[m]  = (const float*)d_in[p + 8];
  }
  size_t mb[2] = { MB0, MB1 };
  size_t w2o[2] = { W2_0, W2_1 };
  size_t b2o[2] = { B2_0, B2_1 };

  u16* wah = (u16*)(ws + WA_H); u16* wal = (u16*)(ws + WA_L);
  u16* wbh = (u16*)(ws + WB_H); u16* wbl = (u16*)(ws + WB_L);

  // ---- phase 1: conv block (MFMA) + tokenize (+LN stats) ----
  {
    u16* pah = (u16*)(ws + P1A); u16* pal = pah + PADN * 2;
    u16* pbh = (u16*)(ws + P1B); u16* pbl = pbh + PADN * 2;
    k_wswz<<<144, 256, 0, stream>>>(CB1, wah, wal);
    k_wswz<<<144, 256, 0, stream>>>(CB2, wbh, wbl);
    k_prep<<<dim3(130, 4), 256, 0, stream>>>(X, pah, pal);
    k_bord<<<9, 256, 0, stream>>>(pbh, pbl);
    k_convm<<<dim3(8, 8, 4), 256, 0, stream>>>(pah, pal, wah, wal, nullptr, pbh, pbl, nullptr, 0);
    k_convm<<<dim3(8, 8, 4), 256, 0, stream>>>(pbh, pbl, wbh, wbl, X, nullptr, nullptr, ws + XR, 1);
    k_tok<<<4096, 256, 0, stream>>>(ws + XR, ws + TOK, ws + MB0 + O_LN);
  }

  // ---- phase 2: mamba x2 ----
  for (int m = 0; m < 2; m++)
    k_fold<<<1, 256, 0, stream>>>(INW[m], LNW[m], LNB[m], ws + w2o[m], ws + b2o[m]);
  k_inproj<<<dim3(256, 4, 2), 256, 0, stream>>>(
      ws + MB0 + O_LN,
      ws + W2_0, ws + B2_0, ws + MB0 + O_XC, ws + MB0 + O_Z,
      ws + W2_1, ws + B2_1, ws + MB1 + O_XC, ws + MB1 + O_Z);
  for (int m = 0; m < 2; m++){
    size_t B = mb[m];
    k_dwconv<<<8192, 256, 0, stream>>>(ws + B + O_XC, CW[m], CBb[m], ws + B + O_U);
  }
  k_xprojdt<<<256, 256, 0, stream>>>(
      ws + MB0 + O_U, XPW[0], DTW[0], DTB[0], ws + MB0 + O_DBL, ws + MB0 + O_DT,
      ws + MB1 + O_U, XPW[1], DTW[1], DTB[1], ws + MB1 + O_DBL, ws + MB1 + O_DT);

  float* HF  = ws + MB0 + O_XC;
  float* AP  = ws + MB0 + O_XC + 1048576;
  float* HIN = ws + MB0 + O_LN;

  k_scanA<<<1024, 256, 0, stream>>>(
      ws + MB0 + O_DT, ws + MB0 + O_DBL, ws + MB0 + O_U, AL[0],
      ws + MB1 + O_DT, ws + MB1 + O_DBL, ws + MB1 + O_U, AL[1],
      HF, AP);
  k_scanB<<<256, 64, 0, stream>>>(HF, AP, HIN);
  k_scanC<<<1024, 256, 0, stream>>>(
      ws + MB0 + O_DT, ws + MB0 + O_DBL, ws + MB0 + O_U, AL[0], DD[0], ws + MB0 + O_XC,
      ws + MB1 + O_DT, ws + MB1 + O_DBL, ws + MB1 + O_U, AL[1], DD[1], ws + MB1 + O_XC,
      HIN);

  k_outproj<<<1024, 256, 0, stream>>>(ws + MB0 + O_XC, ws + MB0 + O_Z, OW[0], ws + OUT0);
  k_outproj<<<1024, 256, 0, stream>>>(ws + MB1 + O_XC, ws + MB1 + O_Z, OW[1], ws + OUT1);

  k_smA<<<256, 256, 0, stream>>>(ws + OUT1, ws + SMP);
  k_smB<<<1, 256, 0, stream>>>(ws + SMP, ws + SMF);
  k_combine<<<256, 256, 0, stream>>>(ws + TOK, ws + OUT0, ws + OUT1, ws + SMF, ws + FEAT);

  // ---- phase 3: upsample + conv block (MFMA) ----
  {
    u16* pah = (u16*)(ws + P3A); u16* pal = pah + PADN * 2;
    u16* pbh = (u16*)(ws + P3B); u16* pbl = pbh + PADN * 2;
    k_up<<<16384, 256, 0, stream>>>(ws + FEAT, ws + UPO);
    k_wswz<<<144, 256, 0, stream>>>(SW1, wah, wal);
    k_wswz<<<144, 256, 0, stream>>>(SW2, wbh, wbl);
    k_prep<<<dim3(130, 4), 256, 0, stream>>>(ws + UPO, pah, pal);
    k_bord<<<9, 256, 0, stream>>>(pbh, pbl);
    k_convm<<<dim3(8, 8, 4), 256, 0, stream>>>(pah, pal, wah, wal, nullptr, pbh, pbl, nullptr, 0);
    k_convm<<<dim3(8, 8, 4), 256, 0, stream>>>(pbh, pbl, wbh, wbl, nullptr, nullptr, nullptr, (float*)d_out, 1);
  }
}

// Round 9
// 449.928 us; speedup vs baseline: 5.5110x; 1.1032x over previous
//
#include <hip/hip_runtime.h>

typedef unsigned int u32;
typedef unsigned short u16;
typedef __attribute__((ext_vector_type(8))) short short8;
typedef __attribute__((ext_vector_type(4))) float f32x4;

__device__ __forceinline__ float sigmoidf_(float x){
  return 1.f / (1.f + __expf(-x));
}
__device__ __forceinline__ u16 f2bf(float f){
  union { float f; u32 i; } v; v.f = f;
  u32 r = v.i + 0x7fffu + ((v.i >> 16) & 1u);
  return (u16)(r >> 16);
}
__device__ __forceinline__ float bf2f(u32 u){
  union { float f; u32 i; } v; v.i = (u & 0xffffu) << 16; return v.f;
}

// ---------------- border zero for padded NHWC bf16 h/l buffers ----------------
__global__ void k_bord(u16* __restrict__ PH, u16* __restrict__ PL){
  int i = blockIdx.x * 256 + threadIdx.x;   // 4 * 516 = 2064 border pixels
  if (i >= 2064) return;
  int b = i / 516, p = i - b * 516;
  int y, x;
  if (p < 130){ y = 0; x = p; }
  else if (p < 260){ y = 129; x = p - 130; }
  else if (p < 388){ y = p - 260 + 1; x = 0; }
  else { y = p - 388 + 1; x = 129; }
  size_t o = (((size_t)b * 130 + y) * 130 + x) * 64;
  uint4 z = make_uint4(0, 0, 0, 0);
#pragma unroll
  for (int q = 0; q < 8; q++){
    *(uint4*)(PH + o + q * 8) = z;
    *(uint4*)(PL + o + q * 8) = z;
  }
}

// ---------------- prep: NCHW fp32 -> padded NHWC bf16 hi/lo ----------------
__global__ __launch_bounds__(256) void k_prep(const float* __restrict__ src,
                                              u16* __restrict__ PH, u16* __restrict__ PL){
  __shared__ float ld[64 * 128];
  int yp = blockIdx.x;          // padded row 0..129
  int b  = blockIdx.y;
  int ys = yp - 1;
  int tid = threadIdx.x;
  if ((u32)ys < 128u){
    for (int i = tid; i < 8192; i += 256){
      int c = i >> 7, x = i & 127;
      ld[i] = src[((size_t)(b * 64 + c) * 128 + ys) * 128 + x];
    }
  }
  __syncthreads();
  for (int i = tid; i < 130 * 64; i += 256){
    int xp = i >> 6, c = i & 63;
    float v = 0.f;
    if ((u32)ys < 128u && (u32)(xp - 1) < 128u) v = ld[c * 128 + (xp - 1)];
    u16 h = f2bf(v);
    u16 l = f2bf(v - bf2f(h));
    size_t o = (((size_t)b * 130 + yp) * 130 + xp) * 64 + c;
    PH[o] = h; PL[o] = l;
  }
}

// ---------------- weight swizzle (two weight sets per launch) ----------------
__global__ void k_wswz2(const float* __restrict__ wA, u16* __restrict__ WHA, u16* __restrict__ WLA,
                        const float* __restrict__ wB, u16* __restrict__ WHB, u16* __restrict__ WLB){
  int gidx = blockIdx.x * 256 + threadIdx.x;   // grid 288 -> 73728
  int sel = gidx >= 36864;
  int idx = gidx - sel * 36864;
  const float* w = sel ? wB : wA;
  u16* WH = sel ? WHB : WHA;
  u16* WL = sel ? WLB : WLA;
  int j    = idx & 7;
  int lane = (idx >> 3) & 63;
  int nt   = (idx >> 9) & 3;
  int kc   = (idx >> 11) & 1;
  int t    = idx >> 12;           // 0..8
  int ic = kc * 32 + ((lane >> 4) & 3) * 8 + j;
  int oc = nt * 16 + (lane & 15);
  float v = w[(oc * 64 + ic) * 9 + t];
  u16 h = f2bf(v);
  u16 l = f2bf(v - bf2f(h));
  WH[idx] = h; WL[idx] = l;
}

// ---------------- MFMA conv3x3 64->64 ----------------
// grid (8,16,4): 16x8 px tile, all 64 oc. block 256 = 4 waves; wave w = rows
// {2w, 2w+1}. 512 blocks = 2 blocks/CU min, LDS 33.8KB -> 4 blocks/CU.
__global__ __launch_bounds__(256) void k_convm(
    const u16* __restrict__ PH, const u16* __restrict__ PL,
    const u16* __restrict__ WH, const u16* __restrict__ WL,
    const float* __restrict__ resid,
    u16* __restrict__ OBH, u16* __restrict__ OBL,
    float* __restrict__ OUTF, int mode)
{
  __shared__ __align__(16) u32 smem[8448];   // max(stage 5760, epi 8448)
  u16* Ah_s = (u16*)smem;                    // 5760 u16: [10r][18c][32ic]
  u16* Al_s = Ah_s + 5760;
  int tid = threadIdx.x;
  int lane = tid & 63, w = tid >> 6;
  int quad = lane >> 4, lcol = lane & 15;
  int b = blockIdx.z, y0 = blockIdx.y * 8, x0 = blockIdx.x * 16;

  f32x4 acc[2][4];
#pragma unroll
  for (int mt = 0; mt < 2; mt++)
#pragma unroll
    for (int nt = 0; nt < 4; nt++)
      acc[mt][nt] = (f32x4){0.f, 0.f, 0.f, 0.f};

  for (int kc = 0; kc < 2; kc++){
    __syncthreads();
    // stage 10x18 halo x 32 ic, hi+lo
    for (int i = tid; i < 720; i += 256){
      int q = i & 3;
      int rc = i >> 2;
      int r = rc / 18, c = rc - r * 18;
      size_t so = (((size_t)b * 130 + y0 + r) * 130 + (x0 + c)) * 64 + kc * 32 + q * 8;
      int de = (r * 18 + c) * 32 + q * 8;
      *(uint4*)(Ah_s + de) = *(const uint4*)(PH + so);
      *(uint4*)(Al_s + de) = *(const uint4*)(PL + so);
    }
    __syncthreads();
#pragma unroll
    for (int t = 0; t < 9; t++){
      int dy = t / 3, dx = t - dy * 3;
      short8 bh[4], bl[4];
#pragma unroll
      for (int nt = 0; nt < 4; nt++){
        int o = ((t * 2 + kc) * 4 + nt) * 512 + lane * 8;
        bh[nt] = *(const short8*)(WH + o);
        bl[nt] = *(const short8*)(WL + o);
      }
      short8 ah[2], al[2];
#pragma unroll
      for (int mt = 0; mt < 2; mt++){
        int e = ((w * 2 + mt + dy) * 18 + (lcol + dx)) * 32 + quad * 8;
        ah[mt] = *(const short8*)(Ah_s + e);
        al[mt] = *(const short8*)(Al_s + e);
      }
#pragma unroll
      for (int mt = 0; mt < 2; mt++)
#pragma unroll
        for (int nt = 0; nt < 4; nt++){
          acc[mt][nt] = __builtin_amdgcn_mfma_f32_16x16x32_bf16(ah[mt], bh[nt], acc[mt][nt], 0, 0, 0);
          acc[mt][nt] = __builtin_amdgcn_mfma_f32_16x16x32_bf16(ah[mt], bl[nt], acc[mt][nt], 0, 0, 0);
          acc[mt][nt] = __builtin_amdgcn_mfma_f32_16x16x32_bf16(al[mt], bh[nt], acc[mt][nt], 0, 0, 0);
        }
    }
  }

  // epilogue. C-frag: col(lane&15)=oc-in-tile, row(quad*4+reg)=px-col.
  __syncthreads();
  if (mode == 0){
    u32* epi = smem;   // [px 128][oc 66]
#pragma unroll
    for (int mt = 0; mt < 2; mt++){
      int row = w * 2 + mt;
#pragma unroll
      for (int nt = 0; nt < 4; nt++){
#pragma unroll
        for (int reg = 0; reg < 4; reg++){
          float v = fmaxf(acc[mt][nt][reg], 0.f);
          u32 h = f2bf(v);
          u32 l = f2bf(v - bf2f(h));
          int ccol = quad * 4 + reg;
          int oc = nt * 16 + lcol;
          epi[(row * 16 + ccol) * 66 + oc] = h | (l << 16);
        }
      }
    }
    __syncthreads();
    for (int i = tid; i < 8192; i += 256){
      int px = i >> 6, oc = i & 63;
      int row = px >> 4, ccol = px & 15;
      u32 pk = epi[px * 66 + oc];
      size_t o = (((size_t)b * 130 + y0 + row + 1) * 130 + (x0 + ccol + 1)) * 64 + oc;
      OBH[o] = (u16)pk;
      OBL[o] = (u16)(pk >> 16);
    }
  } else {
    float* epi = (float*)smem;  // [oc 64][px 131]
#pragma unroll
    for (int mt = 0; mt < 2; mt++){
      int row = w * 2 + mt;
#pragma unroll
      for (int nt = 0; nt < 4; nt++){
#pragma unroll
        for (int reg = 0; reg < 4; reg++){
          int px = row * 16 + quad * 4 + reg;
          int oc = nt * 16 + lcol;
          epi[oc * 131 + px] = acc[mt][nt][reg];
        }
      }
    }
    __syncthreads();
    for (int i = tid; i < 8192; i += 256){
      int oc = i >> 7, px = i & 127;
      int row = px >> 4, c = px & 15;
      size_t o = (((size_t)b * 64 + oc) * 128 + y0 + row) * 128 + x0 + c;
      float v = epi[oc * 131 + px];
      if (resid) v += resid[o];
      OUTF[o] = v;
    }
  }
}

// ---------------- tokenize (2x2 avg) + fused layernorm stats ----------------
__global__ void k_tok(const float* __restrict__ xr, float* __restrict__ T,
                      float* __restrict__ NT){
  int idx = blockIdx.x * 256 + threadIdx.x; // 4*4096*64
  int c = idx & 63;
  int l = (idx >> 6) & 4095;
  int b = idx >> 18;
  int r = l >> 6, cl = l & 63;
  const float* p = xr + (((size_t)(b * 64 + c) * 128 + 2 * r) * 128 + 2 * cl);
  float t = 0.25f * (p[0] + p[1] + p[128] + p[129]);
  float s = t;
  for (int m = 32; m; m >>= 1) s += __shfl_xor(s, m);
  float mu = s * (1.f / 64.f);
  float d = t - mu;
  float q = d * d;
  for (int m = 32; m; m >>= 1) q += __shfl_xor(q, m);
  float var = q * (1.f / 64.f);
  T[idx] = t;
  NT[idx] = d * rsqrtf(var + 1e-5f);
}

// ---------------- fold LN gamma/beta into in_proj weights (both mambas) ----------------
__global__ __launch_bounds__(256) void k_fold2(
    const float* __restrict__ Wa, const float* __restrict__ lnwa, const float* __restrict__ lnba,
    float* __restrict__ W2a, float* __restrict__ B2a,
    const float* __restrict__ Wb, const float* __restrict__ lnwb, const float* __restrict__ lnbb,
    float* __restrict__ W2b, float* __restrict__ B2b){
  int m = blockIdx.x;
  const float* W   = m ? Wb   : Wa;
  const float* lnw = m ? lnwb : lnwa;
  const float* lnb = m ? lnbb : lnba;
  float* W2 = m ? W2b : W2a;
  float* B2 = m ? B2b : B2a;
  __shared__ float gw[64], gb[64];
  int j = threadIdx.x;
  if (j < 64){ gw[j] = lnw[j]; gb[j] = lnb[j]; }
  __syncthreads();
  float bias = 0.f;
#pragma unroll
  for (int k4 = 0; k4 < 16; k4++){
    float4 wv = *(const float4*)&W[j * 64 + k4 * 4];
    W2[j * 64 + k4 * 4 + 0] = wv.x * gw[k4 * 4 + 0];
    W2[j * 64 + k4 * 4 + 1] = wv.y * gw[k4 * 4 + 1];
    W2[j * 64 + k4 * 4 + 2] = wv.z * gw[k4 * 4 + 2];
    W2[j * 64 + k4 * 4 + 3] = wv.w * gw[k4 * 4 + 3];
    bias = fmaf(wv.x, gb[k4 * 4 + 0], bias);
    bias = fmaf(wv.y, gb[k4 * 4 + 1], bias);
    bias = fmaf(wv.z, gb[k4 * 4 + 2], bias);
    bias = fmaf(wv.w, gb[k4 * 4 + 3], bias);
  }
  B2[j] = bias;
}

// ---------------- in_proj (both mambas) ----------------
__global__ __launch_bounds__(256) void k_inproj(
    const float* __restrict__ NT,
    const float* __restrict__ W2a, const float* __restrict__ B2a,
    float* __restrict__ XCa, float* __restrict__ Za,
    const float* __restrict__ W2b, const float* __restrict__ B2b,
    float* __restrict__ XCb, float* __restrict__ Zb)
{
  __shared__ float wL[64 * 68];
  int mz = blockIdx.z;
  const float* W2 = mz ? W2b : W2a;
  const float* B2 = mz ? B2b : B2a;
  float* XC = mz ? XCb : XCa;
  float* Z  = mz ? Zb  : Za;
  int tid = threadIdx.x;
  int t0 = blockIdx.x * 64;
  int j0 = blockIdx.y * 64;
  for (int i = tid; i < 4096; i += 256){
    int jl = i >> 6, k = i & 63;
    wL[jl * 68 + k] = W2[(size_t)(j0 + jl) * 64 + k];
  }
  __syncthreads();
  int tq = tid >> 4, cg = tid & 15;
  const float* ntp = NT + (size_t)(t0 + tq * 4) * 64;
  float acc[4][4];
#pragma unroll
  for (int c = 0; c < 4; c++){
    float bias = B2[j0 + cg + c * 16];
#pragma unroll
    for (int t = 0; t < 4; t++) acc[t][c] = bias;
  }
#pragma unroll 4
  for (int k4 = 0; k4 < 16; k4++){
    float4 lv[4];
#pragma unroll
    for (int t = 0; t < 4; t++)
      lv[t] = *(const float4*)(ntp + t * 64 + k4 * 4);
    float4 wv[4];
#pragma unroll
    for (int c = 0; c < 4; c++)
      wv[c] = *(const float4*)&wL[(cg + c * 16) * 68 + k4 * 4];
#pragma unroll
    for (int t = 0; t < 4; t++)
#pragma unroll
      for (int c = 0; c < 4; c++){
        acc[t][c] = fmaf(lv[t].x, wv[c].x, acc[t][c]);
        acc[t][c] = fmaf(lv[t].y, wv[c].y, acc[t][c]);
        acc[t][c] = fmaf(lv[t].z, wv[c].z, acc[t][c]);
        acc[t][c] = fmaf(lv[t].w, wv[c].w, acc[t][c]);
      }
  }
  if (j0 < 128){
#pragma unroll
    for (int t = 0; t < 4; t++){
      size_t tg = t0 + tq * 4 + t;
#pragma unroll
      for (int c = 0; c < 4; c++)
        XC[tg * 128 + j0 + cg + c * 16] = acc[t][c];
    }
  } else {
#pragma unroll
    for (int t = 0; t < 4; t++){
      size_t tg = t0 + tq * 4 + t;
#pragma unroll
      for (int c = 0; c < 4; c++)
        Z[tg * 128 + (j0 - 128) + cg + c * 16] = acc[t][c];
    }
  }
}

// ---------------- causal depthwise conv(4) + bias + silu (both mambas) ----------------
__global__ void k_dwconv(const float* __restrict__ XC0, const float* __restrict__ cw0,
                         const float* __restrict__ cb0, float* __restrict__ U0,
                         const float* __restrict__ XC1, const float* __restrict__ cw1,
                         const float* __restrict__ cb1, float* __restrict__ U1){
  int bid = blockIdx.x;
  int m = bid >> 13;
  const float* XC = m ? XC1 : XC0;
  const float* cw = m ? cw1 : cw0;
  const float* cb = m ? cb1 : cb0;
  float* U = m ? U1 : U0;
  int idx = (bid & 8191) * 256 + threadIdx.x; // 4*4096*128
  int n = idx & 127;
  int l = (idx >> 7) & 4095;
  float4 wv = *(const float4*)(cw + n * 4);
  float a = cb[n];
  a = fmaf(wv.w, XC[idx], a);
  if (l >= 1) a = fmaf(wv.z, XC[idx - 128], a);
  if (l >= 2) a = fmaf(wv.y, XC[idx - 256], a);
  if (l >= 3) a = fmaf(wv.x, XC[idx - 384], a);
  U[idx] = a * sigmoidf_(a);
}

// ---------------- fused x_proj + dt (both mambas) ----------------
__global__ __launch_bounds__(256) void k_xprojdt(
    const float* __restrict__ U0, const float* __restrict__ XW0,
    const float* __restrict__ DTW0, const float* __restrict__ DTB0,
    float* __restrict__ DBL0, float* __restrict__ DT0,
    const float* __restrict__ U1, const float* __restrict__ XW1,
    const float* __restrict__ DTW1, const float* __restrict__ DTB1,
    float* __restrict__ DBL1, float* __restrict__ DT1)
{
  __shared__ float xw[36 * 132];
  __shared__ float sdtr[128 * 4];
  int bid = blockIdx.x;
  int m = bid >> 7, blk = bid & 127;
  const float* Up   = m ? U1   : U0;
  const float* XWp  = m ? XW1  : XW0;
  const float* DTWp = m ? DTW1 : DTW0;
  const float* DTBp = m ? DTB1 : DTB0;
  float* DBLp = m ? DBL1 : DBL0;
  float* DTp  = m ? DT1  : DT0;
  int tid = threadIdx.x;
  for (int i = tid; i < 4608; i += 256)
    xw[(i >> 7) * 132 + (i & 127)] = XWp[i];
  __syncthreads();
  int slot = tid >> 2, jq = tid & 3;
  size_t tgA = (size_t)blk * 128 + slot;
  size_t tgB = tgA + 64;
  const float4* upA = (const float4*)(Up + tgA * 128);
  const float4* upB = (const float4*)(Up + tgB * 128);
  float accA[9], accB[9];
#pragma unroll
  for (int jj = 0; jj < 9; jj++){ accA[jj] = 0.f; accB[jj] = 0.f; }
  for (int k4 = 0; k4 < 32; k4++){
    float4 uA = upA[k4];
    float4 uB = upB[k4];
#pragma unroll
    for (int jj = 0; jj < 9; jj++){
      float4 w = *(const float4*)&xw[(jq * 9 + jj) * 132 + k4 * 4];
      accA[jj] = fmaf(w.x, uA.x, fmaf(w.y, uA.y, fmaf(w.z, uA.z, fmaf(w.w, uA.w, accA[jj]))));
      accB[jj] = fmaf(w.x, uB.x, fmaf(w.y, uB.y, fmaf(w.z, uB.z, fmaf(w.w, uB.w, accB[jj]))));
    }
  }
#pragma unroll
  for (int jj = 0; jj < 9; jj++){
    DBLp[tgA * 36 + jq * 9 + jj] = accA[jj];
    DBLp[tgB * 36 + jq * 9 + jj] = accB[jj];
  }
  if (jq == 0){
#pragma unroll
    for (int jj = 0; jj < 4; jj++){
      sdtr[slot * 4 + jj] = accA[jj];
      sdtr[(slot + 64) * 4 + jj] = accB[jj];
    }
  }
  __syncthreads();
  int ch = tid & 127, half = tid >> 7;
  float4 wv = *(const float4*)(DTWp + ch * 4);
  float bias = DTBp[ch];
  for (int i = 0; i < 64; i++){
    int tl = half * 64 + i;
    float4 d = *(const float4*)&sdtr[tl * 4];
    float x = bias;
    x = fmaf(wv.x, d.x, x); x = fmaf(wv.y, d.y, x);
    x = fmaf(wv.z, d.z, x); x = fmaf(wv.w, d.w, x);
    x = fmaxf(x, 0.f) + log1pf(__expf(-fabsf(x)));
    DTp[((size_t)blk * 128 + tl) * 128 + ch] = x;
  }
}

// ================= chunked parallel scan (4 states/thread) =================
__global__ __launch_bounds__(256) void k_scanA(
    const float* __restrict__ DT0, const float* __restrict__ DBL0, const float* __restrict__ U0,
    const float* __restrict__ AL0,
    const float* __restrict__ DT1, const float* __restrict__ DBL1, const float* __restrict__ U1,
    const float* __restrict__ AL1,
    float* __restrict__ HF, float* __restrict__ AP)
{
  __shared__ float sdt[64 * 65], su[64 * 65], sB[16 * 68];
  int bid = blockIdx.x;
  int cg = bid & 1;
  int c  = (bid >> 1) & 63;
  int b  = (bid >> 7) & 3;
  int m  = bid >> 9;
  const float* DTp  = m ? DT1  : DT0;
  const float* DBLp = m ? DBL1 : DBL0;
  const float* Up   = m ? U1   : U0;
  const float* ALp  = m ? AL1  : AL0;
  int tid = threadIdx.x;
  int lane = tid & 63, w = tid >> 6;
  int lcol = lane & 15, q = lane >> 4;
  int chL = w * 16 + lcol;
  int n = cg * 64 + chL;
  size_t base = (size_t)b * 4096 + c * 64;
  for (int i = tid; i < 4096; i += 256){
    int ch = i & 63, l = i >> 6;
    size_t off = (base + l) * 128 + cg * 64 + ch;
    sdt[l * 65 + ch] = DTp[off];
    su[l * 65 + ch]  = Up[off];
  }
  for (int i = tid; i < 1024; i += 256){
    int s = i & 15, l = i >> 4;
    sB[s * 68 + l] = DBLp[(base + l) * 36 + 4 + s];
  }
  float A1[4];
#pragma unroll
  for (int j = 0; j < 4; j++) A1[j] = -__expf(ALp[n * 16 + q * 4 + j]);
  __syncthreads();
  float h[4] = {0.f, 0.f, 0.f, 0.f};
  float ap[4] = {1.f, 1.f, 1.f, 1.f};
#pragma unroll
  for (int l4 = 0; l4 < 16; l4++){
    float4 Bv[4];
#pragma unroll
    for (int j = 0; j < 4; j++) Bv[j] = *(const float4*)&sB[(q * 4 + j) * 68 + l4 * 4];
#pragma unroll
    for (int jj = 0; jj < 4; jj++){
      int l = l4 * 4 + jj;
      float dt = sdt[l * 65 + chL];
      float u  = su[l * 65 + chL];
      float dtu = dt * u;
#pragma unroll
      for (int j = 0; j < 4; j++){
        float a = __expf(dt * A1[j]);
        h[j] = fmaf(a, h[j], dtu * (&Bv[j].x)[jj]);
        ap[j] *= a;
      }
    }
  }
  size_t o = ((size_t)((m * 4 + b) * 64 + c)) * 2048 + n * 16 + q * 4;
  *(float4*)&HF[o] = make_float4(h[0], h[1], h[2], h[3]);
  *(float4*)&AP[o] = make_float4(ap[0], ap[1], ap[2], ap[3]);
}

__global__ __launch_bounds__(64) void k_scanB(
    const float* __restrict__ HF, const float* __restrict__ AP, float* __restrict__ HIN)
{
  int r = blockIdx.x * 64 + threadIdx.x;
  int q = r >> 11;        // (m*4+b)
  int p = r & 2047;       // n*16+s
  float h = 0.f;
  for (int c = 0; c < 64; c++){
    size_t o = (size_t)(q * 64 + c) * 2048 + p;
    HIN[o] = h;
    h = fmaf(AP[o], h, HF[o]);
  }
}

__global__ __launch_bounds__(256) void k_scanC(
    const float* __restrict__ DT0, const float* __restrict__ DBL0, const float* __restrict__ U0,
    const float* __restrict__ AL0, const float* __restrict__ D0, float* __restrict__ Y0,
    const float* __restrict__ DT1, const float* __restrict__ DBL1, const float* __restrict__ U1,
    const float* __restrict__ AL1, const float* __restrict__ D1, float* __restrict__ Y1,
    const float* __restrict__ HIN)
{
  __shared__ float sdt[64 * 65], su[64 * 65], sB[16 * 68], sC[16 * 68];
  int bid = blockIdx.x;
  int cg = bid & 1;
  int c  = (bid >> 1) & 63;
  int b  = (bid >> 7) & 3;
  int m  = bid >> 9;
  const float* DTp  = m ? DT1  : DT0;
  const float* DBLp = m ? DBL1 : DBL0;
  const float* Up   = m ? U1   : U0;
  const float* ALp  = m ? AL1  : AL0;
  const float* Dp   = m ? D1   : D0;
  float*       Yp   = m ? Y1   : Y0;
  int tid = threadIdx.x;
  int lane = tid & 63, w = tid >> 6;
  int lcol = lane & 15, q = lane >> 4;
  int chL = w * 16 + lcol;
  int n = cg * 64 + chL;
  size_t base = (size_t)b * 4096 + c * 64;
  for (int i = tid; i < 4096; i += 256){
    int ch = i & 63, l = i >> 6;
    size_t off = (base + l) * 128 + cg * 64 + ch;
    sdt[l * 65 + ch] = DTp[off];
    su[l * 65 + ch]  = Up[off];
  }
  for (int i = tid; i < 1024; i += 256){
    int s = i & 15, l = i >> 4;
    size_t ob = (base + l) * 36;
    sB[s * 68 + l] = DBLp[ob + 4 + s];
    sC[s * 68 + l] = DBLp[ob + 20 + s];
  }
  float A1[4];
#pragma unroll
  for (int j = 0; j < 4; j++) A1[j] = -__expf(ALp[n * 16 + q * 4 + j]);
  float Dn = Dp[n];
  float4 hv = *(const float4*)&HIN[((size_t)((m * 4 + b) * 64 + c)) * 2048 + n * 16 + q * 4];
  float h[4] = {hv.x, hv.y, hv.z, hv.w};
  __syncthreads();
#pragma unroll
  for (int l4 = 0; l4 < 16; l4++){
    float4 Bv[4], Cv[4];
#pragma unroll
    for (int j = 0; j < 4; j++){
      Bv[j] = *(const float4*)&sB[(q * 4 + j) * 68 + l4 * 4];
      Cv[j] = *(const float4*)&sC[(q * 4 + j) * 68 + l4 * 4];
    }
#pragma unroll
    for (int jj = 0; jj < 4; jj++){
      int l = l4 * 4 + jj;
      float dt = sdt[l * 65 + chL];
      float u  = su[l * 65 + chL];
      float dtu = dt * u;
      float p = 0.f;
#pragma unroll
      for (int j = 0; j < 4; j++){
        float a = __expf(dt * A1[j]);
        h[j] = fmaf(a, h[j], dtu * (&Bv[j].x)[jj]);
        p = fmaf(h[j], (&Cv[j].x)[jj], p);
      }
      p += __shfl_xor(p, 16);
      p += __shfl_xor(p, 32);
      if (q == 0)
        Yp[(base + l) * 128 + n] = fmaf(u, Dn, p);
    }
  }
}

// ---------------- out_proj (both mambas): ((Y)*silu(Z)) @ W^T ----------------
__global__ __launch_bounds__(256) void k_outproj(
    const float* __restrict__ Y0, const float* __restrict__ Zg0,
    const float* __restrict__ W0, float* __restrict__ OUT0,
    const float* __restrict__ Y1, const float* __restrict__ Zg1,
    const float* __restrict__ W1, float* __restrict__ OUT1)
{
  __shared__ float yl[16 * 128];
  __shared__ float wT[128 * 65];
  int m = blockIdx.y;
  const float* Y  = m ? Y1  : Y0;
  const float* Zg = m ? Zg1 : Zg0;
  const float* W  = m ? W1  : W0;
  float* OUT = m ? OUT1 : OUT0;
  int tid = threadIdx.x;
  size_t t0 = (size_t)blockIdx.x * 16;
  for (int i = tid; i < 2048; i += 256){
    float z = Zg[t0 * 128 + i];
    yl[i] = Y[t0 * 128 + i] * (z * sigmoidf_(z));
  }
  for (int i = tid; i < 8192; i += 256){
    int k = i & 127, j = i >> 7;
    wT[k * 65 + j] = W[j * 128 + k];
  }
  __syncthreads();
  int j = tid & 63;
  int tg = tid >> 6;
  float acc[4] = {0.f, 0.f, 0.f, 0.f};
  for (int k = 0; k < 128; k += 4){
    float w0 = wT[k * 65 + j], w1 = wT[(k+1) * 65 + j];
    float w2 = wT[(k+2) * 65 + j], w3 = wT[(k+3) * 65 + j];
#pragma unroll
    for (int t = 0; t < 4; t++){
      float4 yv = *(const float4*)&yl[(tg * 4 + t) * 128 + k];
      acc[t] = fmaf(w0, yv.x, fmaf(w1, yv.y, fmaf(w2, yv.z, fmaf(w3, yv.w, acc[t]))));
    }
  }
#pragma unroll
  for (int t = 0; t < 4; t++)
    OUT[(t0 + tg * 4 + t) * 64 + j] = acc[t];
}

// ---------------- softmax over L: partial pass (grid 256 = b4 x lc64) ----------------
__global__ void k_smA(const float* __restrict__ G, float* __restrict__ P){
  int bid = blockIdx.x;
  int b = bid >> 6, lc = bid & 63;
  int tid = threadIdx.x;
  int j = tid & 63, part = tid >> 6;
  size_t base = (size_t)b * 4096 + lc * 64;
  float mx = -3.4e38f;
  for (int i = 0; i < 16; i++){
    int l = part + i * 4;
    mx = fmaxf(mx, G[(base + l) * 64 + j]);
  }
  float sm = 0.f;
  for (int i = 0; i < 16; i++){
    int l = part + i * 4;
    sm += __expf(G[(base + l) * 64 + j] - mx);
  }
  __shared__ float sM[256], sS[256];
  sM[tid] = mx; sS[tid] = sm;
  __syncthreads();
  if (tid < 64){
    float M = sM[tid], S = sS[tid];
    for (int p = 1; p < 4; p++){
      float m2 = sM[p * 64 + tid], s2 = sS[p * 64 + tid];
      float Mn = fmaxf(M, m2);
      S = S * __expf(M - Mn) + s2 * __expf(m2 - Mn);
      M = Mn;
    }
    P[(bid * 64 + tid) * 2] = M;
    P[(bid * 64 + tid) * 2 + 1] = S;
  }
}

__global__ void k_smB(const float* __restrict__ P, float* __restrict__ F){
  int tid = threadIdx.x; // 256 = b(4) x j(64)
  int b = tid >> 6, j = tid & 63;
  float M = -3.4e38f, S = 0.f;
  for (int lc = 0; lc < 64; lc++){
    int idx = ((b * 64 + lc) * 64 + j) * 2;
    float m2 = P[idx], s2 = P[idx + 1];
    float Mn = fmaxf(M, m2);
    S = S * __expf(M - Mn) + s2 * __expf(m2 - Mn);
    M = Mn;
  }
  F[(b * 64 + j) * 2] = M;
  F[(b * 64 + j) * 2 + 1] = S;
}

// ---------------- combine + transpose to (b,c,64,64) ----------------
__global__ void k_combine(const float* __restrict__ T, const float* __restrict__ MAIN,
                          const float* __restrict__ G, const float* __restrict__ F,
                          float* __restrict__ FEAT){
  int bid = blockIdx.x;
  int b = bid >> 6, row = bid & 63;
  int tid = threadIdx.x;
  int j = tid & 63, ls = tid >> 6;
  __shared__ float tile[64 * 65];
  float M = F[(b * 64 + j) * 2], invS = 1.f / F[(b * 64 + j) * 2 + 1];
  size_t lbase = (size_t)b * 4096 + row * 64;
  for (int i = 0; i < 16; i++){
    int col = ls + i * 4;
    size_t off = (lbase + col) * 64 + j;
    float g = __expf(G[off] - M) * invS;
    tile[col * 65 + j] = T[off] + g * MAIN[off];
  }
  __syncthreads();
  int colw = tid & 63, jr = tid >> 6;
  for (int jj = jr; jj < 64; jj += 4)
    FEAT[(((size_t)b * 64 + jj) * 64 + row) * 64 + colw] = tile[colw * 65 + jj];
}

// ---------------- bilinear upsample 64->128 ----------------
__global__ void k_up(const float* __restrict__ FEAT, float* __restrict__ UP){
  size_t idx = (size_t)blockIdx.x * 256 + threadIdx.x;
  int x = idx & 127;
  int y = (idx >> 7) & 127;
  size_t bc = idx >> 14;
  float ay = 0.5f * y - 0.25f;
  float ax = 0.5f * x - 0.25f;
  int fy = (int)floorf(ay); float wy = ay - fy;
  int fx = (int)floorf(ax); float wx = ax - fx;
  int y0 = fy < 0 ? 0 : fy, y1 = fy + 1 > 63 ? 63 : fy + 1;
  int x0 = fx < 0 ? 0 : fx, x1 = fx + 1 > 63 ? 63 : fx + 1;
  const float* p = FEAT + bc * 4096;
  float v = (1.f - wy) * ((1.f - wx) * p[y0 * 64 + x0] + wx * p[y0 * 64 + x1])
          +        wy  * ((1.f - wx) * p[y1 * 64 + x0] + wx * p[y1 * 64 + x1]);
  UP[idx] = v;
}

// ---------------- host launcher ----------------
extern "C" void kernel_launch(void* const* d_in, const int* in_sizes, int n_in,
                              void* d_out, int out_size, void* d_ws, size_t ws_size,
                              hipStream_t stream) {
  // workspace layout (float offsets)
  const size_t P1A = 0, P1B = 4326400, XR = 8652800;
  const size_t MB0 = 0, MB1 = 10027008;
  const size_t O_LN = 0, O_XC = 1048576, O_Z = 3145728, O_U = 5242880,
               O_DT = 7340032, O_DBL = 9437184;
  const size_t TOK = 20054016, OUT0 = 21102592, OUT1 = 22151168;
  const size_t FEAT = 23208448;
  const size_t UPO = 0, P3A = 4194304, P3B = 8520704;
  const size_t WA_H = 19000000, WA_L = 19018432, WB_H = 19036864, WB_L = 19055296;
  const size_t PADN = 2163200;
  const size_t SMP = 0, SMF = 65536;
  const size_t W2_0 = 21102592, B2_0 = 21118976, W2_1 = 21119232, B2_1 = 21135616;
  const size_t TOTAL = 24257024;
  if (ws_size < TOTAL * 4) return;

  float* ws = (float*)d_ws;
  const float* X   = (const float*)d_in[0];
  const float* CB1 = (const float*)d_in[1];
  const float* CB2 = (const float*)d_in[2];
  const float* SW1 = (const float*)d_in[3];
  const float* SW2 = (const float*)d_in[4];
  const float* LNW[2] = { (const float*)d_in[5], (const float*)d_in[7] };
  const float* LNB[2] = { (const float*)d_in[6], (const float*)d_in[8] };
  const float *INW[2], *CW[2], *CBb[2], *XPW[2], *DTW[2], *DTB[2], *AL[2], *DD[2], *OW[2];
  for (int m = 0; m < 2; m++){
    int p = 9 + m * 9;
    INW[m] = (const float*)d_in[p + 0];
    CW[m]  = (const float*)d_in[p + 1];
    CBb[m] = (const float*)d_in[p + 2];
    XPW[m] = (const float*)d_in[p + 3];
    DTW[m] = (const float*)d_in[p + 4];
    DTB[m] = (const float*)d_in[p + 5];
    AL[m]  = (const float*)d_in[p + 6];
    DD[m]  = (const float*)d_in[p + 7];
    OW[m]  = (const float*)d_in[p + 8];
  }

  u16* wah = (u16*)(ws + WA_H); u16* wal = (u16*)(ws + WA_L);
  u16* wbh = (u16*)(ws + WB_H); u16* wbl = (u16*)(ws + WB_L);

  // ---- phase 1: conv block (MFMA) + tokenize (+LN stats) ----
  {
    u16* pah = (u16*)(ws + P1A); u16* pal = pah + PADN * 2;
    u16* pbh = (u16*)(ws + P1B); u16* pbl = pbh + PADN * 2;
    k_wswz2<<<288, 256, 0, stream>>>(CB1, wah, wal, CB2, wbh, wbl);
    k_prep<<<dim3(130, 4), 256, 0, stream>>>(X, pah, pal);
    k_bord<<<9, 256, 0, stream>>>(pbh, pbl);
    k_convm<<<dim3(8, 16, 4), 256, 0, stream>>>(pah, pal, wah, wal, nullptr, pbh, pbl, nullptr, 0);
    k_convm<<<dim3(8, 16, 4), 256, 0, stream>>>(pbh, pbl, wbh, wbl, X, nullptr, nullptr, ws + XR, 1);
    k_tok<<<4096, 256, 0, stream>>>(ws + XR, ws + TOK, ws + MB0 + O_LN);
  }

  // ---- phase 2: mamba x2 ----
  k_fold2<<<2, 256, 0, stream>>>(INW[0], LNW[0], LNB[0], ws + W2_0, ws + B2_0,
                                 INW[1], LNW[1], LNB[1], ws + W2_1, ws + B2_1);
  k_inproj<<<dim3(256, 4, 2), 256, 0, stream>>>(
      ws + MB0 + O_LN,
      ws + W2_0, ws + B2_0, ws + MB0 + O_XC, ws + MB0 + O_Z,
      ws + W2_1, ws + B2_1, ws + MB1 + O_XC, ws + MB1 + O_Z);
  k_dwconv<<<16384, 256, 0, stream>>>(
      ws + MB0 + O_XC, CW[0], CBb[0], ws + MB0 + O_U,
      ws + MB1 + O_XC, CW[1], CBb[1], ws + MB1 + O_U);
  k_xprojdt<<<256, 256, 0, stream>>>(
      ws + MB0 + O_U, XPW[0], DTW[0], DTB[0], ws + MB0 + O_DBL, ws + MB0 + O_DT,
      ws + MB1 + O_U, XPW[1], DTW[1], DTB[1], ws + MB1 + O_DBL, ws + MB1 + O_DT);

  float* HF  = ws + MB0 + O_XC;
  float* AP  = ws + MB0 + O_XC + 1048576;
  float* HIN = ws + MB0 + O_LN;

  k_scanA<<<1024, 256, 0, stream>>>(
      ws + MB0 + O_DT, ws + MB0 + O_DBL, ws + MB0 + O_U, AL[0],
      ws + MB1 + O_DT, ws + MB1 + O_DBL, ws + MB1 + O_U, AL[1],
      HF, AP);
  k_scanB<<<256, 64, 0, stream>>>(HF, AP, HIN);
  k_scanC<<<1024, 256, 0, stream>>>(
      ws + MB0 + O_DT, ws + MB0 + O_DBL, ws + MB0 + O_U, AL[0], DD[0], ws + MB0 + O_XC,
      ws + MB1 + O_DT, ws + MB1 + O_DBL, ws + MB1 + O_U, AL[1], DD[1], ws + MB1 + O_XC,
      HIN);

  k_outproj<<<dim3(1024, 2), 256, 0, stream>>>(
      ws + MB0 + O_XC, ws + MB0 + O_Z, OW[0], ws + OUT0,
      ws + MB1 + O_XC, ws + MB1 + O_Z, OW[1], ws + OUT1);

  k_smA<<<256, 256, 0, stream>>>(ws + OUT1, ws + SMP);
  k_smB<<<1, 256, 0, stream>>>(ws + SMP, ws + SMF);
  k_combine<<<256, 256, 0, stream>>>(ws + TOK, ws + OUT0, ws + OUT1, ws + SMF, ws + FEAT);

  // ---- phase 3: upsample + conv block (MFMA) ----
  {
    u16* pah = (u16*)(ws + P3A); u16* pal = pah + PADN * 2;
    u16* pbh = (u16*)(ws + P3B); u16* pbl = pbh + PADN * 2;
    k_up<<<16384, 256, 0, stream>>>(ws + FEAT, ws + UPO);
    k_wswz2<<<288, 256, 0, stream>>>(SW1, wah, wal, SW2, wbh, wbl);
    k_prep<<<dim3(130, 4), 256, 0, stream>>>(ws + UPO, pah, pal);
    k_bord<<<9, 256, 0, stream>>>(pbh, pbl);
    k_convm<<<dim3(8, 16, 4), 256, 0, stream>>>(pah, pal, wah, wal, nullptr, pbh, pbl, nullptr, 0);
    k_convm<<<dim3(8, 16, 4), 256, 0, stream>>>(pbh, pbl, wbh, wbl, nullptr, nullptr, nullptr, (float*)d_out, 1);
  }
}

// Round 10
// 434.802 us; speedup vs baseline: 5.7027x; 1.0348x over previous
//
#include <hip/hip_runtime.h>

typedef unsigned int u32;
typedef unsigned short u16;
typedef __attribute__((ext_vector_type(8))) short short8;
typedef __attribute__((ext_vector_type(4))) float f32x4;

__device__ __forceinline__ float sigmoidf_(float x){
  return 1.f / (1.f + __expf(-x));
}
__device__ __forceinline__ u16 f2bf(float f){
  union { float f; u32 i; } v; v.f = f;
  u32 r = v.i + 0x7fffu + ((v.i >> 16) & 1u);
  return (u16)(r >> 16);
}
__device__ __forceinline__ float bf2f(u32 u){
  union { float f; u32 i; } v; v.i = (u & 0xffffu) << 16; return v.f;
}

// ---------------- weight swizzle (two sets) + border zero tail ----------------
__global__ void k_wswz2b(const float* __restrict__ wA, u16* __restrict__ WHA, u16* __restrict__ WLA,
                         const float* __restrict__ wB, u16* __restrict__ WHB, u16* __restrict__ WLB,
                         u16* __restrict__ BPH, u16* __restrict__ BPL){
  int gidx = blockIdx.x * 256 + threadIdx.x;   // grid 297 -> 76032
  if (gidx < 73728){
    int sel = gidx >= 36864;
    int idx = gidx - sel * 36864;
    const float* w = sel ? wB : wA;
    u16* WH = sel ? WHB : WHA;
    u16* WL = sel ? WLB : WLA;
    int j    = idx & 7;
    int lane = (idx >> 3) & 63;
    int nt   = (idx >> 9) & 3;
    int kc   = (idx >> 11) & 1;
    int t    = idx >> 12;           // 0..8
    int ic = kc * 32 + ((lane >> 4) & 3) * 8 + j;
    int oc = nt * 16 + (lane & 15);
    float v = w[(oc * 64 + ic) * 9 + t];
    u16 h = f2bf(v);
    u16 l = f2bf(v - bf2f(h));
    WH[idx] = h; WL[idx] = l;
  } else {
    int i = gidx - 73728;           // 2064 border pixels
    if (i >= 2064) return;
    int b = i / 516, p = i - b * 516;
    int y, x;
    if (p < 130){ y = 0; x = p; }
    else if (p < 260){ y = 129; x = p - 130; }
    else if (p < 388){ y = p - 260 + 1; x = 0; }
    else { y = p - 388 + 1; x = 129; }
    size_t o = (((size_t)b * 130 + y) * 130 + x) * 64;
    uint4 z = make_uint4(0, 0, 0, 0);
#pragma unroll
    for (int q = 0; q < 8; q++){
      *(uint4*)(BPH + o + q * 8) = z;
      *(uint4*)(BPL + o + q * 8) = z;
    }
  }
}

// ---------------- prep: NCHW fp32 -> padded NHWC bf16 hi/lo ----------------
__global__ __launch_bounds__(256) void k_prep(const float* __restrict__ src,
                                              u16* __restrict__ PH, u16* __restrict__ PL){
  __shared__ float ld[64 * 128];
  int yp = blockIdx.x;          // padded row 0..129
  int b  = blockIdx.y;
  int ys = yp - 1;
  int tid = threadIdx.x;
  if ((u32)ys < 128u){
    for (int i = tid; i < 8192; i += 256){
      int c = i >> 7, x = i & 127;
      ld[i] = src[((size_t)(b * 64 + c) * 128 + ys) * 128 + x];
    }
  }
  __syncthreads();
  for (int i = tid; i < 130 * 64; i += 256){
    int xp = i >> 6, c = i & 63;
    float v = 0.f;
    if ((u32)ys < 128u && (u32)(xp - 1) < 128u) v = ld[c * 128 + (xp - 1)];
    u16 h = f2bf(v);
    u16 l = f2bf(v - bf2f(h));
    size_t o = (((size_t)b * 130 + yp) * 130 + xp) * 64 + c;
    PH[o] = h; PL[o] = l;
  }
}

// ---------------- prep with fused bilinear upsample 64->128 ----------------
// reads FEAT (b,c,64,64); writes padded NHWC bf16 h/l row yp.
__global__ __launch_bounds__(256) void k_prepup(const float* __restrict__ FEAT,
                                                u16* __restrict__ PH, u16* __restrict__ PL){
  __shared__ float ld0[64 * 64], ld1[64 * 64];
  int yp = blockIdx.x;
  int b  = blockIdx.y;
  int ys = yp - 1;
  int tid = threadIdx.x;
  float wy = 0.f;
  if ((u32)ys < 128u){
    float ay = 0.5f * ys - 0.25f;
    int fy = (int)floorf(ay); wy = ay - fy;
    int y0s = fy < 0 ? 0 : fy, y1s = fy + 1 > 63 ? 63 : fy + 1;
    for (int i = tid; i < 1024; i += 256){
      int c = i >> 4, x4 = (i & 15) * 4;
      *(float4*)&ld0[c * 64 + x4] = *(const float4*)&FEAT[((size_t)(b * 64 + c) * 64 + y0s) * 64 + x4];
      *(float4*)&ld1[c * 64 + x4] = *(const float4*)&FEAT[((size_t)(b * 64 + c) * 64 + y1s) * 64 + x4];
    }
  }
  __syncthreads();
  for (int i = tid; i < 130 * 64; i += 256){
    int xp = i >> 6, c = i & 63;
    float v = 0.f;
    int xs = xp - 1;
    if ((u32)ys < 128u && (u32)xs < 128u){
      float ax = 0.5f * xs - 0.25f;
      int fx = (int)floorf(ax); float wx = ax - fx;
      int x0s = fx < 0 ? 0 : fx, x1s = fx + 1 > 63 ? 63 : fx + 1;
      float v0 = (1.f - wx) * ld0[c * 64 + x0s] + wx * ld0[c * 64 + x1s];
      float v1 = (1.f - wx) * ld1[c * 64 + x0s] + wx * ld1[c * 64 + x1s];
      v = (1.f - wy) * v0 + wy * v1;
    }
    u16 h = f2bf(v);
    u16 l = f2bf(v - bf2f(h));
    size_t o = (((size_t)b * 130 + yp) * 130 + xp) * 64 + c;
    PH[o] = h; PL[o] = l;
  }
}

// ---------------- MFMA conv3x3 64->64 ----------------
// grid (8,16,4): 16x8 px tile, 64 oc. block 256 = 4 waves; wave w = rows {2w,2w+1}.
// mode 0: relu -> padded bf16 h/l.  mode 1: fp32 NCHW (+resid).
// mode 2: (+resid) -> fused 2x2-avg tokenize + LN -> T, NT.
__global__ __launch_bounds__(256) void k_convm(
    const u16* __restrict__ PH, const u16* __restrict__ PL,
    const u16* __restrict__ WH, const u16* __restrict__ WL,
    const float* __restrict__ resid,
    u16* __restrict__ OBH, u16* __restrict__ OBL,
    float* __restrict__ OUTF, float* __restrict__ T, float* __restrict__ NT,
    int mode)
{
  __shared__ __align__(16) u32 smem[9024];   // stage 5760 | epi(+red) 9024
  u16* Ah_s = (u16*)smem;                    // 5760 u16: [10r][18c][32ic]
  u16* Al_s = Ah_s + 5760;
  int tid = threadIdx.x;
  int lane = tid & 63, w = tid >> 6;
  int quad = lane >> 4, lcol = lane & 15;
  int b = blockIdx.z, y0 = blockIdx.y * 8, x0 = blockIdx.x * 16;

  f32x4 acc[2][4];
#pragma unroll
  for (int mt = 0; mt < 2; mt++)
#pragma unroll
    for (int nt = 0; nt < 4; nt++)
      acc[mt][nt] = (f32x4){0.f, 0.f, 0.f, 0.f};

  for (int kc = 0; kc < 2; kc++){
    __syncthreads();
    for (int i = tid; i < 720; i += 256){
      int q = i & 3;
      int rc = i >> 2;
      int r = rc / 18, c = rc - r * 18;
      size_t so = (((size_t)b * 130 + y0 + r) * 130 + (x0 + c)) * 64 + kc * 32 + q * 8;
      int de = (r * 18 + c) * 32 + q * 8;
      *(uint4*)(Ah_s + de) = *(const uint4*)(PH + so);
      *(uint4*)(Al_s + de) = *(const uint4*)(PL + so);
    }
    __syncthreads();
#pragma unroll
    for (int t = 0; t < 9; t++){
      int dy = t / 3, dx = t - dy * 3;
      short8 bh[4], bl[4];
#pragma unroll
      for (int nt = 0; nt < 4; nt++){
        int o = ((t * 2 + kc) * 4 + nt) * 512 + lane * 8;
        bh[nt] = *(const short8*)(WH + o);
        bl[nt] = *(const short8*)(WL + o);
      }
      short8 ah[2], al[2];
#pragma unroll
      for (int mt = 0; mt < 2; mt++){
        int e = ((w * 2 + mt + dy) * 18 + (lcol + dx)) * 32 + quad * 8;
        ah[mt] = *(const short8*)(Ah_s + e);
        al[mt] = *(const short8*)(Al_s + e);
      }
#pragma unroll
      for (int mt = 0; mt < 2; mt++)
#pragma unroll
        for (int nt = 0; nt < 4; nt++){
          acc[mt][nt] = __builtin_amdgcn_mfma_f32_16x16x32_bf16(ah[mt], bh[nt], acc[mt][nt], 0, 0, 0);
          acc[mt][nt] = __builtin_amdgcn_mfma_f32_16x16x32_bf16(ah[mt], bl[nt], acc[mt][nt], 0, 0, 0);
          acc[mt][nt] = __builtin_amdgcn_mfma_f32_16x16x32_bf16(al[mt], bh[nt], acc[mt][nt], 0, 0, 0);
        }
    }
  }

  // epilogue. C-frag: col(lane&15)=oc-in-tile, row(quad*4+reg)=px-col.
  __syncthreads();
  if (mode == 0){
    u32* epi = smem;   // [px 128][oc 66]
#pragma unroll
    for (int mt = 0; mt < 2; mt++){
      int row = w * 2 + mt;
#pragma unroll
      for (int nt = 0; nt < 4; nt++){
#pragma unroll
        for (int reg = 0; reg < 4; reg++){
          float v = fmaxf(acc[mt][nt][reg], 0.f);
          u32 h = f2bf(v);
          u32 l = f2bf(v - bf2f(h));
          int ccol = quad * 4 + reg;
          int oc = nt * 16 + lcol;
          epi[(row * 16 + ccol) * 66 + oc] = h | (l << 16);
        }
      }
    }
    __syncthreads();
    for (int i = tid; i < 8192; i += 256){
      int px = i >> 6, oc = i & 63;
      int row = px >> 4, ccol = px & 15;
      u32 pk = epi[px * 66 + oc];
      size_t o = (((size_t)b * 130 + y0 + row + 1) * 130 + (x0 + ccol + 1)) * 64 + oc;
      OBH[o] = (u16)pk;
      OBL[o] = (u16)(pk >> 16);
    }
  } else {
    float* epi = (float*)smem;  // [oc 64][px 131]
#pragma unroll
    for (int mt = 0; mt < 2; mt++){
      int row = w * 2 + mt;
#pragma unroll
      for (int nt = 0; nt < 4; nt++){
#pragma unroll
        for (int reg = 0; reg < 4; reg++){
          int px = row * 16 + quad * 4 + reg;
          int oc = nt * 16 + lcol;
          epi[oc * 131 + px] = acc[mt][nt][reg];
        }
      }
    }
    __syncthreads();
    if (mode == 1){
      for (int i = tid; i < 8192; i += 256){
        int oc = i >> 7, px = i & 127;
        int row = px >> 4, c = px & 15;
        size_t o = (((size_t)b * 64 + oc) * 128 + y0 + row) * 128 + x0 + c;
        float v = epi[oc * 131 + px];
        if (resid) v += resid[o];
        OUTF[o] = v;
      }
    } else {
      // mode 2: add residual into LDS, then tokenize + LN
      for (int i = tid; i < 8192; i += 256){
        int oc = i >> 7, px = i & 127;
        int row = px >> 4, c = px & 15;
        size_t o = (((size_t)b * 64 + oc) * 128 + y0 + row) * 128 + x0 + c;
        epi[oc * 131 + px] += resid[o];
      }
      __syncthreads();
      float* redS  = (float*)smem + 8384;  // [32][9]
      float* redQ  = redS + 288;           // [32][9]
      float* stats = redQ + 288;           // [32][2]
      int token = tid & 31, cgrp = tid >> 5;
      int tr = token >> 3, tc = token & 7;
      float av[8]; float s = 0.f, q = 0.f;
      int p0 = (2 * tr) * 16 + 2 * tc;
#pragma unroll
      for (int j = 0; j < 8; j++){
        int c = cgrp * 8 + j;
        const float* ep = epi + c * 131;
        float v = 0.25f * (ep[p0] + ep[p0 + 1] + ep[p0 + 16] + ep[p0 + 17]);
        av[j] = v; s += v; q = fmaf(v, v, q);
      }
      redS[token * 9 + cgrp] = s;
      redQ[token * 9 + cgrp] = q;
      __syncthreads();
      if (tid < 32){
        float S = 0.f, Q = 0.f;
        for (int g = 0; g < 8; g++){ S += redS[tid * 9 + g]; Q += redQ[tid * 9 + g]; }
        float mu = S * (1.f / 64.f);
        float var = Q * (1.f / 64.f) - mu * mu;
        stats[tid * 2] = mu;
        stats[tid * 2 + 1] = rsqrtf(var + 1e-5f);
      }
      __syncthreads();
      float mu = stats[token * 2], inv = stats[token * 2 + 1];
      int l = (blockIdx.y * 4 + tr) * 64 + blockIdx.x * 8 + tc;
      size_t to = ((size_t)b * 4096 + l) * 64 + cgrp * 8;
#pragma unroll
      for (int j = 0; j < 8; j++){
        T[to + j] = av[j];
        NT[to + j] = (av[j] - mu) * inv;
      }
    }
  }
}

// ---------------- fold LN gamma/beta into in_proj weights (both mambas) ----------------
__global__ __launch_bounds__(256) void k_fold2(
    const float* __restrict__ Wa, const float* __restrict__ lnwa, const float* __restrict__ lnba,
    float* __restrict__ W2a, float* __restrict__ B2a,
    const float* __restrict__ Wb, const float* __restrict__ lnwb, const float* __restrict__ lnbb,
    float* __restrict__ W2b, float* __restrict__ B2b){
  int m = blockIdx.x;
  const float* W   = m ? Wb   : Wa;
  const float* lnw = m ? lnwb : lnwa;
  const float* lnb = m ? lnbb : lnba;
  float* W2 = m ? W2b : W2a;
  float* B2 = m ? B2b : B2a;
  __shared__ float gw[64], gb[64];
  int j = threadIdx.x;
  if (j < 64){ gw[j] = lnw[j]; gb[j] = lnb[j]; }
  __syncthreads();
  float bias = 0.f;
#pragma unroll
  for (int k4 = 0; k4 < 16; k4++){
    float4 wv = *(const float4*)&W[j * 64 + k4 * 4];
    W2[j * 64 + k4 * 4 + 0] = wv.x * gw[k4 * 4 + 0];
    W2[j * 64 + k4 * 4 + 1] = wv.y * gw[k4 * 4 + 1];
    W2[j * 64 + k4 * 4 + 2] = wv.z * gw[k4 * 4 + 2];
    W2[j * 64 + k4 * 4 + 3] = wv.w * gw[k4 * 4 + 3];
    bias = fmaf(wv.x, gb[k4 * 4 + 0], bias);
    bias = fmaf(wv.y, gb[k4 * 4 + 1], bias);
    bias = fmaf(wv.z, gb[k4 * 4 + 2], bias);
    bias = fmaf(wv.w, gb[k4 * 4 + 3], bias);
  }
  B2[j] = bias;
}

// ---------------- in_proj + fused dwconv/silu (both mambas) ----------------
// grid (256, 4, 2): x = 64-token tile, y = 64-col quarter (0,1 -> XC->U; 2,3 -> Z).
__global__ __launch_bounds__(256) void k_inprojdw(
    const float* __restrict__ NT,
    const float* __restrict__ W2a, const float* __restrict__ B2a,
    float* __restrict__ Ua, float* __restrict__ Za,
    const float* __restrict__ cwa, const float* __restrict__ cba,
    const float* __restrict__ W2b, const float* __restrict__ B2b,
    float* __restrict__ Ub, float* __restrict__ Zb,
    const float* __restrict__ cwb, const float* __restrict__ cbb)
{
  __shared__ float wL[64 * 68];
  __shared__ float xcs[67 * 68];
  int mz = blockIdx.z;
  const float* W2 = mz ? W2b : W2a;
  const float* B2 = mz ? B2b : B2a;
  float* U = mz ? Ub : Ua;
  float* Z  = mz ? Zb : Za;
  const float* cw = mz ? cwb : cwa;
  const float* cb = mz ? cbb : cba;
  int tid = threadIdx.x;
  int t0 = blockIdx.x * 64;
  int j0 = blockIdx.y * 64;
  for (int i = tid; i < 4096; i += 256){
    int jl = i >> 6, k = i & 63;
    wL[jl * 68 + k] = W2[(size_t)(j0 + jl) * 64 + k];
  }
  __syncthreads();
  int tq = tid >> 4, cg = tid & 15;
  const float* ntp = NT + (size_t)(t0 + tq * 4) * 64;
  float acc[4][4];
#pragma unroll
  for (int c = 0; c < 4; c++){
    float bias = B2[j0 + cg + c * 16];
#pragma unroll
    for (int t = 0; t < 4; t++) acc[t][c] = bias;
  }
#pragma unroll 4
  for (int k4 = 0; k4 < 16; k4++){
    float4 lv[4];
#pragma unroll
    for (int t = 0; t < 4; t++)
      lv[t] = *(const float4*)(ntp + t * 64 + k4 * 4);
    float4 wv[4];
#pragma unroll
    for (int c = 0; c < 4; c++)
      wv[c] = *(const float4*)&wL[(cg + c * 16) * 68 + k4 * 4];
#pragma unroll
    for (int t = 0; t < 4; t++)
#pragma unroll
      for (int c = 0; c < 4; c++){
        acc[t][c] = fmaf(lv[t].x, wv[c].x, acc[t][c]);
        acc[t][c] = fmaf(lv[t].y, wv[c].y, acc[t][c]);
        acc[t][c] = fmaf(lv[t].z, wv[c].z, acc[t][c]);
        acc[t][c] = fmaf(lv[t].w, wv[c].w, acc[t][c]);
      }
  }
  if (j0 < 128){
    // 3 boundary tokens (zero at batch start)
    int isStart = ((t0 & 4095) == 0);
    if (tid < 192){
      int e = tid >> 6, col = tid & 63;
      float v = 0.f;
      if (!isStart){
        const float* np = NT + (size_t)(t0 - 3 + e) * 64;
        float a2 = B2[j0 + col];
#pragma unroll 4
        for (int k = 0; k < 64; k += 4){
          float4 nv = *(const float4*)(np + k);
          float4 wv = *(const float4*)&wL[col * 68 + k];
          a2 = fmaf(nv.x, wv.x, fmaf(nv.y, wv.y, fmaf(nv.z, wv.z, fmaf(nv.w, wv.w, a2))));
        }
        v = a2;
      }
      xcs[e * 68 + col] = v;
    }
#pragma unroll
    for (int t = 0; t < 4; t++)
#pragma unroll
      for (int c = 0; c < 4; c++)
        xcs[(3 + tq * 4 + t) * 68 + cg + c * 16] = acc[t][c];
    __syncthreads();
#pragma unroll
    for (int c = 0; c < 4; c++){
      int lc = cg + c * 16;
      int ch = j0 + lc;
      float4 wv = *(const float4*)(cw + ch * 4);
      float bias = cb[ch];
#pragma unroll
      for (int t = 0; t < 4; t++){
        int row = 3 + tq * 4 + t;
        float a = bias;
        a = fmaf(wv.w, xcs[row * 68 + lc], a);
        a = fmaf(wv.z, xcs[(row - 1) * 68 + lc], a);
        a = fmaf(wv.y, xcs[(row - 2) * 68 + lc], a);
        a = fmaf(wv.x, xcs[(row - 3) * 68 + lc], a);
        size_t tg = t0 + tq * 4 + t;
        U[tg * 128 + ch] = a * sigmoidf_(a);
      }
    }
  } else {
#pragma unroll
    for (int t = 0; t < 4; t++){
      size_t tg = t0 + tq * 4 + t;
#pragma unroll
      for (int c = 0; c < 4; c++)
        Z[tg * 128 + (j0 - 128) + cg + c * 16] = acc[t][c];
    }
  }
}

// ---------------- fused x_proj + dt (both mambas) ----------------
__global__ __launch_bounds__(256) void k_xprojdt(
    const float* __restrict__ U0, const float* __restrict__ XW0,
    const float* __restrict__ DTW0, const float* __restrict__ DTB0,
    float* __restrict__ DBL0, float* __restrict__ DT0,
    const float* __restrict__ U1, const float* __restrict__ XW1,
    const float* __restrict__ DTW1, const float* __restrict__ DTB1,
    float* __restrict__ DBL1, float* __restrict__ DT1)
{
  __shared__ float xw[36 * 132];
  __shared__ float sdtr[128 * 4];
  int bid = blockIdx.x;
  int m = bid >> 7, blk = bid & 127;
  const float* Up   = m ? U1   : U0;
  const float* XWp  = m ? XW1  : XW0;
  const float* DTWp = m ? DTW1 : DTW0;
  const float* DTBp = m ? DTB1 : DTB0;
  float* DBLp = m ? DBL1 : DBL0;
  float* DTp  = m ? DT1  : DT0;
  int tid = threadIdx.x;
  for (int i = tid; i < 4608; i += 256)
    xw[(i >> 7) * 132 + (i & 127)] = XWp[i];
  __syncthreads();
  int slot = tid >> 2, jq = tid & 3;
  size_t tgA = (size_t)blk * 128 + slot;
  size_t tgB = tgA + 64;
  const float4* upA = (const float4*)(Up + tgA * 128);
  const float4* upB = (const float4*)(Up + tgB * 128);
  float accA[9], accB[9];
#pragma unroll
  for (int jj = 0; jj < 9; jj++){ accA[jj] = 0.f; accB[jj] = 0.f; }
  for (int k4 = 0; k4 < 32; k4++){
    float4 uA = upA[k4];
    float4 uB = upB[k4];
#pragma unroll
    for (int jj = 0; jj < 9; jj++){
      float4 w = *(const float4*)&xw[(jq * 9 + jj) * 132 + k4 * 4];
      accA[jj] = fmaf(w.x, uA.x, fmaf(w.y, uA.y, fmaf(w.z, uA.z, fmaf(w.w, uA.w, accA[jj]))));
      accB[jj] = fmaf(w.x, uB.x, fmaf(w.y, uB.y, fmaf(w.z, uB.z, fmaf(w.w, uB.w, accB[jj]))));
    }
  }
#pragma unroll
  for (int jj = 0; jj < 9; jj++){
    DBLp[tgA * 36 + jq * 9 + jj] = accA[jj];
    DBLp[tgB * 36 + jq * 9 + jj] = accB[jj];
  }
  if (jq == 0){
#pragma unroll
    for (int jj = 0; jj < 4; jj++){
      sdtr[slot * 4 + jj] = accA[jj];
      sdtr[(slot + 64) * 4 + jj] = accB[jj];
    }
  }
  __syncthreads();
  int ch = tid & 127, half = tid >> 7;
  float4 wv = *(const float4*)(DTWp + ch * 4);
  float bias = DTBp[ch];
  for (int i = 0; i < 64; i++){
    int tl = half * 64 + i;
    float4 d = *(const float4*)&sdtr[tl * 4];
    float x = bias;
    x = fmaf(wv.x, d.x, x); x = fmaf(wv.y, d.y, x);
    x = fmaf(wv.z, d.z, x); x = fmaf(wv.w, d.w, x);
    x = fmaxf(x, 0.f) + log1pf(__expf(-fabsf(x)));
    DTp[((size_t)blk * 128 + tl) * 128 + ch] = x;
  }
}

// ================= chunked parallel scan (4 states/thread) =================
__global__ __launch_bounds__(256) void k_scanA(
    const float* __restrict__ DT0, const float* __restrict__ DBL0, const float* __restrict__ U0,
    const float* __restrict__ AL0,
    const float* __restrict__ DT1, const float* __restrict__ DBL1, const float* __restrict__ U1,
    const float* __restrict__ AL1,
    float* __restrict__ HF, float* __restrict__ AP)
{
  __shared__ float sdt[64 * 65], su[64 * 65], sB[16 * 68];
  int bid = blockIdx.x;
  int cg = bid & 1;
  int c  = (bid >> 1) & 63;
  int b  = (bid >> 7) & 3;
  int m  = bid >> 9;
  const float* DTp  = m ? DT1  : DT0;
  const float* DBLp = m ? DBL1 : DBL0;
  const float* Up   = m ? U1   : U0;
  const float* ALp  = m ? AL1  : AL0;
  int tid = threadIdx.x;
  int lane = tid & 63, w = tid >> 6;
  int lcol = lane & 15, q = lane >> 4;
  int chL = w * 16 + lcol;
  int n = cg * 64 + chL;
  size_t base = (size_t)b * 4096 + c * 64;
  for (int i = tid; i < 4096; i += 256){
    int ch = i & 63, l = i >> 6;
    size_t off = (base + l) * 128 + cg * 64 + ch;
    sdt[l * 65 + ch] = DTp[off];
    su[l * 65 + ch]  = Up[off];
  }
  for (int i = tid; i < 1024; i += 256){
    int s = i & 15, l = i >> 4;
    sB[s * 68 + l] = DBLp[(base + l) * 36 + 4 + s];
  }
  float A1[4];
#pragma unroll
  for (int j = 0; j < 4; j++) A1[j] = -__expf(ALp[n * 16 + q * 4 + j]);
  __syncthreads();
  float h[4] = {0.f, 0.f, 0.f, 0.f};
  float ap[4] = {1.f, 1.f, 1.f, 1.f};
#pragma unroll
  for (int l4 = 0; l4 < 16; l4++){
    float4 Bv[4];
#pragma unroll
    for (int j = 0; j < 4; j++) Bv[j] = *(const float4*)&sB[(q * 4 + j) * 68 + l4 * 4];
#pragma unroll
    for (int jj = 0; jj < 4; jj++){
      int l = l4 * 4 + jj;
      float dt = sdt[l * 65 + chL];
      float u  = su[l * 65 + chL];
      float dtu = dt * u;
#pragma unroll
      for (int j = 0; j < 4; j++){
        float a = __expf(dt * A1[j]);
        h[j] = fmaf(a, h[j], dtu * (&Bv[j].x)[jj]);
        ap[j] *= a;
      }
    }
  }
  size_t o = ((size_t)((m * 4 + b) * 64 + c)) * 2048 + n * 16 + q * 4;
  *(float4*)&HF[o] = make_float4(h[0], h[1], h[2], h[3]);
  *(float4*)&AP[o] = make_float4(ap[0], ap[1], ap[2], ap[3]);
}

__global__ __launch_bounds__(64) void k_scanB(
    const float* __restrict__ HF, const float* __restrict__ AP, float* __restrict__ HIN)
{
  int r = blockIdx.x * 64 + threadIdx.x;
  int q = r >> 11;        // (m*4+b)
  int p = r & 2047;       // n*16+s
  float h = 0.f;
  for (int c = 0; c < 64; c++){
    size_t o = (size_t)(q * 64 + c) * 2048 + p;
    HIN[o] = h;
    h = fmaf(AP[o], h, HF[o]);
  }
}

__global__ __launch_bounds__(256) void k_scanC(
    const float* __restrict__ DT0, const float* __restrict__ DBL0, const float* __restrict__ U0,
    const float* __restrict__ AL0, const float* __restrict__ D0, float* __restrict__ Y0,
    const float* __restrict__ DT1, const float* __restrict__ DBL1, const float* __restrict__ U1,
    const float* __restrict__ AL1, const float* __restrict__ D1, float* __restrict__ Y1,
    const float* __restrict__ HIN)
{
  __shared__ float sdt[64 * 65], su[64 * 65], sB[16 * 68], sC[16 * 68];
  int bid = blockIdx.x;
  int cg = bid & 1;
  int c  = (bid >> 1) & 63;
  int b  = (bid >> 7) & 3;
  int m  = bid >> 9;
  const float* DTp  = m ? DT1  : DT0;
  const float* DBLp = m ? DBL1 : DBL0;
  const float* Up   = m ? U1   : U0;
  const float* ALp  = m ? AL1  : AL0;
  const float* Dp   = m ? D1   : D0;
  float*       Yp   = m ? Y1   : Y0;
  int tid = threadIdx.x;
  int lane = tid & 63, w = tid >> 6;
  int lcol = lane & 15, q = lane >> 4;
  int chL = w * 16 + lcol;
  int n = cg * 64 + chL;
  size_t base = (size_t)b * 4096 + c * 64;
  for (int i = tid; i < 4096; i += 256){
    int ch = i & 63, l = i >> 6;
    size_t off = (base + l) * 128 + cg * 64 + ch;
    sdt[l * 65 + ch] = DTp[off];
    su[l * 65 + ch]  = Up[off];
  }
  for (int i = tid; i < 1024; i += 256){
    int s = i & 15, l = i >> 4;
    size_t ob = (base + l) * 36;
    sB[s * 68 + l] = DBLp[ob + 4 + s];
    sC[s * 68 + l] = DBLp[ob + 20 + s];
  }
  float A1[4];
#pragma unroll
  for (int j = 0; j < 4; j++) A1[j] = -__expf(ALp[n * 16 + q * 4 + j]);
  float Dn = Dp[n];
  float4 hv = *(const float4*)&HIN[((size_t)((m * 4 + b) * 64 + c)) * 2048 + n * 16 + q * 4];
  float h[4] = {hv.x, hv.y, hv.z, hv.w};
  __syncthreads();
#pragma unroll
  for (int l4 = 0; l4 < 16; l4++){
    float4 Bv[4], Cv[4];
#pragma unroll
    for (int j = 0; j < 4; j++){
      Bv[j] = *(const float4*)&sB[(q * 4 + j) * 68 + l4 * 4];
      Cv[j] = *(const float4*)&sC[(q * 4 + j) * 68 + l4 * 4];
    }
#pragma unroll
    for (int jj = 0; jj < 4; jj++){
      int l = l4 * 4 + jj;
      float dt = sdt[l * 65 + chL];
      float u  = su[l * 65 + chL];
      float dtu = dt * u;
      float p = 0.f;
#pragma unroll
      for (int j = 0; j < 4; j++){
        float a = __expf(dt * A1[j]);
        h[j] = fmaf(a, h[j], dtu * (&Bv[j].x)[jj]);
        p = fmaf(h[j], (&Cv[j].x)[jj], p);
      }
      p += __shfl_xor(p, 16);
      p += __shfl_xor(p, 32);
      if (q == 0)
        Yp[(base + l) * 128 + n] = fmaf(u, Dn, p);
    }
  }
}

// ---------------- out_proj (both mambas): ((Y)*silu(Z)) @ W^T ----------------
__global__ __launch_bounds__(256) void k_outproj(
    const float* __restrict__ Y0, const float* __restrict__ Zg0,
    const float* __restrict__ W0, float* __restrict__ OUT0,
    const float* __restrict__ Y1, const float* __restrict__ Zg1,
    const float* __restrict__ W1, float* __restrict__ OUT1)
{
  __shared__ float yl[16 * 128];
  __shared__ float wT[128 * 65];
  int m = blockIdx.y;
  const float* Y  = m ? Y1  : Y0;
  const float* Zg = m ? Zg1 : Zg0;
  const float* W  = m ? W1  : W0;
  float* OUT = m ? OUT1 : OUT0;
  int tid = threadIdx.x;
  size_t t0 = (size_t)blockIdx.x * 16;
  for (int i = tid; i < 2048; i += 256){
    float z = Zg[t0 * 128 + i];
    yl[i] = Y[t0 * 128 + i] * (z * sigmoidf_(z));
  }
  for (int i = tid; i < 8192; i += 256){
    int k = i & 127, j = i >> 7;
    wT[k * 65 + j] = W[j * 128 + k];
  }
  __syncthreads();
  int j = tid & 63;
  int tg = tid >> 6;
  float acc[4] = {0.f, 0.f, 0.f, 0.f};
  for (int k = 0; k < 128; k += 4){
    float w0 = wT[k * 65 + j], w1 = wT[(k+1) * 65 + j];
    float w2 = wT[(k+2) * 65 + j], w3 = wT[(k+3) * 65 + j];
#pragma unroll
    for (int t = 0; t < 4; t++){
      float4 yv = *(const float4*)&yl[(tg * 4 + t) * 128 + k];
      acc[t] = fmaf(w0, yv.x, fmaf(w1, yv.y, fmaf(w2, yv.z, fmaf(w3, yv.w, acc[t]))));
    }
  }
#pragma unroll
  for (int t = 0; t < 4; t++)
    OUT[(t0 + tg * 4 + t) * 64 + j] = acc[t];
}

// ---------------- softmax over L: partial pass (grid 256 = b4 x lc64) ----------------
__global__ void k_smA(const float* __restrict__ G, float* __restrict__ P){
  int bid = blockIdx.x;
  int b = bid >> 6, lc = bid & 63;
  int tid = threadIdx.x;
  int j = tid & 63, part = tid >> 6;
  size_t base = (size_t)b * 4096 + lc * 64;
  float mx = -3.4e38f;
  for (int i = 0; i < 16; i++){
    int l = part + i * 4;
    mx = fmaxf(mx, G[(base + l) * 64 + j]);
  }
  float sm = 0.f;
  for (int i = 0; i < 16; i++){
    int l = part + i * 4;
    sm += __expf(G[(base + l) * 64 + j] - mx);
  }
  __shared__ float sM[256], sS[256];
  sM[tid] = mx; sS[tid] = sm;
  __syncthreads();
  if (tid < 64){
    float M = sM[tid], S = sS[tid];
    for (int p = 1; p < 4; p++){
      float m2 = sM[p * 64 + tid], s2 = sS[p * 64 + tid];
      float Mn = fmaxf(M, m2);
      S = S * __expf(M - Mn) + s2 * __expf(m2 - Mn);
      M = Mn;
    }
    P[(bid * 64 + tid) * 2] = M;
    P[(bid * 64 + tid) * 2 + 1] = S;
  }
}

__global__ void k_smB(const float* __restrict__ P, float* __restrict__ F){
  int tid = threadIdx.x; // 256 = b(4) x j(64)
  int b = tid >> 6, j = tid & 63;
  float M = -3.4e38f, S = 0.f;
  for (int lc = 0; lc < 64; lc++){
    int idx = ((b * 64 + lc) * 64 + j) * 2;
    float m2 = P[idx], s2 = P[idx + 1];
    float Mn = fmaxf(M, m2);
    S = S * __expf(M - Mn) + s2 * __expf(m2 - Mn);
    M = Mn;
  }
  F[(b * 64 + j) * 2] = M;
  F[(b * 64 + j) * 2 + 1] = S;
}

// ---------------- combine + transpose to (b,c,64,64) ----------------
__global__ void k_combine(const float* __restrict__ T, const float* __restrict__ MAIN,
                          const float* __restrict__ G, const float* __restrict__ F,
                          float* __restrict__ FEAT){
  int bid = blockIdx.x;
  int b = bid >> 6, row = bid & 63;
  int tid = threadIdx.x;
  int j = tid & 63, ls = tid >> 6;
  __shared__ float tile[64 * 65];
  float M = F[(b * 64 + j) * 2], invS = 1.f / F[(b * 64 + j) * 2 + 1];
  size_t lbase = (size_t)b * 4096 + row * 64;
  for (int i = 0; i < 16; i++){
    int col = ls + i * 4;
    size_t off = (lbase + col) * 64 + j;
    float g = __expf(G[off] - M) * invS;
    tile[col * 65 + j] = T[off] + g * MAIN[off];
  }
  __syncthreads();
  int colw = tid & 63, jr = tid >> 6;
  for (int jj = jr; jj < 64; jj += 4)
    FEAT[(((size_t)b * 64 + jj) * 64 + row) * 64 + colw] = tile[colw * 65 + jj];
}

// ---------------- host launcher ----------------
extern "C" void kernel_launch(void* const* d_in, const int* in_sizes, int n_in,
                              void* d_out, int out_size, void* d_ws, size_t ws_size,
                              hipStream_t stream) {
  // workspace layout (float offsets)
  const size_t P1A = 0, P1B = 4326400;
  const size_t MB0 = 0, MB1 = 10027008;
  const size_t O_LN = 0, O_XC = 1048576, O_Z = 3145728, O_U = 5242880,
               O_DT = 7340032, O_DBL = 9437184;
  const size_t TOK = 20054016, OUT0 = 21102592, OUT1 = 22151168;
  const size_t FEAT = 23208448;
  const size_t P3A = 4194304, P3B = 8520704;
  const size_t WA_H = 19000000, WA_L = 19018432, WB_H = 19036864, WB_L = 19055296;
  const size_t PADN = 2163200;
  const size_t SMP = 0, SMF = 65536;
  const size_t W2_0 = 21102592, B2_0 = 21118976, W2_1 = 21119232, B2_1 = 21135616;
  const size_t TOTAL = 24257024;
  if (ws_size < TOTAL * 4) return;

  float* ws = (float*)d_ws;
  const float* X   = (const float*)d_in[0];
  const float* CB1 = (const float*)d_in[1];
  const float* CB2 = (const float*)d_in[2];
  const float* SW1 = (const float*)d_in[3];
  const float* SW2 = (const float*)d_in[4];
  const float* LNW[2] = { (const float*)d_in[5], (const float*)d_in[7] };
  const float* LNB[2] = { (const float*)d_in[6], (const float*)d_in[8] };
  const float *INW[2], *CW[2], *CBb[2], *XPW[2], *DTW[2], *DTB[2], *AL[2], *DD[2], *OW[2];
  for (int m = 0; m < 2; m++){
    int p = 9 + m * 9;
    INW[m] = (const float*)d_in[p + 0];
    CW[m]  = (const float*)d_in[p + 1];
    CBb[m] = (const float*)d_in[p + 2];
    XPW[m] = (const float*)d_in[p + 3];
    DTW[m] = (const float*)d_in[p + 4];
    DTB[m] = (const float*)d_in[p + 5];
    AL[m]  = (const float*)d_in[p + 6];
    DD[m]  = (const float*)d_in[p + 7];
    OW[m]  = (const float*)d_in[p + 8];
  }

  u16* wah = (u16*)(ws + WA_H); u16* wal = (u16*)(ws + WA_L);
  u16* wbh = (u16*)(ws + WB_H); u16* wbl = (u16*)(ws + WB_L);

  // ---- phase 1: conv block (MFMA) + fused tokenize/LN ----
  {
    u16* pah = (u16*)(ws + P1A); u16* pal = pah + PADN * 2;
    u16* pbh = (u16*)(ws + P1B); u16* pbl = pbh + PADN * 2;
    k_wswz2b<<<297, 256, 0, stream>>>(CB1, wah, wal, CB2, wbh, wbl, pbh, pbl);
    k_prep<<<dim3(130, 4), 256, 0, stream>>>(X, pah, pal);
    k_convm<<<dim3(8, 16, 4), 256, 0, stream>>>(pah, pal, wah, wal, nullptr,
                                                pbh, pbl, nullptr, nullptr, nullptr, 0);
    k_convm<<<dim3(8, 16, 4), 256, 0, stream>>>(pbh, pbl, wbh, wbl, X,
                                                nullptr, nullptr, nullptr,
                                                ws + TOK, ws + MB0 + O_LN, 2);
  }

  // ---- phase 2: mamba x2 ----
  k_fold2<<<2, 256, 0, stream>>>(INW[0], LNW[0], LNB[0], ws + W2_0, ws + B2_0,
                                 INW[1], LNW[1], LNB[1], ws + W2_1, ws + B2_1);
  k_inprojdw<<<dim3(256, 4, 2), 256, 0, stream>>>(
      ws + MB0 + O_LN,
      ws + W2_0, ws + B2_0, ws + MB0 + O_U, ws + MB0 + O_Z, CW[0], CBb[0],
      ws + W2_1, ws + B2_1, ws + MB1 + O_U, ws + MB1 + O_Z, CW[1], CBb[1]);
  k_xprojdt<<<256, 256, 0, stream>>>(
      ws + MB0 + O_U, XPW[0], DTW[0], DTB[0], ws + MB0 + O_DBL, ws + MB0 + O_DT,
      ws + MB1 + O_U, XPW[1], DTW[1], DTB[1], ws + MB1 + O_DBL, ws + MB1 + O_DT);

  float* HF  = ws + MB0 + O_XC;
  float* AP  = ws + MB0 + O_XC + 1048576;
  float* HIN = ws + MB0 + O_LN;

  k_scanA<<<1024, 256, 0, stream>>>(
      ws + MB0 + O_DT, ws + MB0 + O_DBL, ws + MB0 + O_U, AL[0],
      ws + MB1 + O_DT, ws + MB1 + O_DBL, ws + MB1 + O_U, AL[1],
      HF, AP);
  k_scanB<<<256, 64, 0, stream>>>(HF, AP, HIN);
  k_scanC<<<1024, 256, 0, stream>>>(
      ws + MB0 + O_DT, ws + MB0 + O_DBL, ws + MB0 + O_U, AL[0], DD[0], ws + MB0 + O_XC,
      ws + MB1 + O_DT, ws + MB1 + O_DBL, ws + MB1 + O_U, AL[1], DD[1], ws + MB1 + O_XC,
      HIN);

  k_outproj<<<dim3(1024, 2), 256, 0, stream>>>(
      ws + MB0 + O_XC, ws + MB0 + O_Z, OW[0], ws + OUT0,
      ws + MB1 + O_XC, ws + MB1 + O_Z, OW[1], ws + OUT1);

  k_smA<<<256, 256, 0, stream>>>(ws + OUT1, ws + SMP);
  k_smB<<<1, 256, 0, stream>>>(ws + SMP, ws + SMF);
  k_combine<<<256, 256, 0, stream>>>(ws + TOK, ws + OUT0, ws + OUT1, ws + SMF, ws + FEAT);

  // ---- phase 3: fused upsample+prep + conv block (MFMA) ----
  {
    u16* pah = (u16*)(ws + P3A); u16* pal = pah + PADN * 2;
    u16* pbh = (u16*)(ws + P3B); u16* pbl = pbh + PADN * 2;
    k_wswz2b<<<297, 256, 0, stream>>>(SW1, wah, wal, SW2, wbh, wbl, pbh, pbl);
    k_prepup<<<dim3(130, 4), 256, 0, stream>>>(ws + FEAT, pah, pal);
    k_convm<<<dim3(8, 16, 4), 256, 0, stream>>>(pah, pal, wah, wal, nullptr,
                                                pbh, pbl, nullptr, nullptr, nullptr, 0);
    k_convm<<<dim3(8, 16, 4), 256, 0, stream>>>(pbh, pbl, wbh, wbl, nullptr,
                                                nullptr, nullptr, (float*)d_out,
                                                nullptr, nullptr, 1);
  }
}